// Round 1
// baseline (647.983 us; speedup 1.0000x reference)
//
#include <hip/hip_runtime.h>
#include <cstdint>
#include <cstddef>

// ---- problem constants ----
#define B_      2
#define S_      2048
#define DIM_    2048
#define H_      16
#define KV_LORA_ 512
#define NOPE_D_ 128
#define ROPE_D_ 64
#define V_D_    128
#define Q_D_    192          // NOPE_D + ROPE_D
#define EPS_    1e-6f
#define BS_     (B_ * S_)    // 4096 rows
#define CKV_P_  640          // ckv row pitch (576 padded to 5*128)

typedef __attribute__((ext_vector_type(8))) short bf16x8;
typedef __attribute__((ext_vector_type(4))) float f32x4;

__device__ __forceinline__ ushort f2bf(float f) {
    union { float f; uint32_t u; } v; v.f = f;
    uint32_t u = v.u + 0x7fff + ((v.u >> 16) & 1);  // RNE
    return (ushort)(u >> 16);
}
__device__ __forceinline__ float bf2f(ushort u) {
    union { uint32_t u; float f; } v; v.u = (uint32_t)u << 16; return v.f;
}
__device__ __forceinline__ void gll16(const void* g, void* l) {
    __builtin_amdgcn_global_load_lds(
        (const __attribute__((address_space(1))) unsigned int*)g,
        (__attribute__((address_space(3))) unsigned int*)l, 16, 0, 0);
}

// ============================================================================
// bf16 MFMA GEMM: C = A @ W^T.  (unchanged)
// ============================================================================
template <int OUT_BF16>
__global__ __launch_bounds__(256) void gemm_bf16_t(
    const ushort* __restrict__ A, const ushort* __restrict__ Bw,
    void* __restrict__ Cv, int N, int K)
{
    constexpr int BK = 64;
    __shared__ __align__(16) ushort Af[8192];   // 16 KB
    __shared__ __align__(16) ushort Bf[8192];   // 16 KB
    const int tid = threadIdx.x;
    const int lane = tid & 63;
    const int w = tid >> 6;
    const int l15 = lane & 15, quad = lane >> 4;
    const int m0 = blockIdx.y * 128;
    const int n0 = blockIdx.x * 128;
    const int wm0 = (w & 1) * 64, wn0 = (w >> 1) * 64;

    f32x4 acc[4][4];
#pragma unroll
    for (int i = 0; i < 4; ++i)
#pragma unroll
        for (int j = 0; j < 4; ++j) acc[i][j] = (f32x4){0.f, 0.f, 0.f, 0.f};

    const ushort* ap[4]; const ushort* bp[4];
    ushort* al[4]; ushort* bl[4];
#pragma unroll
    for (int t = 0; t < 4; ++t) {
        int ia = w * 4 + t;
        int kk = ia >> 3, q = (ia >> 1) & 3, mh = ia & 1;
        int koff = kk * 32 + q * 8;
        ap[t] = A  + (size_t)(m0 + mh * 64 + lane) * K + koff;
        bp[t] = Bw + (size_t)(n0 + mh * 64 + lane) * K + koff;
        al[t] = &Af[ia * 512];
        bl[t] = &Bf[ia * 512];
    }

    for (int k0 = 0; k0 < K; k0 += BK) {
        __syncthreads();
#pragma unroll
        for (int t = 0; t < 4; ++t) {
            gll16(ap[t], al[t]);
            gll16(bp[t], bl[t]);
            ap[t] += BK; bp[t] += BK;
        }
        __syncthreads();

        bf16x8 a0[4], a1[4], b0[4], b1[4];
#pragma unroll
        for (int i = 0; i < 4; ++i) {
            a0[i] = *(const bf16x8*)&Af[((0 + quad) * 128 + wm0 + i * 16 + l15) * 8];
            a1[i] = *(const bf16x8*)&Af[((4 + quad) * 128 + wm0 + i * 16 + l15) * 8];
            b0[i] = *(const bf16x8*)&Bf[((0 + quad) * 128 + wn0 + i * 16 + l15) * 8];
            b1[i] = *(const bf16x8*)&Bf[((4 + quad) * 128 + wn0 + i * 16 + l15) * 8];
        }
#pragma unroll
        for (int i = 0; i < 4; ++i)
#pragma unroll
            for (int j = 0; j < 4; ++j)
                acc[i][j] = __builtin_amdgcn_mfma_f32_16x16x32_bf16(a0[i], b0[j], acc[i][j], 0, 0, 0);
#pragma unroll
        for (int i = 0; i < 4; ++i)
#pragma unroll
            for (int j = 0; j < 4; ++j)
                acc[i][j] = __builtin_amdgcn_mfma_f32_16x16x32_bf16(a1[i], b1[j], acc[i][j], 0, 0, 0);
    }

#pragma unroll
    for (int i = 0; i < 4; ++i)
#pragma unroll
        for (int r = 0; r < 4; ++r) {
            size_t base = (size_t)(m0 + wm0 + i * 16 + quad * 4 + r) * N + n0 + wn0 + l15;
#pragma unroll
            for (int j = 0; j < 4; ++j) {
                float v = acc[i][j][r];
                if (OUT_BF16) ((ushort*)Cv)[base + j * 16] = f2bf(v);
                else          ((float*)Cv)[base + j * 16] = v;
            }
        }
}

// ============================================================================
// fp32 -> bf16 cast, 8 elems/thread (unchanged)
// ============================================================================
__global__ __launch_bounds__(256) void cast8(
    const float* __restrict__ s, ushort* __restrict__ d)
{
    size_t i = ((size_t)blockIdx.x * 256 + threadIdx.x) * 8;
    float4 a = *(const float4*)(s + i);
    float4 b = *(const float4*)(s + i + 4);
    ushort4 o0, o1;
    o0.x = f2bf(a.x); o0.y = f2bf(a.y); o0.z = f2bf(a.z); o0.w = f2bf(a.w);
    o1.x = f2bf(b.x); o1.y = f2bf(b.y); o1.z = f2bf(b.z); o1.w = f2bf(b.w);
    *(ushort4*)(d + i) = o0;
    *(ushort4*)(d + i + 4) = o1;
}

// wkva (576 x 2048) -> bf16 (640 x 2048), rows 576..639 zeroed (unchanged)
__global__ __launch_bounds__(256) void cast_wkva_pad(
    const float* __restrict__ s, ushort* __restrict__ d)
{
    size_t i = ((size_t)blockIdx.x * 256 + threadIdx.x) * 8;
    size_t row = i >> 11;   // /2048
    ushort4 o0 = {0,0,0,0}, o1 = {0,0,0,0};
    if (row < 576) {
        float4 a = *(const float4*)(s + i);
        float4 b = *(const float4*)(s + i + 4);
        o0.x = f2bf(a.x); o0.y = f2bf(a.y); o0.z = f2bf(a.z); o0.w = f2bf(a.w);
        o1.x = f2bf(b.x); o1.y = f2bf(b.y); o1.z = f2bf(b.z); o1.w = f2bf(b.w);
    }
    *(ushort4*)(d + i) = o0;
    *(ushort4*)(d + i + 4) = o1;
}

// ============================================================================
// RMSNorm over ckv[:, :512] (fp32, pitch 640) -> cnorm bf16 (unchanged)
// ============================================================================
__global__ __launch_bounds__(256) void rmsnorm_k(
    const float* __restrict__ ckv, const float* __restrict__ nw,
    ushort* __restrict__ cnorm)
{
    const int lane = threadIdx.x & 63;
    const int row = blockIdx.x * 4 + (threadIdx.x >> 6);
    const float* src = ckv + (size_t)row * CKV_P_;
    float4 a = *(const float4*)(src + lane * 4);
    float4 b = *(const float4*)(src + 256 + lane * 4);
    float ss = a.x*a.x + a.y*a.y + a.z*a.z + a.w*a.w
             + b.x*b.x + b.y*b.y + b.z*b.z + b.w*b.w;
#pragma unroll
    for (int off = 32; off > 0; off >>= 1) ss += __shfl_xor(ss, off, 64);
    float rs = rsqrtf(ss * (1.0f / 512.0f) + EPS_);
    float4 w0 = *(const float4*)(nw + lane * 4);
    float4 w1 = *(const float4*)(nw + 256 + lane * 4);
    ushort* dst = cnorm + (size_t)row * KV_LORA_;
    ushort4 o0, o1;
    o0.x = f2bf(a.x*rs*w0.x); o0.y = f2bf(a.y*rs*w0.y);
    o0.z = f2bf(a.z*rs*w0.z); o0.w = f2bf(a.w*rs*w0.w);
    o1.x = f2bf(b.x*rs*w1.x); o1.y = f2bf(b.y*rs*w1.y);
    o1.z = f2bf(b.z*rs*w1.z); o1.w = f2bf(b.w*rs*w1.w);
    *(ushort4*)(dst + lane * 4) = o0;
    *(ushort4*)(dst + 256 + lane * 4) = o1;
}

// ============================================================================
// RoPE k_rope from ckv fp32 (pitch 640, cols 512..575) -> krb bf16 (unchanged)
// ============================================================================
__global__ __launch_bounds__(256) void rope_cast_k(
    const float* __restrict__ ckv, const float* __restrict__ rope_cache,
    ushort* __restrict__ krb)
{
    const int lane = threadIdx.x & 63;
    const int w = blockIdx.x * 4 + (threadIdx.x >> 6);  // [0, BS)
    const int s = w & (S_ - 1);
    float v = ckv[(size_t)w * CKV_P_ + KV_LORA_ + lane];
    float other = __shfl_xor(v, 32, 64);
    float rot = (lane < 32) ? -other : other;
    float c  = rope_cache[s * (2 * ROPE_D_) + lane];
    float sn = rope_cache[s * (2 * ROPE_D_) + ROPE_D_ + lane];
    krb[(size_t)w * ROPE_D_ + lane] = f2bf(v * c + rot * sn);
}

// ============================================================================
// V transpose: kvb bf16 [bs][h*256 + 128 + c] -> vT [b*16+h][vd][s] (unchanged)
// ============================================================================
__global__ __launch_bounds__(256) void transpose_v(
    const ushort* __restrict__ kvb, ushort* __restrict__ vT)
{
    __shared__ ushort T[128][80];
    const int tid = threadIdx.x;
    const int bh = blockIdx.y;
    const int b = bh >> 4, h = bh & 15;
    const int sb = blockIdx.x * 64;
    const size_t rowbase = (size_t)b * S_ + sb;
#pragma unroll
    for (int it = 0; it < 4; ++it) {
        int f = tid + 256 * it;
        int r = f >> 4, c8 = (f & 15) * 8;
        bf16x8 v = *(const bf16x8*)(kvb + (rowbase + r) * 4096 + h * 256 + 128 + c8);
#pragma unroll
        for (int e = 0; e < 8; ++e) T[c8 + e][r] = (ushort)v[e];
    }
    __syncthreads();
#pragma unroll
    for (int it = 0; it < 4; ++it) {
        int f = tid + 256 * it;
        int vd = f >> 3, s8 = (f & 7) * 8;
        *(bf16x8*)(vT + ((size_t)bh * 128 + vd) * S_ + sb + s8) =
            *(const bf16x8*)&T[vd][s8];
    }
}

// ============================================================================
// MFMA flash attention v3.
//  - Same 4-wave / 64-row q-tile / complementary-pair structure as v2, plus:
//  - T14 async-stage: next K/V tile loaded global->regs with COALESCED
//    accesses (16 lanes per kvb row, 8 per krb/vT row) at iteration top;
//    reg->LDS ds_write after the read barrier.  Latency hides under compute.
//  - LDS dests XOR-swizzled (byte ^= (cg&7)<<4) so the reordered writes stay
//    2-way (free); identical XOR applied on fragment reads.
//  - Bijective XCD swizzle: each XCD owns 4 consecutive bh (working set ~4.3MB
//    -> L2-resident; was ~40MB/XCD -> 263MB HBM fetch).
//  - RoPE(q) fused into the Q-fragment load (rotate-half partner of qf[4][e]
//    is qf[5][e], same lane) -> rope_cast_q kernel deleted.
//  - defer-max (THR=8) + setprio(1) around MFMA clusters.
// ============================================================================
__global__ __launch_bounds__(256) void mla_attn_mfma3(
    const ushort* __restrict__ q_bf, const ushort* __restrict__ kvb,
    const ushort* __restrict__ krb, const ushort* __restrict__ vT,
    const float* __restrict__ rope_cache, ushort* __restrict__ attn)
{
    __shared__ __align__(16) char Kf[24 * 64 * 16];   // 24 KB (swizzled)
    __shared__ __align__(16) char Vf[8 * 128 * 16];   // 16 KB (swizzled)
    __shared__ __align__(16) ushort Pf[8 * 64 * 8];   //  8 KB

    const int tid = threadIdx.x;
    const int lane = tid & 63;
    const int w = tid >> 6;

    // XCD swizzle: dispatch round-robins lin%8 across XCDs; map so each XCD
    // gets 64 consecutive swz ids = 4 consecutive bh. Bijective (512%8==0).
    const int lin = (int)blockIdx.y * 16 + (int)blockIdx.x;
    const int swz = (lin & 7) * 64 + (lin >> 3);
    const int bh = swz >> 4;
    const int px = swz & 15;                 // complementary-pair index
    const int b = bh >> 4, h = bh & 15;
    const size_t bS = (size_t)b * S_;
    const int l15 = lane & 15, quad = lane >> 4;
    const int sb = w * 16;
    const float scale = 0.07216878364870323f;  // 192^-0.5

    // ---- staging descriptors: 10 coalesced 16B chunks per thread ----
    int gk[4], dk[6];          // kvb (K-nope): 4 chunks, 16 lanes/row (256 B)
#pragma unroll
    for (int i = 0; i < 4; ++i) {
        int F = i * 256 + tid;
        int n = F >> 4, cu = F & 15;
        gk[i] = (int)((bS + n) * 4096 + h * 256 + cu * 8);
        dk[i] = ((cu * 64 + n) * 16) ^ ((cu & 7) << 4);
    }
    int gr[2];                 // krb (k_rope): 2 chunks, 8 lanes/row (128 B)
#pragma unroll
    for (int i = 0; i < 2; ++i) {
        int F = i * 256 + tid;
        int n = F >> 3, cu = F & 7;
        gr[i] = (int)((bS + n) * 64 + cu * 8);
        dk[4 + i] = (((16 + cu) * 64 + n) * 16) ^ (cu << 4);
    }
    int gv[4], dv[4];          // vT (V): 4 chunks, 8 lanes/row (128 B)
#pragma unroll
    for (int i = 0; i < 4; ++i) {
        int F = i * 256 + tid;
        int vd = F >> 3, ku = F & 7;
        gv[i] = (int)(((size_t)bh * 128 + vd) * S_ + ku * 8);
        dv[i] = ((ku * 128 + vd) * 16) ^ (ku << 4);
    }

    bf16x8 ones_frag = {};
    if (l15 == 0) {
#pragma unroll
        for (int e = 0; e < 8; ++e) ones_frag[e] = (short)0x3F80;  // bf16 1.0
    }

    bf16x8 stg[10];
    auto stage_load = [&](int kb) {
#pragma unroll
        for (int c = 0; c < 4; ++c)
            stg[c] = *(const bf16x8*)(kvb + gk[c] + (size_t)kb * 4096);
#pragma unroll
        for (int c = 0; c < 2; ++c)
            stg[4 + c] = *(const bf16x8*)(krb + gr[c] + kb * 64);
#pragma unroll
        for (int c = 0; c < 4; ++c)
            stg[6 + c] = *(const bf16x8*)(vT + gv[c] + kb);
    };
    auto stage_write = [&]() {
#pragma unroll
        for (int c = 0; c < 6; ++c) *(bf16x8*)(Kf + dk[c]) = stg[c];
#pragma unroll
        for (int c = 0; c < 4; ++c) *(bf16x8*)(Vf + dv[c]) = stg[6 + c];
    };

#pragma unroll 1
    for (int hv = 0; hv < 2; ++hv) {
        const int qt = hv == 0 ? px : 31 - px;
        const int qbase = qt * 64;

        stage_load(0);   // tile-0 loads fly while we do Q-load + RoPE

        // ---- Q fragments with fused RoPE on dims 128..191 ----
        bf16x8 qf[6];
        {
            const ushort* qrow =
                q_bf + (bS + qbase + sb + l15) * (size_t)(H_ * Q_D_) + h * Q_D_;
#pragma unroll
            for (int ks = 0; ks < 4; ++ks)
                qf[ks] = *(const bf16x8*)(qrow + ks * 32 + quad * 8);
            bf16x8 q4 = *(const bf16x8*)(qrow + 128 + quad * 8);
            bf16x8 q5 = *(const bf16x8*)(qrow + 160 + quad * 8);
            const float* rc = rope_cache + (size_t)(qbase + sb + l15) * 128 + quad * 8;
            f32x4 c0l = *(const f32x4*)(rc + 0),  c0h = *(const f32x4*)(rc + 4);
            f32x4 c1l = *(const f32x4*)(rc + 32), c1h = *(const f32x4*)(rc + 36);
            f32x4 s0l = *(const f32x4*)(rc + 64), s0h = *(const f32x4*)(rc + 68);
            f32x4 s1l = *(const f32x4*)(rc + 96), s1h = *(const f32x4*)(rc + 100);
            bf16x8 o4, o5;
#pragma unroll
            for (int e = 0; e < 4; ++e) {
                float a4 = bf2f((ushort)q4[e]), b4 = bf2f((ushort)q4[e + 4]);
                float a5 = bf2f((ushort)q5[e]), b5 = bf2f((ushort)q5[e + 4]);
                o4[e]     = (short)f2bf(a4 * c0l[e] - a5 * s0l[e]);
                o4[e + 4] = (short)f2bf(b4 * c0h[e] - b5 * s0h[e]);
                o5[e]     = (short)f2bf(a5 * c1l[e] + a4 * s1l[e]);
                o5[e + 4] = (short)f2bf(b5 * c1h[e] + b4 * s1h[e]);
            }
            qf[4] = o4; qf[5] = o5;
        }

        f32x4 ov[8];
#pragma unroll
        for (int i = 0; i < 8; ++i) ov[i] = (f32x4){0.f, 0.f, 0.f, 0.f};
        f32x4 lsum = (f32x4){0.f, 0.f, 0.f, 0.f};
        float m_run[4];
#pragma unroll
        for (int i = 0; i < 4; ++i) m_run[i] = -3e38f;

        __syncthreads();           // WAR: prior readers of Kf/Vf done
        stage_write();             // vmcnt drain + ds_write tile 0
        __syncthreads();           // tile 0 visible

        for (int kt = 0; kt <= qt; ++kt) {
            const int kbase = kt * 64;
            if (kt < qt) stage_load(kbase + 64);   // prefetch next tile -> regs

            // ---- QK^T: 16x64 strip ----
            f32x4 sc[4];
#pragma unroll
            for (int nt = 0; nt < 4; ++nt) sc[nt] = (f32x4){0.f, 0.f, 0.f, 0.f};
            __builtin_amdgcn_s_setprio(1);
#pragma unroll
            for (int ks = 0; ks < 6; ++ks) {
                const int cg = ks * 4 + quad;
                bf16x8 a = qf[ks];
#pragma unroll
                for (int nt = 0; nt < 4; ++nt) {
                    bf16x8 bb = *(const bf16x8*)(Kf +
                        (((cg * 64 + nt * 16 + l15) * 16) ^ ((cg & 7) << 4)));
                    sc[nt] = __builtin_amdgcn_mfma_f32_16x16x32_bf16(a, bb, sc[nt], 0, 0, 0);
                }
            }
            __builtin_amdgcn_s_setprio(0);

            // ---- softmax (defer-max, THR = 8) ----
            const bool need_mask = (kbase + 63 > qbase + sb);
            float pv[4][4];
#pragma unroll
            for (int i = 0; i < 4; ++i) {
                int qrow_g = qbase + sb + quad * 4 + i;
                float sv[4];
                float mx = -3e38f;
#pragma unroll
                for (int nt = 0; nt < 4; ++nt) {
                    float v = sc[nt][i] * scale;
                    if (need_mask && (kbase + nt * 16 + l15) > qrow_g) v = -3e38f;
                    sv[nt] = v;
                    mx = fmaxf(mx, v);
                }
#pragma unroll
                for (int m = 1; m < 16; m <<= 1) mx = fmaxf(mx, __shfl_xor(mx, m, 64));
                if (!__all((int)(mx - m_run[i] <= 8.0f))) {
                    float mnew = fmaxf(mx, m_run[i]);
                    float alpha = __expf(m_run[i] - mnew);
                    m_run[i] = mnew;
                    lsum[i] *= alpha;
#pragma unroll
                    for (int nt2 = 0; nt2 < 8; ++nt2) ov[nt2][i] *= alpha;
                }
#pragma unroll
                for (int nt = 0; nt < 4; ++nt) pv[nt][i] = __expf(sv[nt] - m_run[i]);
            }

            // ---- P -> fragment-order LDS (own 16-row band only) ----
#pragma unroll
            for (int nt = 0; nt < 4; ++nt)
#pragma unroll
                for (int i = 0; i < 4; ++i) {
                    int c = nt * 16 + l15;
                    Pf[(size_t)(((c >> 5) * 4 + ((c >> 3) & 3)) * 64 + sb + quad * 4 + i) * 8 + (c & 7)]
                        = f2bf(pv[nt][i]);
                }

            // ---- PV (+ row-sum via ones-frag) ----
            __builtin_amdgcn_s_setprio(1);
#pragma unroll
            for (int ks2p = 0; ks2p < 2; ++ks2p) {
                const int cg2 = ks2p * 4 + quad;
                bf16x8 pa = *(const bf16x8*)&Pf[(size_t)((ks2p * 4 + quad) * 64 + sb + l15) * 8];
                lsum = __builtin_amdgcn_mfma_f32_16x16x32_bf16(pa, ones_frag, lsum, 0, 0, 0);
#pragma unroll
                for (int nt2 = 0; nt2 < 8; ++nt2) {
                    bf16x8 vb = *(const bf16x8*)(Vf +
                        (((cg2 * 128 + nt2 * 16 + l15) * 16) ^ (cg2 << 4)));
                    ov[nt2] = __builtin_amdgcn_mfma_f32_16x16x32_bf16(pa, vb, ov[nt2], 0, 0, 0);
                }
            }
            __builtin_amdgcn_s_setprio(0);

            __syncthreads();                 // all LDS readers done (WAR)
            if (kt < qt) stage_write();      // write prefetched tile
            __syncthreads();                 // next tile visible
        }

        // ---- epilogue: l lives in lanes l15==0 (col 0); broadcast in-quad ----
#pragma unroll
        for (int i = 0; i < 4; ++i) {
            float l = __shfl(lsum[i], lane & 48, 64);
            float inv = 1.0f / l;
            size_t base = (bS + qbase + sb + quad * 4 + i) * (size_t)(H_ * V_D_) + h * V_D_;
#pragma unroll
            for (int nt2 = 0; nt2 < 8; ++nt2)
                attn[base + nt2 * 16 + l15] = f2bf(ov[nt2][i] * inv);
        }
    }
}

// ============================================================================
// launch
// ============================================================================
extern "C" void kernel_launch(void* const* d_in, const int* in_sizes, int n_in,
                              void* d_out, int out_size, void* d_ws, size_t ws_size,
                              hipStream_t stream)
{
    const float* x          = (const float*)d_in[0];
    const float* rope_cache = (const float*)d_in[1];
    const float* wq         = (const float*)d_in[2];
    const float* wkva       = (const float*)d_in[3];
    const float* norm_w     = (const float*)d_in[4];
    const float* wkvb       = (const float*)d_in[5];
    const float* wo         = (const float*)d_in[6];
    float* out = (float*)d_out;

    char* p = (char*)d_ws;
    ushort* xb       = (ushort*)p; p += (size_t)BS_ * DIM_ * 2;
    ushort* q_bf     = (ushort*)p; p += (size_t)BS_ * H_ * Q_D_ * 2;
    float*  ckv      = (float*) p; p += (size_t)BS_ * CKV_P_ * 4;
    ushort* cnorm_bf = (ushort*)p; p += (size_t)BS_ * KV_LORA_ * 2;
    ushort* kvb      = (ushort*)p; p += (size_t)BS_ * 4096 * 2;
    ushort* attn_bf  = (ushort*)p; p += (size_t)BS_ * H_ * Q_D_ * 2;  // old qb slot
    ushort* krb      = (ushort*)p; p += (size_t)BS_ * ROPE_D_ * 2;
    ushort* vT       = (ushort*)p; p += (size_t)32 * 128 * S_ * 2;
    ushort* wq_bf    = (ushort*)p; p += (size_t)3072 * DIM_ * 2;
    ushort* wkva_bf  = (ushort*)p; p += (size_t)CKV_P_ * DIM_ * 2;
    ushort* wkvb_bf  = (ushort*)p; p += (size_t)4096 * KV_LORA_ * 2;
    ushort* wo_bf    = (ushort*)p; p += (size_t)DIM_ * 2048 * 2;

    dim3 blk(256);

    cast8<<<(BS_ * DIM_) / (8 * 256), blk, 0, stream>>>(x, xb);
    cast8<<<(3072 * DIM_) / (8 * 256), blk, 0, stream>>>(wq, wq_bf);
    cast_wkva_pad<<<(CKV_P_ * DIM_) / (8 * 256), blk, 0, stream>>>(wkva, wkva_bf);
    cast8<<<(4096 * KV_LORA_) / (8 * 256), blk, 0, stream>>>(wkvb, wkvb_bf);
    cast8<<<(DIM_ * 2048) / (8 * 256), blk, 0, stream>>>(wo, wo_bf);

    // 1. q_bf = x @ wq^T          (4096 x 3072 x 2048)
    gemm_bf16_t<1><<<dim3(3072 / 128, BS_ / 128), blk, 0, stream>>>(
        xb, wq_bf, q_bf, 3072, DIM_);
    // 2. ckv = x @ wkva^T         (4096 x 640 x 2048), fp32 out
    gemm_bf16_t<0><<<dim3(CKV_P_ / 128, BS_ / 128), blk, 0, stream>>>(
        xb, wkva_bf, ckv, CKV_P_, DIM_);
    // 3. cnorm_bf = rmsnorm(ckv[:, :512]) * norm_w
    rmsnorm_k<<<BS_ / 4, blk, 0, stream>>>(ckv, norm_w, cnorm_bf);
    // 4. krb = rope(ckv[:, 512:576])
    rope_cast_k<<<BS_ / 4, blk, 0, stream>>>(ckv, rope_cache, krb);
    // 5. kvb = cnorm @ wkvb^T     (4096 x 4096 x 512), bf16 out
    gemm_bf16_t<1><<<dim3(4096 / 128, BS_ / 128), blk, 0, stream>>>(
        cnorm_bf, wkvb_bf, kvb, 4096, KV_LORA_);
    // 6. vT = transpose(V part of kvb)
    transpose_v<<<dim3(S_ / 64, B_ * H_), blk, 0, stream>>>(kvb, vT);
    // 7. flash attention v3 (RoPE(q) fused) -> attn_bf
    mla_attn_mfma3<<<dim3(16, B_ * H_), blk, 0, stream>>>(
        q_bf, kvb, krb, vT, rope_cache, attn_bf);
    // 8. out = attn @ wo^T        (4096 x 2048 x 2048), fp32 out
    gemm_bf16_t<0><<<dim3(DIM_ / 128, BS_ / 128), blk, 0, stream>>>(
        attn_bf, wo_bf, out, DIM_, 2048);
}

// Round 2
// 566.305 us; speedup vs baseline: 1.1442x; 1.1442x over previous
//
#include <hip/hip_runtime.h>
#include <cstdint>
#include <cstddef>

// ---- problem constants ----
#define B_      2
#define S_      2048
#define DIM_    2048
#define H_      16
#define KV_LORA_ 512
#define NOPE_D_ 128
#define ROPE_D_ 64
#define V_D_    128
#define Q_D_    192          // NOPE_D + ROPE_D
#define EPS_    1e-6f
#define BS_     (B_ * S_)    // 4096 rows
#define CKV_P_  640          // ckv row pitch (576 padded to 5*128)

typedef __attribute__((ext_vector_type(8))) short bf16x8;
typedef __attribute__((ext_vector_type(4))) float f32x4;

__device__ __forceinline__ ushort f2bf(float f) {
    union { float f; uint32_t u; } v; v.f = f;
    uint32_t u = v.u + 0x7fff + ((v.u >> 16) & 1);  // RNE
    return (ushort)(u >> 16);
}
__device__ __forceinline__ float bf2f(ushort u) {
    union { uint32_t u; float f; } v; v.u = (uint32_t)u << 16; return v.f;
}
__device__ __forceinline__ void gll16(const void* g, void* l) {
    __builtin_amdgcn_global_load_lds(
        (const __attribute__((address_space(1))) unsigned int*)g,
        (__attribute__((address_space(3))) unsigned int*)l, 16, 0, 0);
}

// ============================================================================
// bf16 MFMA GEMM: C = A @ W^T.  (unchanged)
// ============================================================================
template <int OUT_BF16>
__global__ __launch_bounds__(256) void gemm_bf16_t(
    const ushort* __restrict__ A, const ushort* __restrict__ Bw,
    void* __restrict__ Cv, int N, int K)
{
    constexpr int BK = 64;
    __shared__ __align__(16) ushort Af[8192];   // 16 KB
    __shared__ __align__(16) ushort Bf[8192];   // 16 KB
    const int tid = threadIdx.x;
    const int lane = tid & 63;
    const int w = tid >> 6;
    const int l15 = lane & 15, quad = lane >> 4;
    const int m0 = blockIdx.y * 128;
    const int n0 = blockIdx.x * 128;
    const int wm0 = (w & 1) * 64, wn0 = (w >> 1) * 64;

    f32x4 acc[4][4];
#pragma unroll
    for (int i = 0; i < 4; ++i)
#pragma unroll
        for (int j = 0; j < 4; ++j) acc[i][j] = (f32x4){0.f, 0.f, 0.f, 0.f};

    const ushort* ap[4]; const ushort* bp[4];
    ushort* al[4]; ushort* bl[4];
#pragma unroll
    for (int t = 0; t < 4; ++t) {
        int ia = w * 4 + t;
        int kk = ia >> 3, q = (ia >> 1) & 3, mh = ia & 1;
        int koff = kk * 32 + q * 8;
        ap[t] = A  + (size_t)(m0 + mh * 64 + lane) * K + koff;
        bp[t] = Bw + (size_t)(n0 + mh * 64 + lane) * K + koff;
        al[t] = &Af[ia * 512];
        bl[t] = &Bf[ia * 512];
    }

    for (int k0 = 0; k0 < K; k0 += BK) {
        __syncthreads();
#pragma unroll
        for (int t = 0; t < 4; ++t) {
            gll16(ap[t], al[t]);
            gll16(bp[t], bl[t]);
            ap[t] += BK; bp[t] += BK;
        }
        __syncthreads();

        bf16x8 a0[4], a1[4], b0[4], b1[4];
#pragma unroll
        for (int i = 0; i < 4; ++i) {
            a0[i] = *(const bf16x8*)&Af[((0 + quad) * 128 + wm0 + i * 16 + l15) * 8];
            a1[i] = *(const bf16x8*)&Af[((4 + quad) * 128 + wm0 + i * 16 + l15) * 8];
            b0[i] = *(const bf16x8*)&Bf[((0 + quad) * 128 + wn0 + i * 16 + l15) * 8];
            b1[i] = *(const bf16x8*)&Bf[((4 + quad) * 128 + wn0 + i * 16 + l15) * 8];
        }
#pragma unroll
        for (int i = 0; i < 4; ++i)
#pragma unroll
            for (int j = 0; j < 4; ++j)
                acc[i][j] = __builtin_amdgcn_mfma_f32_16x16x32_bf16(a0[i], b0[j], acc[i][j], 0, 0, 0);
#pragma unroll
        for (int i = 0; i < 4; ++i)
#pragma unroll
            for (int j = 0; j < 4; ++j)
                acc[i][j] = __builtin_amdgcn_mfma_f32_16x16x32_bf16(a1[i], b1[j], acc[i][j], 0, 0, 0);
    }

#pragma unroll
    for (int i = 0; i < 4; ++i)
#pragma unroll
        for (int r = 0; r < 4; ++r) {
            size_t base = (size_t)(m0 + wm0 + i * 16 + quad * 4 + r) * N + n0 + wn0 + l15;
#pragma unroll
            for (int j = 0; j < 4; ++j) {
                float v = acc[i][j][r];
                if (OUT_BF16) ((ushort*)Cv)[base + j * 16] = f2bf(v);
                else          ((float*)Cv)[base + j * 16] = v;
            }
        }
}

// ============================================================================
// fp32 -> bf16 cast, 8 elems/thread (unchanged)
// ============================================================================
__global__ __launch_bounds__(256) void cast8(
    const float* __restrict__ s, ushort* __restrict__ d)
{
    size_t i = ((size_t)blockIdx.x * 256 + threadIdx.x) * 8;
    float4 a = *(const float4*)(s + i);
    float4 b = *(const float4*)(s + i + 4);
    ushort4 o0, o1;
    o0.x = f2bf(a.x); o0.y = f2bf(a.y); o0.z = f2bf(a.z); o0.w = f2bf(a.w);
    o1.x = f2bf(b.x); o1.y = f2bf(b.y); o1.z = f2bf(b.z); o1.w = f2bf(b.w);
    *(ushort4*)(d + i) = o0;
    *(ushort4*)(d + i + 4) = o1;
}

// wkva (576 x 2048) -> bf16 (640 x 2048), rows 576..639 zeroed (unchanged)
__global__ __launch_bounds__(256) void cast_wkva_pad(
    const float* __restrict__ s, ushort* __restrict__ d)
{
    size_t i = ((size_t)blockIdx.x * 256 + threadIdx.x) * 8;
    size_t row = i >> 11;   // /2048
    ushort4 o0 = {0,0,0,0}, o1 = {0,0,0,0};
    if (row < 576) {
        float4 a = *(const float4*)(s + i);
        float4 b = *(const float4*)(s + i + 4);
        o0.x = f2bf(a.x); o0.y = f2bf(a.y); o0.z = f2bf(a.z); o0.w = f2bf(a.w);
        o1.x = f2bf(b.x); o1.y = f2bf(b.y); o1.z = f2bf(b.z); o1.w = f2bf(b.w);
    }
    *(ushort4*)(d + i) = o0;
    *(ushort4*)(d + i + 4) = o1;
}

// ============================================================================
// RMSNorm over ckv[:, :512] (fp32, pitch 640) -> cnorm bf16 (unchanged)
// ============================================================================
__global__ __launch_bounds__(256) void rmsnorm_k(
    const float* __restrict__ ckv, const float* __restrict__ nw,
    ushort* __restrict__ cnorm)
{
    const int lane = threadIdx.x & 63;
    const int row = blockIdx.x * 4 + (threadIdx.x >> 6);
    const float* src = ckv + (size_t)row * CKV_P_;
    float4 a = *(const float4*)(src + lane * 4);
    float4 b = *(const float4*)(src + 256 + lane * 4);
    float ss = a.x*a.x + a.y*a.y + a.z*a.z + a.w*a.w
             + b.x*b.x + b.y*b.y + b.z*b.z + b.w*b.w;
#pragma unroll
    for (int off = 32; off > 0; off >>= 1) ss += __shfl_xor(ss, off, 64);
    float rs = rsqrtf(ss * (1.0f / 512.0f) + EPS_);
    float4 w0 = *(const float4*)(nw + lane * 4);
    float4 w1 = *(const float4*)(nw + 256 + lane * 4);
    ushort* dst = cnorm + (size_t)row * KV_LORA_;
    ushort4 o0, o1;
    o0.x = f2bf(a.x*rs*w0.x); o0.y = f2bf(a.y*rs*w0.y);
    o0.z = f2bf(a.z*rs*w0.z); o0.w = f2bf(a.w*rs*w0.w);
    o1.x = f2bf(b.x*rs*w1.x); o1.y = f2bf(b.y*rs*w1.y);
    o1.z = f2bf(b.z*rs*w1.z); o1.w = f2bf(b.w*rs*w1.w);
    *(ushort4*)(dst + lane * 4) = o0;
    *(ushort4*)(dst + 256 + lane * 4) = o1;
}

// ============================================================================
// RoPE k_rope from ckv fp32 (pitch 640, cols 512..575) -> krb bf16 (unchanged)
// ============================================================================
__global__ __launch_bounds__(256) void rope_cast_k(
    const float* __restrict__ ckv, const float* __restrict__ rope_cache,
    ushort* __restrict__ krb)
{
    const int lane = threadIdx.x & 63;
    const int w = blockIdx.x * 4 + (threadIdx.x >> 6);  // [0, BS)
    const int s = w & (S_ - 1);
    float v = ckv[(size_t)w * CKV_P_ + KV_LORA_ + lane];
    float other = __shfl_xor(v, 32, 64);
    float rot = (lane < 32) ? -other : other;
    float c  = rope_cache[s * (2 * ROPE_D_) + lane];
    float sn = rope_cache[s * (2 * ROPE_D_) + ROPE_D_ + lane];
    krb[(size_t)w * ROPE_D_ + lane] = f2bf(v * c + rot * sn);
}

// ============================================================================
// V transpose: kvb bf16 [bs][h*256 + 128 + c] -> vT [b*16+h][vd][s] (unchanged)
// ============================================================================
__global__ __launch_bounds__(256) void transpose_v(
    const ushort* __restrict__ kvb, ushort* __restrict__ vT)
{
    __shared__ ushort T[128][80];
    const int tid = threadIdx.x;
    const int bh = blockIdx.y;
    const int b = bh >> 4, h = bh & 15;
    const int sb = blockIdx.x * 64;
    const size_t rowbase = (size_t)b * S_ + sb;
#pragma unroll
    for (int it = 0; it < 4; ++it) {
        int f = tid + 256 * it;
        int r = f >> 4, c8 = (f & 15) * 8;
        bf16x8 v = *(const bf16x8*)(kvb + (rowbase + r) * 4096 + h * 256 + 128 + c8);
#pragma unroll
        for (int e = 0; e < 8; ++e) T[c8 + e][r] = (ushort)v[e];
    }
    __syncthreads();
#pragma unroll
    for (int it = 0; it < 4; ++it) {
        int f = tid + 256 * it;
        int vd = f >> 3, s8 = (f & 7) * 8;
        *(bf16x8*)(vT + ((size_t)bh * 128 + vd) * S_ + sb + s8) =
            *(const bf16x8*)&T[vd][s8];
    }
}

// ============================================================================
// MFMA flash attention v4.
//  - 8 waves (512 thr), q-tile 128 rows (wave w owns rows w*16..+15): one
//    K/V staging now feeds 8 waves (staging per unit compute halved vs v2).
//  - Staging via global_load_lds (NO staging VGPRs -> ~150 VGPR, fixes the
//    v3 occupancy cliff) into DOUBLE-BUFFERED fragment-order LDS:
//      Kf[2][ks(6)][quad(4)][n(64)][8]   (2 x 24 KB)
//      Vf[2][ks2(2)][quad(4)][n(128)][8] (2 x 16 KB)
//      Pf[ks2(2)][quad(4)][m(128)][8]    (16 KB)     total 96 KB
//    Prefetch of tile t+1 issued right after the barrier that published
//    tile t; the compute phase covers its (L2-hit) latency; one barrier/iter.
//  - Bijective XCD swizzle: 256 blocks, each XCD owns 4 consecutive bh
//    (~4.2 MB working set ~ L2-resident; kept from v3 where it cut
//    FETCH_SIZE 263->39 MB).
//  - RoPE(q) fused into Q-fragment load (verified in v3).
//  - defer-max (THR=8) + setprio(1) around MFMA clusters.
//  - Complementary pairing over 128-row q-tiles: block px does qt=px and
//    15-px => every block does exactly 34 K-iterations.
// ============================================================================
__global__ __launch_bounds__(512, 2) void mla_attn_mfma4(
    const ushort* __restrict__ q_bf, const ushort* __restrict__ kvb,
    const ushort* __restrict__ krb, const ushort* __restrict__ vT,
    const float* __restrict__ rope_cache, ushort* __restrict__ attn)
{
    __shared__ __align__(16) ushort Kf[2][24 * 64 * 8];   // 2 x 24 KB
    __shared__ __align__(16) ushort Vf[2][8 * 128 * 8];   // 2 x 16 KB
    __shared__ __align__(16) ushort Pf[8 * 128 * 8];      // 16 KB

    const int tid = threadIdx.x;
    const int lane = tid & 63;
    const int w = tid >> 6;                  // wave 0..7

    // XCD swizzle: 256 blocks; XCD k gets swz in [k*32,(k+1)*32) = 4 bh.
    const int lin = (int)blockIdx.y * 8 + (int)blockIdx.x;
    const int swz = (lin & 7) * 32 + (lin >> 3);
    const int bh = swz >> 3;
    const int px = swz & 7;                  // complementary-pair index
    const int b = bh >> 4, h = bh & 15;
    const size_t bS = (size_t)b * S_;
    const int l15 = lane & 15, quad = lane >> 4;
    const int sb = w * 16;                   // wave's q-row band (0..112)
    const float scale = 0.07216878364870323f;  // 192^-0.5

    bf16x8 ones_frag = {};
    if (l15 == 0) {
#pragma unroll
        for (int e = 0; e < 8; ++e) ones_frag[e] = (short)0x3F80;  // bf16 1.0
    }

    // stage one 64-row K/V tile into buffer bufi (wave w: 3 K + 2 V chunks)
    auto stage = [&](int kbase, int bufi) {
#pragma unroll
        for (int r = 0; r < 3; ++r) {
            int ia = w + r * 8;                       // 0..23
            int ks = ia >> 2, qc = ia & 3;
            ushort* dst = &Kf[bufi][ia * 512];
            const ushort* src = (ks < 4)
                ? kvb + (bS + kbase + lane) * 4096 + h * 256 + ks * 32 + qc * 8
                : krb + (bS + kbase + lane) * 64 + (ks - 4) * 32 + qc * 8;
            gll16(src, dst);
        }
#pragma unroll
        for (int r = 0; r < 2; ++r) {
            int ia2 = w + r * 8;                      // 0..15
            int ks2 = ia2 >> 3, qc = (ia2 >> 1) & 3, hh = ia2 & 1;
            ushort* dst = &Vf[bufi][ia2 * 512];
            const ushort* src =
                vT + ((size_t)bh * 128 + hh * 64 + lane) * S_ + kbase + ks2 * 32 + qc * 8;
            gll16(src, dst);
        }
    };

#pragma unroll 1
    for (int hv = 0; hv < 2; ++hv) {
        const int qt = hv == 0 ? px : 15 - px;
        const int qbase = qt * 128;
        const int nkt = 2 * qt + 2;          // 64-row K tiles for this q-tile

        stage(0, 0);                          // tile-0 DMA flies under Q+RoPE

        // ---- Q fragments with fused RoPE on dims 128..191 ----
        bf16x8 qf[6];
        {
            const ushort* qrow =
                q_bf + (bS + qbase + sb + l15) * (size_t)(H_ * Q_D_) + h * Q_D_;
#pragma unroll
            for (int ks = 0; ks < 4; ++ks)
                qf[ks] = *(const bf16x8*)(qrow + ks * 32 + quad * 8);
            bf16x8 q4 = *(const bf16x8*)(qrow + 128 + quad * 8);
            bf16x8 q5 = *(const bf16x8*)(qrow + 160 + quad * 8);
            const float* rc = rope_cache + (size_t)(qbase + sb + l15) * 128 + quad * 8;
            f32x4 c0l = *(const f32x4*)(rc + 0),  c0h = *(const f32x4*)(rc + 4);
            f32x4 c1l = *(const f32x4*)(rc + 32), c1h = *(const f32x4*)(rc + 36);
            f32x4 s0l = *(const f32x4*)(rc + 64), s0h = *(const f32x4*)(rc + 68);
            f32x4 s1l = *(const f32x4*)(rc + 96), s1h = *(const f32x4*)(rc + 100);
            bf16x8 o4, o5;
#pragma unroll
            for (int e = 0; e < 4; ++e) {
                float a4 = bf2f((ushort)q4[e]), b4 = bf2f((ushort)q4[e + 4]);
                float a5 = bf2f((ushort)q5[e]), b5 = bf2f((ushort)q5[e + 4]);
                o4[e]     = (short)f2bf(a4 * c0l[e] - a5 * s0l[e]);
                o4[e + 4] = (short)f2bf(b4 * c0h[e] - b5 * s0h[e]);
                o5[e]     = (short)f2bf(a5 * c1l[e] + a4 * s1l[e]);
                o5[e + 4] = (short)f2bf(b5 * c1h[e] + b4 * s1h[e]);
            }
            qf[4] = o4; qf[5] = o5;
        }

        f32x4 ov[8];
#pragma unroll
        for (int i = 0; i < 8; ++i) ov[i] = (f32x4){0.f, 0.f, 0.f, 0.f};
        f32x4 lsum = (f32x4){0.f, 0.f, 0.f, 0.f};
        float m_run[4];
#pragma unroll
        for (int i = 0; i < 4; ++i) m_run[i] = -3e38f;

        __syncthreads();                      // tile 0 visible

        for (int kt = 0; kt < nkt; ++kt) {
            const int kbase = kt * 64;
            const int cur = kt & 1;
            if (kt + 1 < nkt) stage((kt + 1) * 64, cur ^ 1);  // prefetch

            if (kbase <= qbase + sb + 15) {   // strip not fully masked
                // ---- QK^T: 16x64 strip ----
                f32x4 sc[4];
#pragma unroll
                for (int nt = 0; nt < 4; ++nt) sc[nt] = (f32x4){0.f, 0.f, 0.f, 0.f};
                __builtin_amdgcn_s_setprio(1);
#pragma unroll
                for (int ks = 0; ks < 6; ++ks) {
                    bf16x8 a = qf[ks];
#pragma unroll
                    for (int nt = 0; nt < 4; ++nt) {
                        bf16x8 bb = *(const bf16x8*)
                            &Kf[cur][((ks * 4 + quad) * 64 + nt * 16 + l15) * 8];
                        sc[nt] = __builtin_amdgcn_mfma_f32_16x16x32_bf16(a, bb, sc[nt], 0, 0, 0);
                    }
                }
                __builtin_amdgcn_s_setprio(0);

                // ---- softmax (defer-max, THR = 8) ----
                const bool need_mask = (kbase + 63 > qbase + sb);
                float pv[4][4];
#pragma unroll
                for (int i = 0; i < 4; ++i) {
                    int qrow_g = qbase + sb + quad * 4 + i;
                    float sv[4];
                    float mx = -3e38f;
#pragma unroll
                    for (int nt = 0; nt < 4; ++nt) {
                        float v = sc[nt][i] * scale;
                        if (need_mask && (kbase + nt * 16 + l15) > qrow_g) v = -3e38f;
                        sv[nt] = v;
                        mx = fmaxf(mx, v);
                    }
#pragma unroll
                    for (int m = 1; m < 16; m <<= 1) mx = fmaxf(mx, __shfl_xor(mx, m, 64));
                    if (!__all((int)(mx - m_run[i] <= 8.0f))) {
                        float mnew = fmaxf(mx, m_run[i]);
                        float alpha = __expf(m_run[i] - mnew);
                        m_run[i] = mnew;
                        lsum[i] *= alpha;
#pragma unroll
                        for (int nt2 = 0; nt2 < 8; ++nt2) ov[nt2][i] *= alpha;
                    }
#pragma unroll
                    for (int nt = 0; nt < 4; ++nt) pv[nt][i] = __expf(sv[nt] - m_run[i]);
                }

                // ---- P -> fragment-order LDS (own 16-row band only) ----
#pragma unroll
                for (int nt = 0; nt < 4; ++nt)
#pragma unroll
                    for (int i = 0; i < 4; ++i) {
                        int c = nt * 16 + l15;
                        Pf[(size_t)(((c >> 5) * 4 + ((c >> 3) & 3)) * 128 + sb + quad * 4 + i) * 8 + (c & 7)]
                            = f2bf(pv[nt][i]);
                    }

                // ---- PV (+ row-sum via ones-frag) ----
                __builtin_amdgcn_s_setprio(1);
#pragma unroll
                for (int ks2p = 0; ks2p < 2; ++ks2p) {
                    bf16x8 pa = *(const bf16x8*)
                        &Pf[(size_t)((ks2p * 4 + quad) * 128 + sb + l15) * 8];
                    lsum = __builtin_amdgcn_mfma_f32_16x16x32_bf16(pa, ones_frag, lsum, 0, 0, 0);
#pragma unroll
                    for (int nt2 = 0; nt2 < 8; ++nt2) {
                        bf16x8 vb = *(const bf16x8*)
                            &Vf[cur][((ks2p * 4 + quad) * 128 + nt2 * 16 + l15) * 8];
                        ov[nt2] = __builtin_amdgcn_mfma_f32_16x16x32_bf16(pa, vb, ov[nt2], 0, 0, 0);
                    }
                }
                __builtin_amdgcn_s_setprio(0);
            }

            __syncthreads();   // publish tile kt+1; WAR-protect buf cur^1
        }

        // ---- epilogue: l lives in lanes l15==0 (col 0); broadcast in-quad ----
#pragma unroll
        for (int i = 0; i < 4; ++i) {
            float l = __shfl(lsum[i], lane & 48, 64);
            float inv = 1.0f / l;
            size_t base = (bS + qbase + sb + quad * 4 + i) * (size_t)(H_ * V_D_) + h * V_D_;
#pragma unroll
            for (int nt2 = 0; nt2 < 8; ++nt2)
                attn[base + nt2 * 16 + l15] = f2bf(ov[nt2][i] * inv);
        }
    }
}

// ============================================================================
// launch
// ============================================================================
extern "C" void kernel_launch(void* const* d_in, const int* in_sizes, int n_in,
                              void* d_out, int out_size, void* d_ws, size_t ws_size,
                              hipStream_t stream)
{
    const float* x          = (const float*)d_in[0];
    const float* rope_cache = (const float*)d_in[1];
    const float* wq         = (const float*)d_in[2];
    const float* wkva       = (const float*)d_in[3];
    const float* norm_w     = (const float*)d_in[4];
    const float* wkvb       = (const float*)d_in[5];
    const float* wo         = (const float*)d_in[6];
    float* out = (float*)d_out;

    char* p = (char*)d_ws;
    ushort* xb       = (ushort*)p; p += (size_t)BS_ * DIM_ * 2;
    ushort* q_bf     = (ushort*)p; p += (size_t)BS_ * H_ * Q_D_ * 2;
    float*  ckv      = (float*) p; p += (size_t)BS_ * CKV_P_ * 4;
    ushort* cnorm_bf = (ushort*)p; p += (size_t)BS_ * KV_LORA_ * 2;
    ushort* kvb      = (ushort*)p; p += (size_t)BS_ * 4096 * 2;
    ushort* attn_bf  = (ushort*)p; p += (size_t)BS_ * H_ * Q_D_ * 2;
    ushort* krb      = (ushort*)p; p += (size_t)BS_ * ROPE_D_ * 2;
    ushort* vT       = (ushort*)p; p += (size_t)32 * 128 * S_ * 2;
    ushort* wq_bf    = (ushort*)p; p += (size_t)3072 * DIM_ * 2;
    ushort* wkva_bf  = (ushort*)p; p += (size_t)CKV_P_ * DIM_ * 2;
    ushort* wkvb_bf  = (ushort*)p; p += (size_t)4096 * KV_LORA_ * 2;
    ushort* wo_bf    = (ushort*)p; p += (size_t)DIM_ * 2048 * 2;

    dim3 blk(256);

    cast8<<<(BS_ * DIM_) / (8 * 256), blk, 0, stream>>>(x, xb);
    cast8<<<(3072 * DIM_) / (8 * 256), blk, 0, stream>>>(wq, wq_bf);
    cast_wkva_pad<<<(CKV_P_ * DIM_) / (8 * 256), blk, 0, stream>>>(wkva, wkva_bf);
    cast8<<<(4096 * KV_LORA_) / (8 * 256), blk, 0, stream>>>(wkvb, wkvb_bf);
    cast8<<<(DIM_ * 2048) / (8 * 256), blk, 0, stream>>>(wo, wo_bf);

    // 1. q_bf = x @ wq^T          (4096 x 3072 x 2048)
    gemm_bf16_t<1><<<dim3(3072 / 128, BS_ / 128), blk, 0, stream>>>(
        xb, wq_bf, q_bf, 3072, DIM_);
    // 2. ckv = x @ wkva^T         (4096 x 640 x 2048), fp32 out
    gemm_bf16_t<0><<<dim3(CKV_P_ / 128, BS_ / 128), blk, 0, stream>>>(
        xb, wkva_bf, ckv, CKV_P_, DIM_);
    // 3. cnorm_bf = rmsnorm(ckv[:, :512]) * norm_w
    rmsnorm_k<<<BS_ / 4, blk, 0, stream>>>(ckv, norm_w, cnorm_bf);
    // 4. krb = rope(ckv[:, 512:576])
    rope_cast_k<<<BS_ / 4, blk, 0, stream>>>(ckv, rope_cache, krb);
    // 5. kvb = cnorm @ wkvb^T     (4096 x 4096 x 512), bf16 out
    gemm_bf16_t<1><<<dim3(4096 / 128, BS_ / 128), blk, 0, stream>>>(
        cnorm_bf, wkvb_bf, kvb, 4096, KV_LORA_);
    // 6. vT = transpose(V part of kvb)
    transpose_v<<<dim3(S_ / 64, B_ * H_), blk, 0, stream>>>(kvb, vT);
    // 7. flash attention v4 (RoPE(q) fused) -> attn_bf
    mla_attn_mfma4<<<dim3(8, B_ * H_), dim3(512), 0, stream>>>(
        q_bf, kvb, krb, vT, rope_cache, attn_bf);
    // 8. out = attn @ wo^T        (4096 x 2048 x 2048), fp32 out
    gemm_bf16_t<0><<<dim3(DIM_ / 128, BS_ / 128), blk, 0, stream>>>(
        attn_bf, wo_bf, out, DIM_, 2048);
}

// Round 3
// 521.583 us; speedup vs baseline: 1.2423x; 1.0857x over previous
//
#include <hip/hip_runtime.h>
#include <cstdint>
#include <cstddef>

// ---- problem constants ----
#define B_      2
#define S_      2048
#define DIM_    2048
#define H_      16
#define KV_LORA_ 512
#define NOPE_D_ 128
#define ROPE_D_ 64
#define V_D_    128
#define Q_D_    192          // NOPE_D + ROPE_D
#define EPS_    1e-6f
#define BS_     (B_ * S_)    // 4096 rows
#define CKV_P_  640          // ckv row pitch (576 padded to 5*128)

typedef __attribute__((ext_vector_type(8))) short bf16x8;
typedef __attribute__((ext_vector_type(4))) float f32x4;
typedef __attribute__((ext_vector_type(16))) float f32x16;

__device__ __forceinline__ ushort f2bf(float f) {
    union { float f; uint32_t u; } v; v.f = f;
    uint32_t u = v.u + 0x7fff + ((v.u >> 16) & 1);  // RNE
    return (ushort)(u >> 16);
}
__device__ __forceinline__ float bf2f(ushort u) {
    union { uint32_t u; float f; } v; v.u = (uint32_t)u << 16; return v.f;
}
__device__ __forceinline__ void gll16(const void* g, void* l) {
    __builtin_amdgcn_global_load_lds(
        (const __attribute__((address_space(1))) unsigned int*)g,
        (__attribute__((address_space(3))) unsigned int*)l, 16, 0, 0);
}

// ============================================================================
// bf16 MFMA GEMM: C = A @ W^T.  (unchanged)
// ============================================================================
template <int OUT_BF16>
__global__ __launch_bounds__(256) void gemm_bf16_t(
    const ushort* __restrict__ A, const ushort* __restrict__ Bw,
    void* __restrict__ Cv, int N, int K)
{
    constexpr int BK = 64;
    __shared__ __align__(16) ushort Af[8192];   // 16 KB
    __shared__ __align__(16) ushort Bf[8192];   // 16 KB
    const int tid = threadIdx.x;
    const int lane = tid & 63;
    const int w = tid >> 6;
    const int l15 = lane & 15, quad = lane >> 4;
    const int m0 = blockIdx.y * 128;
    const int n0 = blockIdx.x * 128;
    const int wm0 = (w & 1) * 64, wn0 = (w >> 1) * 64;

    f32x4 acc[4][4];
#pragma unroll
    for (int i = 0; i < 4; ++i)
#pragma unroll
        for (int j = 0; j < 4; ++j) acc[i][j] = (f32x4){0.f, 0.f, 0.f, 0.f};

    const ushort* ap[4]; const ushort* bp[4];
    ushort* al[4]; ushort* bl[4];
#pragma unroll
    for (int t = 0; t < 4; ++t) {
        int ia = w * 4 + t;
        int kk = ia >> 3, q = (ia >> 1) & 3, mh = ia & 1;
        int koff = kk * 32 + q * 8;
        ap[t] = A  + (size_t)(m0 + mh * 64 + lane) * K + koff;
        bp[t] = Bw + (size_t)(n0 + mh * 64 + lane) * K + koff;
        al[t] = &Af[ia * 512];
        bl[t] = &Bf[ia * 512];
    }

    for (int k0 = 0; k0 < K; k0 += BK) {
        __syncthreads();
#pragma unroll
        for (int t = 0; t < 4; ++t) {
            gll16(ap[t], al[t]);
            gll16(bp[t], bl[t]);
            ap[t] += BK; bp[t] += BK;
        }
        __syncthreads();

        bf16x8 a0[4], a1[4], b0[4], b1[4];
#pragma unroll
        for (int i = 0; i < 4; ++i) {
            a0[i] = *(const bf16x8*)&Af[((0 + quad) * 128 + wm0 + i * 16 + l15) * 8];
            a1[i] = *(const bf16x8*)&Af[((4 + quad) * 128 + wm0 + i * 16 + l15) * 8];
            b0[i] = *(const bf16x8*)&Bf[((0 + quad) * 128 + wn0 + i * 16 + l15) * 8];
            b1[i] = *(const bf16x8*)&Bf[((4 + quad) * 128 + wn0 + i * 16 + l15) * 8];
        }
#pragma unroll
        for (int i = 0; i < 4; ++i)
#pragma unroll
            for (int j = 0; j < 4; ++j)
                acc[i][j] = __builtin_amdgcn_mfma_f32_16x16x32_bf16(a0[i], b0[j], acc[i][j], 0, 0, 0);
#pragma unroll
        for (int i = 0; i < 4; ++i)
#pragma unroll
            for (int j = 0; j < 4; ++j)
                acc[i][j] = __builtin_amdgcn_mfma_f32_16x16x32_bf16(a1[i], b1[j], acc[i][j], 0, 0, 0);
    }

#pragma unroll
    for (int i = 0; i < 4; ++i)
#pragma unroll
        for (int r = 0; r < 4; ++r) {
            size_t base = (size_t)(m0 + wm0 + i * 16 + quad * 4 + r) * N + n0 + wn0 + l15;
#pragma unroll
            for (int j = 0; j < 4; ++j) {
                float v = acc[i][j][r];
                if (OUT_BF16) ((ushort*)Cv)[base + j * 16] = f2bf(v);
                else          ((float*)Cv)[base + j * 16] = v;
            }
        }
}

// ============================================================================
// fp32 -> bf16 cast, 8 elems/thread (unchanged)
// ============================================================================
__global__ __launch_bounds__(256) void cast8(
    const float* __restrict__ s, ushort* __restrict__ d)
{
    size_t i = ((size_t)blockIdx.x * 256 + threadIdx.x) * 8;
    float4 a = *(const float4*)(s + i);
    float4 b = *(const float4*)(s + i + 4);
    ushort4 o0, o1;
    o0.x = f2bf(a.x); o0.y = f2bf(a.y); o0.z = f2bf(a.z); o0.w = f2bf(a.w);
    o1.x = f2bf(b.x); o1.y = f2bf(b.y); o1.z = f2bf(b.z); o1.w = f2bf(b.w);
    *(ushort4*)(d + i) = o0;
    *(ushort4*)(d + i + 4) = o1;
}

// wkva (576 x 2048) -> bf16 (640 x 2048), rows 576..639 zeroed (unchanged)
__global__ __launch_bounds__(256) void cast_wkva_pad(
    const float* __restrict__ s, ushort* __restrict__ d)
{
    size_t i = ((size_t)blockIdx.x * 256 + threadIdx.x) * 8;
    size_t row = i >> 11;   // /2048
    ushort4 o0 = {0,0,0,0}, o1 = {0,0,0,0};
    if (row < 576) {
        float4 a = *(const float4*)(s + i);
        float4 b = *(const float4*)(s + i + 4);
        o0.x = f2bf(a.x); o0.y = f2bf(a.y); o0.z = f2bf(a.z); o0.w = f2bf(a.w);
        o1.x = f2bf(b.x); o1.y = f2bf(b.y); o1.z = f2bf(b.z); o1.w = f2bf(b.w);
    }
    *(ushort4*)(d + i) = o0;
    *(ushort4*)(d + i + 4) = o1;
}

// ============================================================================
// Fused RMSNorm (ckv[:, :512] -> cnorm bf16) + RoPE-k (ckv[:, 512:576] -> krb)
// One wave per row.
// ============================================================================
__global__ __launch_bounds__(256) void rmsnorm_rope_k(
    const float* __restrict__ ckv, const float* __restrict__ nw,
    const float* __restrict__ rope_cache,
    ushort* __restrict__ cnorm, ushort* __restrict__ krb)
{
    const int lane = threadIdx.x & 63;
    const int row = blockIdx.x * 4 + (threadIdx.x >> 6);
    const float* src = ckv + (size_t)row * CKV_P_;
    float4 a = *(const float4*)(src + lane * 4);
    float4 b = *(const float4*)(src + 256 + lane * 4);
    float ss = a.x*a.x + a.y*a.y + a.z*a.z + a.w*a.w
             + b.x*b.x + b.y*b.y + b.z*b.z + b.w*b.w;
#pragma unroll
    for (int off = 32; off > 0; off >>= 1) ss += __shfl_xor(ss, off, 64);
    float rs = rsqrtf(ss * (1.0f / 512.0f) + EPS_);
    float4 w0 = *(const float4*)(nw + lane * 4);
    float4 w1 = *(const float4*)(nw + 256 + lane * 4);
    ushort* dst = cnorm + (size_t)row * KV_LORA_;
    ushort4 o0, o1;
    o0.x = f2bf(a.x*rs*w0.x); o0.y = f2bf(a.y*rs*w0.y);
    o0.z = f2bf(a.z*rs*w0.z); o0.w = f2bf(a.w*rs*w0.w);
    o1.x = f2bf(b.x*rs*w1.x); o1.y = f2bf(b.y*rs*w1.y);
    o1.z = f2bf(b.z*rs*w1.z); o1.w = f2bf(b.w*rs*w1.w);
    *(ushort4*)(dst + lane * 4) = o0;
    *(ushort4*)(dst + 256 + lane * 4) = o1;

    // RoPE on cols 512..575 of the same row
    float v = src[KV_LORA_ + lane];
    float other = __shfl_xor(v, 32, 64);
    float rot = (lane < 32) ? -other : other;
    int s = row & (S_ - 1);
    float c  = rope_cache[s * (2 * ROPE_D_) + lane];
    float sn = rope_cache[s * (2 * ROPE_D_) + ROPE_D_ + lane];
    krb[(size_t)row * ROPE_D_ + lane] = f2bf(v * c + rot * sn);
}

// ============================================================================
// In-place RoPE on q_bf cols 128..191.  One wave per (bs,h) row.
// ============================================================================
__global__ __launch_bounds__(256) void rope_q_inplace(
    ushort* __restrict__ q_bf, const float* __restrict__ rope_cache)
{
    const int lane = threadIdx.x & 63;
    const int wv = blockIdx.x * 4 + (threadIdx.x >> 6);  // [0, BS*H)
    const int bsr = wv >> 4;
    const int h = wv & 15;
    const int s = bsr & (S_ - 1);
    ushort* p = q_bf + (size_t)bsr * (H_ * Q_D_) + h * Q_D_ + 128;
    float v = bf2f(p[lane]);
    float other = __shfl_xor(v, 32, 64);
    float rot = (lane < 32) ? -other : other;
    float c  = rope_cache[s * (2 * ROPE_D_) + lane];
    float sn = rope_cache[s * (2 * ROPE_D_) + ROPE_D_ + lane];
    p[lane] = f2bf(v * c + rot * sn);
}

// ============================================================================
// V transpose: kvb bf16 [bs][h*256 + 128 + c] -> vT [b*16+h][vd][s] (unchanged)
// ============================================================================
__global__ __launch_bounds__(256) void transpose_v(
    const ushort* __restrict__ kvb, ushort* __restrict__ vT)
{
    __shared__ ushort T[128][80];
    const int tid = threadIdx.x;
    const int bh = blockIdx.y;
    const int b = bh >> 4, h = bh & 15;
    const int sb = blockIdx.x * 64;
    const size_t rowbase = (size_t)b * S_ + sb;
#pragma unroll
    for (int it = 0; it < 4; ++it) {
        int f = tid + 256 * it;
        int r = f >> 4, c8 = (f & 15) * 8;
        bf16x8 v = *(const bf16x8*)(kvb + (rowbase + r) * 4096 + h * 256 + 128 + c8);
#pragma unroll
        for (int e = 0; e < 8; ++e) T[c8 + e][r] = (ushort)v[e];
    }
    __syncthreads();
#pragma unroll
    for (int it = 0; it < 4; ++it) {
        int f = tid + 256 * it;
        int vd = f >> 3, s8 = (f & 7) * 8;
        *(bf16x8*)(vT + ((size_t)bh * 128 + vd) * S_ + sb + s8) =
            *(const bf16x8*)&T[vd][s8];
    }
}

// ============================================================================
// MFMA flash attention v5: 32x32 swapped-operand structure.
//  - 8 waves (512 thr).  q-tile 128 rows = 4 bands x 32 rows; wave w owns
//    band (w&3), k-half koff = (w>>2)*32 of each 64-row K tile (k-split).
//    Each wave runs an independent online softmax over its k-subsequence;
//    halves merged once per q-tile through LDS.
//  - Swapped MFMAs: S^T = mfma32(K, Q)  (thread owns ONE q-row = lane&31,
//    row-reduce = 1 shfl_xor(32)); O^T = mfma32(V^T, P^T).  P^T B-frags are
//    built IN-REGISTER from the S^T C-layout via 8 shfl_xor + selects —
//    no P LDS round-trip at all (was 16 ds_write + lgkm chain + 16 KB).
//    C-layout (m74/m101): col=lane&31, row=(r&3)+8*(r>>2)+4*(lane>>5).
//  - Staging: global_load_lds into double-buffered fragment-order LDS:
//      Kf[2][d8(24)][krow(64)][8]  2x24 KB,  Vf[2][s8(8)][vd(128)][8] 2x16 KB
//    = 80 KB total.  One barrier per K-iteration.
//  - XCD swizzle (kept from v3/v4: FETCH 263->34 MB), defer-max THR=8,
//    setprio around MFMA clusters, complementary q-tile pairing (34 iters).
// ============================================================================
__global__ __launch_bounds__(512, 2) void mla_attn_mfma5(
    const ushort* __restrict__ qb, const ushort* __restrict__ kvb,
    const ushort* __restrict__ krb, const ushort* __restrict__ vT,
    ushort* __restrict__ attn)
{
    __shared__ __align__(16) ushort LDSU[40960];   // 80 KB
    const int KFo[2] = {0, 12288};
    const int VFo[2] = {24576, 32768};

    const int tid = threadIdx.x;
    const int lane = tid & 63;
    const int w = tid >> 6;               // wave 0..7
    const int l31 = lane & 31, hi = lane >> 5;
    const int band = w & 3;               // 32-row q band
    const int koff = (w >> 2) * 32;       // k half of 64-row K tile

    // XCD swizzle: 256 blocks; XCD k gets swz in [k*32,(k+1)*32) = 4 bh.
    const int lin = (int)blockIdx.y * 8 + (int)blockIdx.x;
    const int swz = (lin & 7) * 32 + (lin >> 3);
    const int bh = swz >> 3;
    const int px = swz & 7;
    const int b = bh >> 4, h = bh & 15;
    const size_t bS = (size_t)b * S_;
    const float scale = 0.07216878364870323f;   // 192^-0.5

    // stage one 64-row K/V tile into buffer bufi (wave w: 3 K + 2 V chunks)
    auto stage = [&](int kbase, int bufi) {
#pragma unroll
        for (int r = 0; r < 3; ++r) {
            int c = w + r * 8;                 // 0..23 = d8
            ushort* dst = &LDSU[KFo[bufi] + (c * 64 + lane) * 8];
            const ushort* src = (c < 16)
                ? kvb + (bS + kbase + lane) * 4096 + h * 256 + c * 8
                : krb + (bS + kbase + lane) * 64 + (c - 16) * 8;
            gll16(src, dst);
        }
#pragma unroll
        for (int r = 0; r < 2; ++r) {
            int c = w + r * 8;                 // 0..15: s8 = c&7, vd-half = c>>3
            ushort* dst = &LDSU[VFo[bufi] + (((c & 7) * 128) + (c >> 3) * 64 + lane) * 8];
            const ushort* src =
                vT + ((size_t)bh * 128 + (c >> 3) * 64 + lane) * S_ + kbase + (c & 7) * 8;
            gll16(src, dst);
        }
    };

#pragma unroll 1
    for (int hv = 0; hv < 2; ++hv) {
        const int qt = hv ? 15 - px : px;
        const int qbase = qt * 128;
        const int nkt = 2 * qt + 2;
        const int bmin = qbase + band * 32;   // wave's first q row

        stage(0, 0);

        // Q B-frags: lane holds q-row = bmin+l31, d = c*16 + hi*8 + e
        bf16x8 qf[12];
        {
            const ushort* qrow = qb + (bS + bmin + l31) * (size_t)(H_ * Q_D_) + h * Q_D_;
#pragma unroll
            for (int c = 0; c < 12; ++c)
                qf[c] = *(const bf16x8*)(qrow + c * 16 + hi * 8);
        }

        f32x16 ov[4];
#pragma unroll
        for (int vt = 0; vt < 4; ++vt)
#pragma unroll
            for (int r = 0; r < 16; ++r) ov[vt][r] = 0.f;
        float m_run = -3e38f, lsum = 0.f;

        __syncthreads();                      // tile 0 visible

        for (int kt = 0; kt < nkt; ++kt) {
            const int kb = kt * 64;
            const int cur = kt & 1;
            if (kt + 1 < nkt) stage((kt + 1) * 64, cur ^ 1);

            const int kg = kb + koff;         // wave's 32-k strip start
            if (kg <= bmin + 31) {            // strip not fully masked
                // ---- S^T = K * Q : one 32x32 tile, K=192 ----
                f32x16 sc;
#pragma unroll
                for (int r = 0; r < 16; ++r) sc[r] = 0.f;
                __builtin_amdgcn_s_setprio(1);
#pragma unroll
                for (int c = 0; c < 12; ++c) {
                    bf16x8 kf = *(const bf16x8*)
                        &LDSU[KFo[cur] + ((c * 2 + hi) * 64 + koff + l31) * 8];
                    sc = __builtin_amdgcn_mfma_f32_32x32x16_bf16(kf, qf[c], sc, 0, 0, 0);
                }
                __builtin_amdgcn_s_setprio(0);

                // thread holds S[k = kg + crow(r,hi)][q = bmin + l31],
                // crow(r,hi) = (r&3) + 8*(r>>2) + 4*hi
                const bool need_mask = (kg == bmin);   // only diagonal strips
                float p[16]; float mx = -3e38f;
#pragma unroll
                for (int r = 0; r < 16; ++r) {
                    float v = sc[r] * scale;
                    if (need_mask) {
                        int kr = (r & 3) + 8 * (r >> 2) + 4 * hi;
                        if (kr > l31) v = -3e38f;
                    }
                    p[r] = v; mx = fmaxf(mx, v);
                }
                mx = fmaxf(mx, __shfl_xor(mx, 32, 64));   // full 64-k row max
                if (!__all(mx - m_run <= 8.0f)) {
                    float mn = fmaxf(mx, m_run);
                    float al = __expf(m_run - mn);
                    m_run = mn; lsum *= al;
#pragma unroll
                    for (int vt = 0; vt < 4; ++vt)
#pragma unroll
                        for (int r = 0; r < 16; ++r) ov[vt][r] *= al;
                }
                float s_loc = 0.f;
#pragma unroll
                for (int r = 0; r < 16; ++r) { p[r] = __expf(p[r] - m_run); s_loc += p[r]; }
                lsum += s_loc + __shfl_xor(s_loc, 32, 64);

                // ---- P^T B-frags in-register ----
                // pack pairs: w8[m] = bf16{p[2m], p[2m+1]}
                uint32_t w8[8];
#pragma unroll
                for (int m = 0; m < 8; ++m)
                    w8[m] = (uint32_t)f2bf(p[2 * m]) | ((uint32_t)f2bf(p[2 * m + 1]) << 16);
                // word j of chunk c = w8[4c + 2*hi_t + (j&1)] from lane-half (j>>1)
                bf16x8 pb[2];
#pragma unroll
                for (int c = 0; c < 2; ++c) {
                    uint32_t wd[4];
#pragma unroll
                    for (int par = 0; par < 2; ++par) {
                        uint32_t a  = w8[4 * c + par];
                        uint32_t bb = w8[4 * c + 2 + par];
                        uint32_t t  = __shfl_xor(bb, 32, 64);
                        uint32_t t2 = __shfl_xor(a, 32, 64);
                        wd[par]     = hi ? t : a;      // words 0,1 (from low half)
                        wd[par + 2] = hi ? bb : t2;    // words 2,3 (from high half)
                    }
                    union { uint32_t u[4]; bf16x8 v; } cvt;
                    cvt.u[0] = wd[0]; cvt.u[1] = wd[1]; cvt.u[2] = wd[2]; cvt.u[3] = wd[3];
                    pb[c] = cvt.v;
                }

                // ---- O^T += V^T * P^T ----
                __builtin_amdgcn_s_setprio(1);
#pragma unroll
                for (int vt = 0; vt < 4; ++vt)
#pragma unroll
                    for (int c = 0; c < 2; ++c) {
                        bf16x8 vf = *(const bf16x8*)
                            &LDSU[VFo[cur] + (((koff >> 3) + c * 2 + hi) * 128 + vt * 32 + l31) * 8];
                        ov[vt] = __builtin_amdgcn_mfma_f32_32x32x16_bf16(vf, pb[c], ov[vt], 0, 0, 0);
                    }
                __builtin_amdgcn_s_setprio(0);
            }
            __syncthreads();   // publish prefetched tile; WAR-protect buffers
        }

        // ---- merge the two k-halves of each band through LDS ----
        float* mrg = (float*)LDSU;   // [band][lane][68] floats  (~68 KB < 80 KB)
        if (w >= 4) {
            float* dst = mrg + (size_t)((w - 4) * 64 + lane) * 68;
#pragma unroll
            for (int vt = 0; vt < 4; ++vt)
#pragma unroll
                for (int g = 0; g < 4; ++g) {
                    f32x4 v4v = { ov[vt][g * 4 + 0], ov[vt][g * 4 + 1],
                                  ov[vt][g * 4 + 2], ov[vt][g * 4 + 3] };
                    *(f32x4*)(dst + vt * 16 + g * 4) = v4v;
                }
            dst[64] = m_run; dst[65] = lsum;
        }
        __syncthreads();
        if (w < 4) {
            const float* srcm = mrg + (size_t)(w * 64 + lane) * 68;
            float mB = srcm[64], lB = srcm[65];
            float M = fmaxf(m_run, mB);
            float eA = __expf(m_run - M), eB = __expf(mB - M);
            float L = lsum * eA + lB * eB;
            float inv = 1.0f / L;
            size_t obase = (bS + bmin + l31) * (size_t)(H_ * V_D_) + h * V_D_;
#pragma unroll
            for (int vt = 0; vt < 4; ++vt)
#pragma unroll
                for (int g = 0; g < 4; ++g) {
                    ushort4 o;
                    o.x = f2bf((ov[vt][g*4+0] * eA + srcm[vt*16+g*4+0] * eB) * inv);
                    o.y = f2bf((ov[vt][g*4+1] * eA + srcm[vt*16+g*4+1] * eB) * inv);
                    o.z = f2bf((ov[vt][g*4+2] * eA + srcm[vt*16+g*4+2] * eB) * inv);
                    o.w = f2bf((ov[vt][g*4+3] * eA + srcm[vt*16+g*4+3] * eB) * inv);
                    // vd = vt*32 + g*8 + hi*4 + {0..3}
                    *(ushort4*)(attn + obase + vt * 32 + g * 8 + hi * 4) = o;
                }
        }
        __syncthreads();   // merge reads done before next hv's stage(0,0)
    }
}

// ============================================================================
// launch
// ============================================================================
extern "C" void kernel_launch(void* const* d_in, const int* in_sizes, int n_in,
                              void* d_out, int out_size, void* d_ws, size_t ws_size,
                              hipStream_t stream)
{
    const float* x          = (const float*)d_in[0];
    const float* rope_cache = (const float*)d_in[1];
    const float* wq         = (const float*)d_in[2];
    const float* wkva       = (const float*)d_in[3];
    const float* norm_w     = (const float*)d_in[4];
    const float* wkvb       = (const float*)d_in[5];
    const float* wo         = (const float*)d_in[6];
    float* out = (float*)d_out;

    char* p = (char*)d_ws;
    ushort* xb       = (ushort*)p; p += (size_t)BS_ * DIM_ * 2;
    ushort* q_bf     = (ushort*)p; p += (size_t)BS_ * H_ * Q_D_ * 2;
    float*  ckv      = (float*) p; p += (size_t)BS_ * CKV_P_ * 4;
    ushort* cnorm_bf = (ushort*)p; p += (size_t)BS_ * KV_LORA_ * 2;
    ushort* kvb      = (ushort*)p; p += (size_t)BS_ * 4096 * 2;
    ushort* attn_bf  = (ushort*)p; p += (size_t)BS_ * H_ * Q_D_ * 2;
    ushort* krb      = (ushort*)p; p += (size_t)BS_ * ROPE_D_ * 2;
    ushort* vT       = (ushort*)p; p += (size_t)32 * 128 * S_ * 2;
    ushort* wq_bf    = (ushort*)p; p += (size_t)3072 * DIM_ * 2;
    ushort* wkva_bf  = (ushort*)p; p += (size_t)CKV_P_ * DIM_ * 2;
    ushort* wkvb_bf  = (ushort*)p; p += (size_t)4096 * KV_LORA_ * 2;
    ushort* wo_bf    = (ushort*)p; p += (size_t)DIM_ * 2048 * 2;

    dim3 blk(256);

    cast8<<<(BS_ * DIM_) / (8 * 256), blk, 0, stream>>>(x, xb);
    cast8<<<(3072 * DIM_) / (8 * 256), blk, 0, stream>>>(wq, wq_bf);
    cast_wkva_pad<<<(CKV_P_ * DIM_) / (8 * 256), blk, 0, stream>>>(wkva, wkva_bf);
    cast8<<<(4096 * KV_LORA_) / (8 * 256), blk, 0, stream>>>(wkvb, wkvb_bf);
    cast8<<<(DIM_ * 2048) / (8 * 256), blk, 0, stream>>>(wo, wo_bf);

    // 1. q_bf = x @ wq^T          (4096 x 3072 x 2048)
    gemm_bf16_t<1><<<dim3(3072 / 128, BS_ / 128), blk, 0, stream>>>(
        xb, wq_bf, q_bf, 3072, DIM_);
    // 2. ckv = x @ wkva^T         (4096 x 640 x 2048), fp32 out
    gemm_bf16_t<0><<<dim3(CKV_P_ / 128, BS_ / 128), blk, 0, stream>>>(
        xb, wkva_bf, ckv, CKV_P_, DIM_);
    // 3. cnorm + krb fused
    rmsnorm_rope_k<<<BS_ / 4, blk, 0, stream>>>(ckv, norm_w, rope_cache, cnorm_bf, krb);
    // 4. RoPE(q) in place
    rope_q_inplace<<<BS_ * H_ / 4, blk, 0, stream>>>(q_bf, rope_cache);
    // 5. kvb = cnorm @ wkvb^T     (4096 x 4096 x 512), bf16 out
    gemm_bf16_t<1><<<dim3(4096 / 128, BS_ / 128), blk, 0, stream>>>(
        cnorm_bf, wkvb_bf, kvb, 4096, KV_LORA_);
    // 6. vT = transpose(V part of kvb)
    transpose_v<<<dim3(S_ / 64, B_ * H_), blk, 0, stream>>>(kvb, vT);
    // 7. flash attention v5 -> attn_bf
    mla_attn_mfma5<<<dim3(8, B_ * H_), dim3(512), 0, stream>>>(
        q_bf, kvb, krb, vT, attn_bf);
    // 8. out = attn @ wo^T        (4096 x 2048 x 2048), fp32 out
    gemm_bf16_t<0><<<dim3(DIM_ / 128, BS_ / 128), blk, 0, stream>>>(
        attn_bf, wo_bf, out, DIM_, 2048);
}

// Round 4
// 502.227 us; speedup vs baseline: 1.2902x; 1.0385x over previous
//
#include <hip/hip_runtime.h>
#include <cstdint>
#include <cstddef>

// ---- problem constants ----
#define B_      2
#define S_      2048
#define DIM_    2048
#define H_      16
#define KV_LORA_ 512
#define NOPE_D_ 128
#define ROPE_D_ 64
#define V_D_    128
#define Q_D_    192          // NOPE_D + ROPE_D
#define EPS_    1e-6f
#define BS_     (B_ * S_)    // 4096 rows
#define CKV_P_  640          // ckv row pitch (576 padded to 5*128)

typedef __attribute__((ext_vector_type(8))) short bf16x8;
typedef __attribute__((ext_vector_type(4))) float f32x4;
typedef __attribute__((ext_vector_type(16))) float f32x16;

__device__ __forceinline__ ushort f2bf(float f) {
    union { float f; uint32_t u; } v; v.f = f;
    uint32_t u = v.u + 0x7fff + ((v.u >> 16) & 1);  // RNE
    return (ushort)(u >> 16);
}
__device__ __forceinline__ float bf2f(ushort u) {
    union { uint32_t u; float f; } v; v.u = (uint32_t)u << 16; return v.f;
}
__device__ __forceinline__ void gll16(const void* g, void* l) {
    __builtin_amdgcn_global_load_lds(
        (const __attribute__((address_space(1))) unsigned int*)g,
        (__attribute__((address_space(3))) unsigned int*)l, 16, 0, 0);
}

// ============================================================================
// 256x256 8-phase bf16 GEMM: C = A @ W^T   (m201-style template, plain HIP)
//  - 512 thr = 8 waves (4M x 2N), per-wave 64x128 output, BK=64.
//  - LDS 128 KB: L[buf2][A/B][kh2][quad4][row256][8] fragment-order
//    (16-lane-contiguous ds_read_b128 -> conflict-free, no swizzle needed).
//  - Phases = (kh, nh): q0 reads A(kh0)+B(kh0,lo), q1 B(kh0,hi),
//    q2 A(kh1)+B(kh1,lo), q3 B(kh1,hi); 16 MFMA each.
//  - Slot freed at phase p is restaged (for K-tile t+2, same buffer) at
//    phase p+1; B1(t+1) staged at q0 into the other buffer.  One half-tile
//    (2 gll16/thread) per phase => single boundary wait vmcnt(6), never 0.
//  - Raw s_barrier (no vmcnt drain), lgkmcnt(0)+sched_barrier before MFMA,
//    setprio(1) around MFMA cluster, XCD-bijective block swizzle.
//  - Tail: dummy stages (kt=0) keep the vmcnt arithmetic exact.
// ============================================================================
#define GQ_BARRIER()  __builtin_amdgcn_s_barrier()
#define GQ_LGKM0()    do { asm volatile("s_waitcnt lgkmcnt(0)" ::: "memory"); \
                           __builtin_amdgcn_sched_barrier(0); } while (0)

template <int OUT_BF16>
__global__ __launch_bounds__(512, 2) void gemm256_8ph(
    const ushort* __restrict__ A, const ushort* __restrict__ Bw,
    void* __restrict__ Cv, int N, int K, int nbx)
{
    __shared__ __align__(16) ushort L[2][2][2][4][256][8];   // 128 KB

    const int tid = threadIdx.x;
    const int lane = tid & 63;
    const int w = tid >> 6;
    const int l15 = lane & 15, quad = lane >> 4;

    // XCD-bijective swizzle (gridDim.x % 8 == 0 for all our shapes)
    const int nwg = (int)gridDim.x;
    const int cpx = nwg >> 3;
    const int lin = (int)blockIdx.x;
    const int swz = (lin & 7) * cpx + (lin >> 3);
    const int m0 = (swz / nbx) * 256;
    const int n0 = (swz % nbx) * 256;

    const int wm0 = (w & 3) * 64;     // wave M offset (4 M-frags)
    const int wn0 = (w >> 2) * 128;   // wave N offset (8 N-frags)

    const int NT = K >> 6;            // K-tiles (>= 2 for all our shapes)

    f32x4 acc[4][8];
#pragma unroll
    for (int i = 0; i < 4; ++i)
#pragma unroll
        for (int j = 0; j < 8; ++j) acc[i][j] = (f32x4){0.f, 0.f, 0.f, 0.f};

    // stage one 16 KB slot (ab, kh) of K-tile kt into buffer buf:
    // 16 chunks of 1 KB; wave w takes chunks w and w+8. 2 gll16 / thread.
    auto stage = [&](int ab, int kh, int kt, int buf) {
#pragma unroll
        for (int j = 0; j < 2; ++j) {
            int ci = w + j * 8;
            int qd = ci >> 2, rg = ci & 3;
            ushort* dst = &L[buf][ab][kh][qd][rg * 64 + lane][0];
            const ushort* src = (ab ? Bw + (size_t)(n0 + rg * 64 + lane) * K
                                    : A  + (size_t)(m0 + rg * 64 + lane) * K)
                                + kt * 64 + kh * 32 + qd * 8;
            gll16(src, dst);
        }
    };

    // ---- prologue: tile0 (A0,B0,A1,B1) + tile1 (A0,B0,A1) = 14 loads ----
    stage(0, 0, 0, 0); stage(1, 0, 0, 0); stage(0, 1, 0, 0); stage(1, 1, 0, 0);
    if (NT > 1) { stage(0, 0, 1, 1); stage(1, 0, 1, 1); stage(0, 1, 1, 1); }
    else        { stage(0, 0, 0, 1); stage(1, 0, 0, 1); stage(0, 1, 0, 1); }  // dummies
    asm volatile("s_waitcnt vmcnt(6)" ::: "memory");
    GQ_BARRIER();

    bf16x8 a[4], b[4];

    for (int t = 0; t < NT; ++t) {
        const int c = t & 1, o = c ^ 1;
        const int kt1 = (t + 1 < NT) ? t + 1 : 0;   // dummy-clamped
        const int kt2 = (t + 2 < NT) ? t + 2 : 0;

        // ---------- q0: (kh0, nh0) ----------
#pragma unroll
        for (int fm = 0; fm < 4; ++fm)
            a[fm] = *(const bf16x8*)&L[c][0][0][quad][wm0 + fm * 16 + l15][0];
#pragma unroll
        for (int fn = 0; fn < 4; ++fn)
            b[fn] = *(const bf16x8*)&L[c][1][0][quad][wn0 + fn * 16 + l15][0];
        stage(1, 1, kt1, o);              // B1(t+1) -> other buf (freed q3 prev)
        GQ_BARRIER();
        GQ_LGKM0();
        __builtin_amdgcn_s_setprio(1);
#pragma unroll
        for (int fm = 0; fm < 4; ++fm)
#pragma unroll
            for (int fn = 0; fn < 4; ++fn)
                acc[fm][fn] = __builtin_amdgcn_mfma_f32_16x16x32_bf16(a[fm], b[fn], acc[fm][fn], 0, 0, 0);
        __builtin_amdgcn_s_setprio(0);
        GQ_BARRIER();

        // ---------- q1: (kh0, nh1) ----------
#pragma unroll
        for (int fn = 0; fn < 4; ++fn)
            b[fn] = *(const bf16x8*)&L[c][1][0][quad][wn0 + 64 + fn * 16 + l15][0];
        stage(0, 0, kt2, c);              // A0(t+2) -> same buf (freed q0)
        GQ_BARRIER();
        GQ_LGKM0();
        __builtin_amdgcn_s_setprio(1);
#pragma unroll
        for (int fm = 0; fm < 4; ++fm)
#pragma unroll
            for (int fn = 0; fn < 4; ++fn)
                acc[fm][4 + fn] = __builtin_amdgcn_mfma_f32_16x16x32_bf16(a[fm], b[fn], acc[fm][4 + fn], 0, 0, 0);
        __builtin_amdgcn_s_setprio(0);
        GQ_BARRIER();

        // ---------- q2: (kh1, nh0) ----------
#pragma unroll
        for (int fm = 0; fm < 4; ++fm)
            a[fm] = *(const bf16x8*)&L[c][0][1][quad][wm0 + fm * 16 + l15][0];
#pragma unroll
        for (int fn = 0; fn < 4; ++fn)
            b[fn] = *(const bf16x8*)&L[c][1][1][quad][wn0 + fn * 16 + l15][0];
        stage(1, 0, kt2, c);              // B0(t+2) -> same buf (freed q1)
        GQ_BARRIER();
        GQ_LGKM0();
        __builtin_amdgcn_s_setprio(1);
#pragma unroll
        for (int fm = 0; fm < 4; ++fm)
#pragma unroll
            for (int fn = 0; fn < 4; ++fn)
                acc[fm][fn] = __builtin_amdgcn_mfma_f32_16x16x32_bf16(a[fm], b[fn], acc[fm][fn], 0, 0, 0);
        __builtin_amdgcn_s_setprio(0);
        GQ_BARRIER();

        // ---------- q3: (kh1, nh1) ----------
#pragma unroll
        for (int fn = 0; fn < 4; ++fn)
            b[fn] = *(const bf16x8*)&L[c][1][1][quad][wn0 + 64 + fn * 16 + l15][0];
        stage(0, 1, kt2, c);              // A1(t+2) -> same buf (freed q2)
        GQ_BARRIER();
        GQ_LGKM0();
        __builtin_amdgcn_s_setprio(1);
#pragma unroll
        for (int fm = 0; fm < 4; ++fm)
#pragma unroll
            for (int fn = 0; fn < 4; ++fn)
                acc[fm][4 + fn] = __builtin_amdgcn_mfma_f32_16x16x32_bf16(a[fm], b[fn], acc[fm][4 + fn], 0, 0, 0);
        __builtin_amdgcn_s_setprio(0);
        asm volatile("s_waitcnt vmcnt(6)" ::: "memory");   // next tile landed
        GQ_BARRIER();
    }

    // ---- epilogue ----
#pragma unroll
    for (int fm = 0; fm < 4; ++fm)
#pragma unroll
        for (int r = 0; r < 4; ++r) {
            size_t base = (size_t)(m0 + wm0 + fm * 16 + quad * 4 + r) * N + n0 + wn0 + l15;
#pragma unroll
            for (int fn = 0; fn < 8; ++fn) {
                float v = acc[fm][fn][r];
                if (OUT_BF16) ((ushort*)Cv)[base + fn * 16] = f2bf(v);
                else          ((float*)Cv)[base + fn * 16] = v;
            }
        }
}

// ============================================================================
// bf16 MFMA GEMM 128x128 (old structure) — kept for ckv (N=640)
// ============================================================================
template <int OUT_BF16>
__global__ __launch_bounds__(256) void gemm_bf16_t(
    const ushort* __restrict__ A, const ushort* __restrict__ Bw,
    void* __restrict__ Cv, int N, int K)
{
    constexpr int BK = 64;
    __shared__ __align__(16) ushort Af[8192];   // 16 KB
    __shared__ __align__(16) ushort Bf[8192];   // 16 KB
    const int tid = threadIdx.x;
    const int lane = tid & 63;
    const int w = tid >> 6;
    const int l15 = lane & 15, quad = lane >> 4;
    const int m0 = blockIdx.y * 128;
    const int n0 = blockIdx.x * 128;
    const int wm0 = (w & 1) * 64, wn0 = (w >> 1) * 64;

    f32x4 acc[4][4];
#pragma unroll
    for (int i = 0; i < 4; ++i)
#pragma unroll
        for (int j = 0; j < 4; ++j) acc[i][j] = (f32x4){0.f, 0.f, 0.f, 0.f};

    const ushort* ap[4]; const ushort* bp[4];
    ushort* al[4]; ushort* bl[4];
#pragma unroll
    for (int t = 0; t < 4; ++t) {
        int ia = w * 4 + t;
        int kk = ia >> 3, q = (ia >> 1) & 3, mh = ia & 1;
        int koff = kk * 32 + q * 8;
        ap[t] = A  + (size_t)(m0 + mh * 64 + lane) * K + koff;
        bp[t] = Bw + (size_t)(n0 + mh * 64 + lane) * K + koff;
        al[t] = &Af[ia * 512];
        bl[t] = &Bf[ia * 512];
    }

    for (int k0 = 0; k0 < K; k0 += BK) {
        __syncthreads();
#pragma unroll
        for (int t = 0; t < 4; ++t) {
            gll16(ap[t], al[t]);
            gll16(bp[t], bl[t]);
            ap[t] += BK; bp[t] += BK;
        }
        __syncthreads();

        bf16x8 a0[4], a1[4], b0[4], b1[4];
#pragma unroll
        for (int i = 0; i < 4; ++i) {
            a0[i] = *(const bf16x8*)&Af[((0 + quad) * 128 + wm0 + i * 16 + l15) * 8];
            a1[i] = *(const bf16x8*)&Af[((4 + quad) * 128 + wm0 + i * 16 + l15) * 8];
            b0[i] = *(const bf16x8*)&Bf[((0 + quad) * 128 + wn0 + i * 16 + l15) * 8];
            b1[i] = *(const bf16x8*)&Bf[((4 + quad) * 128 + wn0 + i * 16 + l15) * 8];
        }
#pragma unroll
        for (int i = 0; i < 4; ++i)
#pragma unroll
            for (int j = 0; j < 4; ++j)
                acc[i][j] = __builtin_amdgcn_mfma_f32_16x16x32_bf16(a0[i], b0[j], acc[i][j], 0, 0, 0);
#pragma unroll
        for (int i = 0; i < 4; ++i)
#pragma unroll
            for (int j = 0; j < 4; ++j)
                acc[i][j] = __builtin_amdgcn_mfma_f32_16x16x32_bf16(a1[i], b1[j], acc[i][j], 0, 0, 0);
    }

#pragma unroll
    for (int i = 0; i < 4; ++i)
#pragma unroll
        for (int r = 0; r < 4; ++r) {
            size_t base = (size_t)(m0 + wm0 + i * 16 + quad * 4 + r) * N + n0 + wn0 + l15;
#pragma unroll
            for (int j = 0; j < 4; ++j) {
                float v = acc[i][j][r];
                if (OUT_BF16) ((ushort*)Cv)[base + j * 16] = f2bf(v);
                else          ((float*)Cv)[base + j * 16] = v;
            }
        }
}

// ============================================================================
// fp32 -> bf16 cast, 8 elems/thread (unchanged)
// ============================================================================
__global__ __launch_bounds__(256) void cast8(
    const float* __restrict__ s, ushort* __restrict__ d)
{
    size_t i = ((size_t)blockIdx.x * 256 + threadIdx.x) * 8;
    float4 a = *(const float4*)(s + i);
    float4 b = *(const float4*)(s + i + 4);
    ushort4 o0, o1;
    o0.x = f2bf(a.x); o0.y = f2bf(a.y); o0.z = f2bf(a.z); o0.w = f2bf(a.w);
    o1.x = f2bf(b.x); o1.y = f2bf(b.y); o1.z = f2bf(b.z); o1.w = f2bf(b.w);
    *(ushort4*)(d + i) = o0;
    *(ushort4*)(d + i + 4) = o1;
}

// wkva (576 x 2048) -> bf16 (640 x 2048), rows 576..639 zeroed (unchanged)
__global__ __launch_bounds__(256) void cast_wkva_pad(
    const float* __restrict__ s, ushort* __restrict__ d)
{
    size_t i = ((size_t)blockIdx.x * 256 + threadIdx.x) * 8;
    size_t row = i >> 11;   // /2048
    ushort4 o0 = {0,0,0,0}, o1 = {0,0,0,0};
    if (row < 576) {
        float4 a = *(const float4*)(s + i);
        float4 b = *(const float4*)(s + i + 4);
        o0.x = f2bf(a.x); o0.y = f2bf(a.y); o0.z = f2bf(a.z); o0.w = f2bf(a.w);
        o1.x = f2bf(b.x); o1.y = f2bf(b.y); o1.z = f2bf(b.z); o1.w = f2bf(b.w);
    }
    *(ushort4*)(d + i) = o0;
    *(ushort4*)(d + i + 4) = o1;
}

// ============================================================================
// Fused RMSNorm + RoPE-k (unchanged)
// ============================================================================
__global__ __launch_bounds__(256) void rmsnorm_rope_k(
    const float* __restrict__ ckv, const float* __restrict__ nw,
    const float* __restrict__ rope_cache,
    ushort* __restrict__ cnorm, ushort* __restrict__ krb)
{
    const int lane = threadIdx.x & 63;
    const int row = blockIdx.x * 4 + (threadIdx.x >> 6);
    const float* src = ckv + (size_t)row * CKV_P_;
    float4 a = *(const float4*)(src + lane * 4);
    float4 b = *(const float4*)(src + 256 + lane * 4);
    float ss = a.x*a.x + a.y*a.y + a.z*a.z + a.w*a.w
             + b.x*b.x + b.y*b.y + b.z*b.z + b.w*b.w;
#pragma unroll
    for (int off = 32; off > 0; off >>= 1) ss += __shfl_xor(ss, off, 64);
    float rs = rsqrtf(ss * (1.0f / 512.0f) + EPS_);
    float4 w0 = *(const float4*)(nw + lane * 4);
    float4 w1 = *(const float4*)(nw + 256 + lane * 4);
    ushort* dst = cnorm + (size_t)row * KV_LORA_;
    ushort4 o0, o1;
    o0.x = f2bf(a.x*rs*w0.x); o0.y = f2bf(a.y*rs*w0.y);
    o0.z = f2bf(a.z*rs*w0.z); o0.w = f2bf(a.w*rs*w0.w);
    o1.x = f2bf(b.x*rs*w1.x); o1.y = f2bf(b.y*rs*w1.y);
    o1.z = f2bf(b.z*rs*w1.z); o1.w = f2bf(b.w*rs*w1.w);
    *(ushort4*)(dst + lane * 4) = o0;
    *(ushort4*)(dst + 256 + lane * 4) = o1;

    float v = src[KV_LORA_ + lane];
    float other = __shfl_xor(v, 32, 64);
    float rot = (lane < 32) ? -other : other;
    int s = row & (S_ - 1);
    float c  = rope_cache[s * (2 * ROPE_D_) + lane];
    float sn = rope_cache[s * (2 * ROPE_D_) + ROPE_D_ + lane];
    krb[(size_t)row * ROPE_D_ + lane] = f2bf(v * c + rot * sn);
}

// ============================================================================
// In-place RoPE on q_bf cols 128..191 (unchanged)
// ============================================================================
__global__ __launch_bounds__(256) void rope_q_inplace(
    ushort* __restrict__ q_bf, const float* __restrict__ rope_cache)
{
    const int lane = threadIdx.x & 63;
    const int wv = blockIdx.x * 4 + (threadIdx.x >> 6);  // [0, BS*H)
    const int bsr = wv >> 4;
    const int h = wv & 15;
    const int s = bsr & (S_ - 1);
    ushort* p = q_bf + (size_t)bsr * (H_ * Q_D_) + h * Q_D_ + 128;
    float v = bf2f(p[lane]);
    float other = __shfl_xor(v, 32, 64);
    float rot = (lane < 32) ? -other : other;
    float c  = rope_cache[s * (2 * ROPE_D_) + lane];
    float sn = rope_cache[s * (2 * ROPE_D_) + ROPE_D_ + lane];
    p[lane] = f2bf(v * c + rot * sn);
}

// ============================================================================
// V transpose (unchanged)
// ============================================================================
__global__ __launch_bounds__(256) void transpose_v(
    const ushort* __restrict__ kvb, ushort* __restrict__ vT)
{
    __shared__ ushort T[128][80];
    const int tid = threadIdx.x;
    const int bh = blockIdx.y;
    const int b = bh >> 4, h = bh & 15;
    const int sb = blockIdx.x * 64;
    const size_t rowbase = (size_t)b * S_ + sb;
#pragma unroll
    for (int it = 0; it < 4; ++it) {
        int f = tid + 256 * it;
        int r = f >> 4, c8 = (f & 15) * 8;
        bf16x8 v = *(const bf16x8*)(kvb + (rowbase + r) * 4096 + h * 256 + 128 + c8);
#pragma unroll
        for (int e = 0; e < 8; ++e) T[c8 + e][r] = (ushort)v[e];
    }
    __syncthreads();
#pragma unroll
    for (int it = 0; it < 4; ++it) {
        int f = tid + 256 * it;
        int vd = f >> 3, s8 = (f & 7) * 8;
        *(bf16x8*)(vT + ((size_t)bh * 128 + vd) * S_ + sb + s8) =
            *(const bf16x8*)&T[vd][s8];
    }
}

// ============================================================================
// MFMA flash attention v5 (unchanged from round 3 — passed)
// ============================================================================
__global__ __launch_bounds__(512, 2) void mla_attn_mfma5(
    const ushort* __restrict__ qb, const ushort* __restrict__ kvb,
    const ushort* __restrict__ krb, const ushort* __restrict__ vT,
    ushort* __restrict__ attn)
{
    __shared__ __align__(16) ushort LDSU[40960];   // 80 KB
    const int KFo[2] = {0, 12288};
    const int VFo[2] = {24576, 32768};

    const int tid = threadIdx.x;
    const int lane = tid & 63;
    const int w = tid >> 6;               // wave 0..7
    const int l31 = lane & 31, hi = lane >> 5;
    const int band = w & 3;               // 32-row q band
    const int koff = (w >> 2) * 32;       // k half of 64-row K tile

    const int lin = (int)blockIdx.y * 8 + (int)blockIdx.x;
    const int swz = (lin & 7) * 32 + (lin >> 3);
    const int bh = swz >> 3;
    const int px = swz & 7;
    const int b = bh >> 4, h = bh & 15;
    const size_t bS = (size_t)b * S_;
    const float scale = 0.07216878364870323f;   // 192^-0.5

    auto stage = [&](int kbase, int bufi) {
#pragma unroll
        for (int r = 0; r < 3; ++r) {
            int c = w + r * 8;                 // 0..23 = d8
            ushort* dst = &LDSU[KFo[bufi] + (c * 64 + lane) * 8];
            const ushort* src = (c < 16)
                ? kvb + (bS + kbase + lane) * 4096 + h * 256 + c * 8
                : krb + (bS + kbase + lane) * 64 + (c - 16) * 8;
            gll16(src, dst);
        }
#pragma unroll
        for (int r = 0; r < 2; ++r) {
            int c = w + r * 8;                 // 0..15: s8 = c&7, vd-half = c>>3
            ushort* dst = &LDSU[VFo[bufi] + (((c & 7) * 128) + (c >> 3) * 64 + lane) * 8];
            const ushort* src =
                vT + ((size_t)bh * 128 + (c >> 3) * 64 + lane) * S_ + kbase + (c & 7) * 8;
            gll16(src, dst);
        }
    };

#pragma unroll 1
    for (int hv = 0; hv < 2; ++hv) {
        const int qt = hv ? 15 - px : px;
        const int qbase = qt * 128;
        const int nkt = 2 * qt + 2;
        const int bmin = qbase + band * 32;   // wave's first q row

        stage(0, 0);

        bf16x8 qf[12];
        {
            const ushort* qrow = qb + (bS + bmin + l31) * (size_t)(H_ * Q_D_) + h * Q_D_;
#pragma unroll
            for (int c = 0; c < 12; ++c)
                qf[c] = *(const bf16x8*)(qrow + c * 16 + hi * 8);
        }

        f32x16 ov[4];
#pragma unroll
        for (int vt = 0; vt < 4; ++vt)
#pragma unroll
            for (int r = 0; r < 16; ++r) ov[vt][r] = 0.f;
        float m_run = -3e38f, lsum = 0.f;

        __syncthreads();                      // tile 0 visible

        for (int kt = 0; kt < nkt; ++kt) {
            const int kb = kt * 64;
            const int cur = kt & 1;
            if (kt + 1 < nkt) stage((kt + 1) * 64, cur ^ 1);

            const int kg = kb + koff;         // wave's 32-k strip start
            if (kg <= bmin + 31) {            // strip not fully masked
                f32x16 sc;
#pragma unroll
                for (int r = 0; r < 16; ++r) sc[r] = 0.f;
                __builtin_amdgcn_s_setprio(1);
#pragma unroll
                for (int c = 0; c < 12; ++c) {
                    bf16x8 kf = *(const bf16x8*)
                        &LDSU[KFo[cur] + ((c * 2 + hi) * 64 + koff + l31) * 8];
                    sc = __builtin_amdgcn_mfma_f32_32x32x16_bf16(kf, qf[c], sc, 0, 0, 0);
                }
                __builtin_amdgcn_s_setprio(0);

                const bool need_mask = (kg == bmin);   // only diagonal strips
                float p[16]; float mx = -3e38f;
#pragma unroll
                for (int r = 0; r < 16; ++r) {
                    float v = sc[r] * scale;
                    if (need_mask) {
                        int kr = (r & 3) + 8 * (r >> 2) + 4 * hi;
                        if (kr > l31) v = -3e38f;
                    }
                    p[r] = v; mx = fmaxf(mx, v);
                }
                mx = fmaxf(mx, __shfl_xor(mx, 32, 64));   // full 64-k row max
                if (!__all(mx - m_run <= 8.0f)) {
                    float mn = fmaxf(mx, m_run);
                    float al = __expf(m_run - mn);
                    m_run = mn; lsum *= al;
#pragma unroll
                    for (int vt = 0; vt < 4; ++vt)
#pragma unroll
                        for (int r = 0; r < 16; ++r) ov[vt][r] *= al;
                }
                float s_loc = 0.f;
#pragma unroll
                for (int r = 0; r < 16; ++r) { p[r] = __expf(p[r] - m_run); s_loc += p[r]; }
                lsum += s_loc + __shfl_xor(s_loc, 32, 64);

                uint32_t w8[8];
#pragma unroll
                for (int m = 0; m < 8; ++m)
                    w8[m] = (uint32_t)f2bf(p[2 * m]) | ((uint32_t)f2bf(p[2 * m + 1]) << 16);
                bf16x8 pb[2];
#pragma unroll
                for (int c = 0; c < 2; ++c) {
                    uint32_t wd[4];
#pragma unroll
                    for (int par = 0; par < 2; ++par) {
                        uint32_t a  = w8[4 * c + par];
                        uint32_t bb = w8[4 * c + 2 + par];
                        uint32_t t  = __shfl_xor(bb, 32, 64);
                        uint32_t t2 = __shfl_xor(a, 32, 64);
                        wd[par]     = hi ? t : a;
                        wd[par + 2] = hi ? bb : t2;
                    }
                    union { uint32_t u[4]; bf16x8 v; } cvt;
                    cvt.u[0] = wd[0]; cvt.u[1] = wd[1]; cvt.u[2] = wd[2]; cvt.u[3] = wd[3];
                    pb[c] = cvt.v;
                }

                __builtin_amdgcn_s_setprio(1);
#pragma unroll
                for (int vt = 0; vt < 4; ++vt)
#pragma unroll
                    for (int c = 0; c < 2; ++c) {
                        bf16x8 vf = *(const bf16x8*)
                            &LDSU[VFo[cur] + (((koff >> 3) + c * 2 + hi) * 128 + vt * 32 + l31) * 8];
                        ov[vt] = __builtin_amdgcn_mfma_f32_32x32x16_bf16(vf, pb[c], ov[vt], 0, 0, 0);
                    }
                __builtin_amdgcn_s_setprio(0);
            }
            __syncthreads();   // publish prefetched tile; WAR-protect buffers
        }

        float* mrg = (float*)LDSU;
        if (w >= 4) {
            float* dst = mrg + (size_t)((w - 4) * 64 + lane) * 68;
#pragma unroll
            for (int vt = 0; vt < 4; ++vt)
#pragma unroll
                for (int g = 0; g < 4; ++g) {
                    f32x4 v4v = { ov[vt][g * 4 + 0], ov[vt][g * 4 + 1],
                                  ov[vt][g * 4 + 2], ov[vt][g * 4 + 3] };
                    *(f32x4*)(dst + vt * 16 + g * 4) = v4v;
                }
            dst[64] = m_run; dst[65] = lsum;
        }
        __syncthreads();
        if (w < 4) {
            const float* srcm = mrg + (size_t)(w * 64 + lane) * 68;
            float mB = srcm[64], lB = srcm[65];
            float M = fmaxf(m_run, mB);
            float eA = __expf(m_run - M), eB = __expf(mB - M);
            float L = lsum * eA + lB * eB;
            float inv = 1.0f / L;
            size_t obase = (bS + bmin + l31) * (size_t)(H_ * V_D_) + h * V_D_;
#pragma unroll
            for (int vt = 0; vt < 4; ++vt)
#pragma unroll
                for (int g = 0; g < 4; ++g) {
                    ushort4 o;
                    o.x = f2bf((ov[vt][g*4+0] * eA + srcm[vt*16+g*4+0] * eB) * inv);
                    o.y = f2bf((ov[vt][g*4+1] * eA + srcm[vt*16+g*4+1] * eB) * inv);
                    o.z = f2bf((ov[vt][g*4+2] * eA + srcm[vt*16+g*4+2] * eB) * inv);
                    o.w = f2bf((ov[vt][g*4+3] * eA + srcm[vt*16+g*4+3] * eB) * inv);
                    *(ushort4*)(attn + obase + vt * 32 + g * 8 + hi * 4) = o;
                }
        }
        __syncthreads();
    }
}

// ============================================================================
// launch
// ============================================================================
extern "C" void kernel_launch(void* const* d_in, const int* in_sizes, int n_in,
                              void* d_out, int out_size, void* d_ws, size_t ws_size,
                              hipStream_t stream)
{
    const float* x          = (const float*)d_in[0];
    const float* rope_cache = (const float*)d_in[1];
    const float* wq         = (const float*)d_in[2];
    const float* wkva       = (const float*)d_in[3];
    const float* norm_w     = (const float*)d_in[4];
    const float* wkvb       = (const float*)d_in[5];
    const float* wo         = (const float*)d_in[6];
    float* out = (float*)d_out;

    char* p = (char*)d_ws;
    ushort* xb       = (ushort*)p; p += (size_t)BS_ * DIM_ * 2;
    ushort* q_bf     = (ushort*)p; p += (size_t)BS_ * H_ * Q_D_ * 2;
    float*  ckv      = (float*) p; p += (size_t)BS_ * CKV_P_ * 4;
    ushort* cnorm_bf = (ushort*)p; p += (size_t)BS_ * KV_LORA_ * 2;
    ushort* kvb      = (ushort*)p; p += (size_t)BS_ * 4096 * 2;
    ushort* attn_bf  = (ushort*)p; p += (size_t)BS_ * H_ * Q_D_ * 2;
    ushort* krb      = (ushort*)p; p += (size_t)BS_ * ROPE_D_ * 2;
    ushort* vT       = (ushort*)p; p += (size_t)32 * 128 * S_ * 2;
    ushort* wq_bf    = (ushort*)p; p += (size_t)3072 * DIM_ * 2;
    ushort* wkva_bf  = (ushort*)p; p += (size_t)CKV_P_ * DIM_ * 2;
    ushort* wkvb_bf  = (ushort*)p; p += (size_t)4096 * KV_LORA_ * 2;
    ushort* wo_bf    = (ushort*)p; p += (size_t)DIM_ * 2048 * 2;

    dim3 blk(256);

    cast8<<<(BS_ * DIM_) / (8 * 256), blk, 0, stream>>>(x, xb);
    cast8<<<(3072 * DIM_) / (8 * 256), blk, 0, stream>>>(wq, wq_bf);
    cast_wkva_pad<<<(CKV_P_ * DIM_) / (8 * 256), blk, 0, stream>>>(wkva, wkva_bf);
    cast8<<<(4096 * KV_LORA_) / (8 * 256), blk, 0, stream>>>(wkvb, wkvb_bf);
    cast8<<<(DIM_ * 2048) / (8 * 256), blk, 0, stream>>>(wo, wo_bf);

    // 1. q_bf = x @ wq^T          (4096 x 3072 x 2048), 256^2 8-phase
    gemm256_8ph<1><<<dim3((3072 / 256) * (BS_ / 256)), dim3(512), 0, stream>>>(
        xb, wq_bf, q_bf, 3072, DIM_, 3072 / 256);
    // 2. ckv = x @ wkva^T         (4096 x 640 x 2048), fp32 out, old kernel
    gemm_bf16_t<0><<<dim3(CKV_P_ / 128, BS_ / 128), blk, 0, stream>>>(
        xb, wkva_bf, ckv, CKV_P_, DIM_);
    // 3. cnorm + krb fused
    rmsnorm_rope_k<<<BS_ / 4, blk, 0, stream>>>(ckv, norm_w, rope_cache, cnorm_bf, krb);
    // 4. RoPE(q) in place
    rope_q_inplace<<<BS_ * H_ / 4, blk, 0, stream>>>(q_bf, rope_cache);
    // 5. kvb = cnorm @ wkvb^T     (4096 x 4096 x 512), bf16 out, 256^2 8-phase
    gemm256_8ph<1><<<dim3((4096 / 256) * (BS_ / 256)), dim3(512), 0, stream>>>(
        cnorm_bf, wkvb_bf, kvb, 4096, KV_LORA_, 4096 / 256);
    // 6. vT = transpose(V part of kvb)
    transpose_v<<<dim3(S_ / 64, B_ * H_), blk, 0, stream>>>(kvb, vT);
    // 7. flash attention v5 -> attn_bf
    mla_attn_mfma5<<<dim3(8, B_ * H_), dim3(512), 0, stream>>>(
        q_bf, kvb, krb, vT, attn_bf);
    // 8. out = attn @ wo^T        (4096 x 2048 x 2048), fp32 out, 256^2 8-phase
    gemm256_8ph<0><<<dim3((2048 / 256) * (BS_ / 256)), dim3(512), 0, stream>>>(
        attn_bf, wo_bf, out, DIM_, 2048, 2048 / 256);
}

// Round 6
// 417.349 us; speedup vs baseline: 1.5526x; 1.2034x over previous
//
#include <hip/hip_runtime.h>
#include <cstdint>
#include <cstddef>

// ---- problem constants ----
#define B_      2
#define S_      2048
#define DIM_    2048
#define H_      16
#define KV_LORA_ 512
#define NOPE_D_ 128
#define ROPE_D_ 64
#define V_D_    128
#define Q_D_    192          // NOPE_D + ROPE_D
#define EPS_    1e-6f
#define BS_     (B_ * S_)    // 4096 rows
#define CKV_P_  768          // ckv row pitch (576 real cols, padded to 768)

typedef __attribute__((ext_vector_type(8))) short bf16x8;
typedef __attribute__((ext_vector_type(4))) float f32x4;
typedef __attribute__((ext_vector_type(16))) float f32x16;

__device__ __forceinline__ ushort f2bf(float f) {
    union { float f; uint32_t u; } v; v.f = f;
    uint32_t u = v.u + 0x7fff + ((v.u >> 16) & 1);  // RNE
    return (ushort)(u >> 16);
}
__device__ __forceinline__ float bf2f(ushort u) {
    union { uint32_t u; float f; } v; v.u = (uint32_t)u << 16; return v.f;
}
__device__ __forceinline__ void gll16(const void* g, void* l) {
    __builtin_amdgcn_global_load_lds(
        (const __attribute__((address_space(1))) unsigned int*)g,
        (__attribute__((address_space(3))) unsigned int*)l, 16, 0, 0);
}

#define GQ_BARRIER()  __builtin_amdgcn_s_barrier()
#define GQ_LGKM0()    do { asm volatile("s_waitcnt lgkmcnt(0)" ::: "memory"); \
                           __builtin_amdgcn_sched_barrier(0); } while (0)

// ============================================================================
// 256x256 8-phase bf16 GEMM (proven round 4).  MODE: 0=f32 out pitch N,
// 1=bf16 out pitch N, 2=split (cols<3072 -> bf16 Cv pitch 3072; else f32 Cv2
// pitch 768 at col-3072) for the fused q-proj + ckv GEMM.
// ============================================================================
template <int MODE>
__global__ __launch_bounds__(512, 2) void gemm256_8ph(
    const ushort* __restrict__ A, const ushort* __restrict__ Bw,
    void* __restrict__ Cv, void* __restrict__ Cv2, int N, int K, int nbx)
{
    __shared__ __align__(16) ushort L[2][2][2][4][256][8];   // 128 KB

    const int tid = threadIdx.x;
    const int lane = tid & 63;
    const int w = tid >> 6;
    const int l15 = lane & 15, quad = lane >> 4;

    // XCD-bijective swizzle (gridDim.x % 8 == 0 for all our shapes)
    const int nwg = (int)gridDim.x;
    const int cpx = nwg >> 3;
    const int lin = (int)blockIdx.x;
    const int swz = (lin & 7) * cpx + (lin >> 3);
    const int m0 = (swz / nbx) * 256;
    const int n0 = (swz % nbx) * 256;

    const int wm0 = (w & 3) * 64;     // wave M offset (4 M-frags)
    const int wn0 = (w >> 2) * 128;   // wave N offset (8 N-frags)

    const int NT = K >> 6;            // K-tiles (>= 2 for all our shapes)

    f32x4 acc[4][8];
#pragma unroll
    for (int i = 0; i < 4; ++i)
#pragma unroll
        for (int j = 0; j < 8; ++j) acc[i][j] = (f32x4){0.f, 0.f, 0.f, 0.f};

    // stage one 16 KB slot (ab, kh) of K-tile kt into buffer buf
    auto stage = [&](int ab, int kh, int kt, int buf) {
#pragma unroll
        for (int j = 0; j < 2; ++j) {
            int ci = w + j * 8;
            int qd = ci >> 2, rg = ci & 3;
            ushort* dst = &L[buf][ab][kh][qd][rg * 64 + lane][0];
            const ushort* src = (ab ? Bw + (size_t)(n0 + rg * 64 + lane) * K
                                    : A  + (size_t)(m0 + rg * 64 + lane) * K)
                                + kt * 64 + kh * 32 + qd * 8;
            gll16(src, dst);
        }
    };

    // ---- prologue: tile0 (A0,B0,A1,B1) + tile1 (A0,B0,A1) = 14 loads ----
    stage(0, 0, 0, 0); stage(1, 0, 0, 0); stage(0, 1, 0, 0); stage(1, 1, 0, 0);
    if (NT > 1) { stage(0, 0, 1, 1); stage(1, 0, 1, 1); stage(0, 1, 1, 1); }
    else        { stage(0, 0, 0, 1); stage(1, 0, 0, 1); stage(0, 1, 0, 1); }
    asm volatile("s_waitcnt vmcnt(6)" ::: "memory");
    GQ_BARRIER();

    bf16x8 a[4], b[4];

    for (int t = 0; t < NT; ++t) {
        const int c = t & 1, o = c ^ 1;
        const int kt1 = (t + 1 < NT) ? t + 1 : 0;
        const int kt2 = (t + 2 < NT) ? t + 2 : 0;

        // ---------- q0: (kh0, nh0) ----------
#pragma unroll
        for (int fm = 0; fm < 4; ++fm)
            a[fm] = *(const bf16x8*)&L[c][0][0][quad][wm0 + fm * 16 + l15][0];
#pragma unroll
        for (int fn = 0; fn < 4; ++fn)
            b[fn] = *(const bf16x8*)&L[c][1][0][quad][wn0 + fn * 16 + l15][0];
        stage(1, 1, kt1, o);
        GQ_BARRIER();
        GQ_LGKM0();
        __builtin_amdgcn_s_setprio(1);
#pragma unroll
        for (int fm = 0; fm < 4; ++fm)
#pragma unroll
            for (int fn = 0; fn < 4; ++fn)
                acc[fm][fn] = __builtin_amdgcn_mfma_f32_16x16x32_bf16(a[fm], b[fn], acc[fm][fn], 0, 0, 0);
        __builtin_amdgcn_s_setprio(0);
        GQ_BARRIER();

        // ---------- q1: (kh0, nh1) ----------
#pragma unroll
        for (int fn = 0; fn < 4; ++fn)
            b[fn] = *(const bf16x8*)&L[c][1][0][quad][wn0 + 64 + fn * 16 + l15][0];
        stage(0, 0, kt2, c);
        GQ_BARRIER();
        GQ_LGKM0();
        __builtin_amdgcn_s_setprio(1);
#pragma unroll
        for (int fm = 0; fm < 4; ++fm)
#pragma unroll
            for (int fn = 0; fn < 4; ++fn)
                acc[fm][4 + fn] = __builtin_amdgcn_mfma_f32_16x16x32_bf16(a[fm], b[fn], acc[fm][4 + fn], 0, 0, 0);
        __builtin_amdgcn_s_setprio(0);
        GQ_BARRIER();

        // ---------- q2: (kh1, nh0) ----------
#pragma unroll
        for (int fm = 0; fm < 4; ++fm)
            a[fm] = *(const bf16x8*)&L[c][0][1][quad][wm0 + fm * 16 + l15][0];
#pragma unroll
        for (int fn = 0; fn < 4; ++fn)
            b[fn] = *(const bf16x8*)&L[c][1][1][quad][wn0 + fn * 16 + l15][0];
        stage(1, 0, kt2, c);
        GQ_BARRIER();
        GQ_LGKM0();
        __builtin_amdgcn_s_setprio(1);
#pragma unroll
        for (int fm = 0; fm < 4; ++fm)
#pragma unroll
            for (int fn = 0; fn < 4; ++fn)
                acc[fm][fn] = __builtin_amdgcn_mfma_f32_16x16x32_bf16(a[fm], b[fn], acc[fm][fn], 0, 0, 0);
        __builtin_amdgcn_s_setprio(0);
        GQ_BARRIER();

        // ---------- q3: (kh1, nh1) ----------
#pragma unroll
        for (int fn = 0; fn < 4; ++fn)
            b[fn] = *(const bf16x8*)&L[c][1][1][quad][wn0 + 64 + fn * 16 + l15][0];
        stage(0, 1, kt2, c);
        GQ_BARRIER();
        GQ_LGKM0();
        __builtin_amdgcn_s_setprio(1);
#pragma unroll
        for (int fm = 0; fm < 4; ++fm)
#pragma unroll
            for (int fn = 0; fn < 4; ++fn)
                acc[fm][4 + fn] = __builtin_amdgcn_mfma_f32_16x16x32_bf16(a[fm], b[fn], acc[fm][4 + fn], 0, 0, 0);
        __builtin_amdgcn_s_setprio(0);
        asm volatile("s_waitcnt vmcnt(6)" ::: "memory");
        GQ_BARRIER();
    }

    // ---- epilogue ----
#pragma unroll
    for (int fm = 0; fm < 4; ++fm)
#pragma unroll
        for (int r = 0; r < 4; ++r) {
            int row = m0 + wm0 + fm * 16 + quad * 4 + r;
            if (MODE == 2) {
                if (n0 < 3072) {
                    size_t base = (size_t)row * 3072 + n0 + wn0 + l15;
#pragma unroll
                    for (int fn = 0; fn < 8; ++fn)
                        ((ushort*)Cv)[base + fn * 16] = f2bf(acc[fm][fn][r]);
                } else {
                    size_t base = (size_t)row * CKV_P_ + (n0 - 3072) + wn0 + l15;
#pragma unroll
                    for (int fn = 0; fn < 8; ++fn)
                        ((float*)Cv2)[base + fn * 16] = acc[fm][fn][r];
                }
            } else {
                size_t base = (size_t)row * N + n0 + wn0 + l15;
#pragma unroll
                for (int fn = 0; fn < 8; ++fn) {
                    float v = acc[fm][fn][r];
                    if (MODE == 1) ((ushort*)Cv)[base + fn * 16] = f2bf(v);
                    else           ((float*)Cv)[base + fn * 16] = v;
                }
            }
        }
}

// ============================================================================
// 256x128-tile GEMM, 2 phases/K-tile, counted-vmcnt pipeline (for wo:
// N=2048 gives 256 blocks = full machine).  8 waves (4M x 2N), per-wave
// 64x64, acc[4][4].  LDS 96 KB.  ph0 stages A1(t+1),B(t+1) -> other buf;
// ph1 stages A0(t+2) -> same buf.  Single vmcnt(2) per K-tile. Never 0.
// ============================================================================
template <int OUT_BF16>
__global__ __launch_bounds__(512, 2) void gemm_bn128(
    const ushort* __restrict__ A, const ushort* __restrict__ Bw,
    void* __restrict__ Cv, int N, int K, int nbx)
{
    __shared__ __align__(16) ushort LA[2][2][4][256][8];   // 64 KB
    __shared__ __align__(16) ushort LB[2][2][4][128][8];   // 32 KB

    const int tid = threadIdx.x;
    const int lane = tid & 63;
    const int w = tid >> 6;
    const int l15 = lane & 15, quad = lane >> 4;

    const int nwg = (int)gridDim.x;
    const int cpx = nwg >> 3;
    const int lin = (int)blockIdx.x;
    const int swz = (lin & 7) * cpx + (lin >> 3);
    const int m0 = (swz / nbx) * 256;
    const int n0 = (swz % nbx) * 128;

    const int wm0 = (w & 3) * 64;
    const int wn0 = (w >> 2) * 64;

    const int NT = K >> 6;

    f32x4 acc[4][4];
#pragma unroll
    for (int i = 0; i < 4; ++i)
#pragma unroll
        for (int j = 0; j < 4; ++j) acc[i][j] = (f32x4){0.f, 0.f, 0.f, 0.f};

    auto stageA = [&](int kh, int kt, int buf) {
#pragma unroll
        for (int j = 0; j < 2; ++j) {
            int ci = w + j * 8;
            int qd = ci >> 2, rg = ci & 3;
            ushort* dst = &LA[buf][kh][qd][rg * 64 + lane][0];
            const ushort* src = A + (size_t)(m0 + rg * 64 + lane) * K
                                + kt * 64 + kh * 32 + qd * 8;
            gll16(src, dst);
        }
    };
    auto stageB = [&](int kt, int buf) {
#pragma unroll
        for (int j = 0; j < 2; ++j) {
            int ci = w + j * 8;
            int kh = ci >> 3, qd = (ci >> 1) & 3, rh = ci & 1;
            ushort* dst = &LB[buf][kh][qd][rh * 64 + lane][0];
            const ushort* src = Bw + (size_t)(n0 + rh * 64 + lane) * K
                                + kt * 64 + kh * 32 + qd * 8;
            gll16(src, dst);
        }
    };

    // ---- prologue: tile0 {A0,A1,B} + A0(tile1) = 8 loads ----
    stageA(0, 0, 0); stageA(1, 0, 0); stageB(0, 0);
    stageA(0, (NT > 1) ? 1 : 0, 1);
    asm volatile("s_waitcnt vmcnt(2)" ::: "memory");
    GQ_BARRIER();

    bf16x8 a[4], b[4];

    for (int t = 0; t < NT; ++t) {
        const int c = t & 1, o = c ^ 1;
        const int kt1 = (t + 1 < NT) ? t + 1 : 0;
        const int kt2 = (t + 2 < NT) ? t + 2 : 0;

        // ---------- ph0 (kh0) ----------
#pragma unroll
        for (int fm = 0; fm < 4; ++fm)
            a[fm] = *(const bf16x8*)&LA[c][0][quad][wm0 + fm * 16 + l15][0];
#pragma unroll
        for (int fn = 0; fn < 4; ++fn)
            b[fn] = *(const bf16x8*)&LB[c][0][quad][wn0 + fn * 16 + l15][0];
        stageA(1, kt1, o); stageB(kt1, o);
        GQ_BARRIER();
        GQ_LGKM0();
        __builtin_amdgcn_s_setprio(1);
#pragma unroll
        for (int fm = 0; fm < 4; ++fm)
#pragma unroll
            for (int fn = 0; fn < 4; ++fn)
                acc[fm][fn] = __builtin_amdgcn_mfma_f32_16x16x32_bf16(a[fm], b[fn], acc[fm][fn], 0, 0, 0);
        __builtin_amdgcn_s_setprio(0);
        GQ_BARRIER();

        // ---------- ph1 (kh1) ----------
#pragma unroll
        for (int fm = 0; fm < 4; ++fm)
            a[fm] = *(const bf16x8*)&LA[c][1][quad][wm0 + fm * 16 + l15][0];
#pragma unroll
        for (int fn = 0; fn < 4; ++fn)
            b[fn] = *(const bf16x8*)&LB[c][1][quad][wn0 + fn * 16 + l15][0];
        stageA(0, kt2, c);
        GQ_BARRIER();
        GQ_LGKM0();
        __builtin_amdgcn_s_setprio(1);
#pragma unroll
        for (int fm = 0; fm < 4; ++fm)
#pragma unroll
            for (int fn = 0; fn < 4; ++fn)
                acc[fm][fn] = __builtin_amdgcn_mfma_f32_16x16x32_bf16(a[fm], b[fn], acc[fm][fn], 0, 0, 0);
        __builtin_amdgcn_s_setprio(0);
        asm volatile("s_waitcnt vmcnt(2)" ::: "memory");   // tile t+1 landed
        GQ_BARRIER();
    }

    // ---- epilogue ----
#pragma unroll
    for (int fm = 0; fm < 4; ++fm)
#pragma unroll
        for (int r = 0; r < 4; ++r) {
            size_t base = (size_t)(m0 + wm0 + fm * 16 + quad * 4 + r) * N + n0 + wn0 + l15;
#pragma unroll
            for (int fn = 0; fn < 4; ++fn) {
                float v = acc[fm][fn][r];
                if (OUT_BF16) ((ushort*)Cv)[base + fn * 16] = f2bf(v);
                else          ((float*)Cv)[base + fn * 16] = v;
            }
        }
}

// ============================================================================
// Fused cast kernel: x->xb, wq->wc[0:3072], wkva->wc[3072:3648],
// zeros->wc[3648:3840], wkvb->wkvb_bf, wo->wo_bf.   8 elems/thread.
// Segment boundaries (elems): 8388608 / 14680064 / 15859712 / 16252928 /
// 18350080 / 22544384.  Grid = 22544384/8/256 = 11008 blocks.
// ============================================================================
__global__ __launch_bounds__(256) void cast_all(
    const float* __restrict__ x, const float* __restrict__ wq,
    const float* __restrict__ wkva, const float* __restrict__ wkvb,
    const float* __restrict__ wo,
    ushort* __restrict__ xb, ushort* __restrict__ wc,
    ushort* __restrict__ wkvb_bf, ushort* __restrict__ wo_bf)
{
    size_t i = ((size_t)blockIdx.x * 256 + threadIdx.x) * 8;
    const float* s; ushort* d;
    if (i < 8388608)        { s = x + i;                  d = xb + i; }
    else if (i < 14680064)  { s = wq + (i - 8388608);     d = wc + (i - 8388608); }
    else if (i < 15859712)  { s = wkva + (i - 14680064);  d = wc + (i - 8388608); }
    else if (i < 16252928)  {   // zero pad rows 3648..3839 of wc
        ushort4 z = {0, 0, 0, 0};
        ushort* dz = wc + (i - 8388608);
        *(ushort4*)dz = z; *(ushort4*)(dz + 4) = z;
        return;
    }
    else if (i < 18350080)  { s = wkvb + (i - 16252928);  d = wkvb_bf + (i - 16252928); }
    else                    { s = wo + (i - 18350080);    d = wo_bf + (i - 18350080); }
    float4 a = *(const float4*)s;
    float4 b = *(const float4*)(s + 4);
    ushort4 o0, o1;
    o0.x = f2bf(a.x); o0.y = f2bf(a.y); o0.z = f2bf(a.z); o0.w = f2bf(a.w);
    o1.x = f2bf(b.x); o1.y = f2bf(b.y); o1.z = f2bf(b.z); o1.w = f2bf(b.w);
    *(ushort4*)d = o0;
    *(ushort4*)(d + 4) = o1;
}

// ============================================================================
// Fused RMSNorm (ckv[:, :512] -> cnorm bf16) + RoPE-k (ckv[:, 512:576] -> krb)
// pitch CKV_P_ = 768.
// ============================================================================
__global__ __launch_bounds__(256) void rmsnorm_rope_k(
    const float* __restrict__ ckv, const float* __restrict__ nw,
    const float* __restrict__ rope_cache,
    ushort* __restrict__ cnorm, ushort* __restrict__ krb)
{
    const int lane = threadIdx.x & 63;
    const int row = blockIdx.x * 4 + (threadIdx.x >> 6);
    const float* src = ckv + (size_t)row * CKV_P_;
    float4 a = *(const float4*)(src + lane * 4);
    float4 b = *(const float4*)(src + 256 + lane * 4);
    float ss = a.x*a.x + a.y*a.y + a.z*a.z + a.w*a.w
             + b.x*b.x + b.y*b.y + b.z*b.z + b.w*b.w;
#pragma unroll
    for (int off = 32; off > 0; off >>= 1) ss += __shfl_xor(ss, off, 64);
    float rs = rsqrtf(ss * (1.0f / 512.0f) + EPS_);
    float4 w0 = *(const float4*)(nw + lane * 4);
    float4 w1 = *(const float4*)(nw + 256 + lane * 4);
    ushort* dst = cnorm + (size_t)row * KV_LORA_;
    ushort4 o0, o1;
    o0.x = f2bf(a.x*rs*w0.x); o0.y = f2bf(a.y*rs*w0.y);
    o0.z = f2bf(a.z*rs*w0.z); o0.w = f2bf(a.w*rs*w0.w);
    o1.x = f2bf(b.x*rs*w1.x); o1.y = f2bf(b.y*rs*w1.y);
    o1.z = f2bf(b.z*rs*w1.z); o1.w = f2bf(b.w*rs*w1.w);
    *(ushort4*)(dst + lane * 4) = o0;
    *(ushort4*)(dst + 256 + lane * 4) = o1;

    float v = src[KV_LORA_ + lane];
    float other = __shfl_xor(v, 32, 64);
    float rot = (lane < 32) ? -other : other;
    int s = row & (S_ - 1);
    float c  = rope_cache[s * (2 * ROPE_D_) + lane];
    float sn = rope_cache[s * (2 * ROPE_D_) + ROPE_D_ + lane];
    krb[(size_t)row * ROPE_D_ + lane] = f2bf(v * c + rot * sn);
}

// ============================================================================
// In-place RoPE on q_bf cols 128..191 (unchanged)
// ============================================================================
__global__ __launch_bounds__(256) void rope_q_inplace(
    ushort* __restrict__ q_bf, const float* __restrict__ rope_cache)
{
    const int lane = threadIdx.x & 63;
    const int wv = blockIdx.x * 4 + (threadIdx.x >> 6);  // [0, BS*H)
    const int bsr = wv >> 4;
    const int h = wv & 15;
    const int s = bsr & (S_ - 1);
    ushort* p = q_bf + (size_t)bsr * (H_ * Q_D_) + h * Q_D_ + 128;
    float v = bf2f(p[lane]);
    float other = __shfl_xor(v, 32, 64);
    float rot = (lane < 32) ? -other : other;
    float c  = rope_cache[s * (2 * ROPE_D_) + lane];
    float sn = rope_cache[s * (2 * ROPE_D_) + ROPE_D_ + lane];
    p[lane] = f2bf(v * c + rot * sn);
}

// ============================================================================
// V transpose (unchanged)
// ============================================================================
__global__ __launch_bounds__(256) void transpose_v(
    const ushort* __restrict__ kvb, ushort* __restrict__ vT)
{
    __shared__ ushort T[128][80];
    const int tid = threadIdx.x;
    const int bh = blockIdx.y;
    const int b = bh >> 4, h = bh & 15;
    const int sb = blockIdx.x * 64;
    const size_t rowbase = (size_t)b * S_ + sb;
#pragma unroll
    for (int it = 0; it < 4; ++it) {
        int f = tid + 256 * it;
        int r = f >> 4, c8 = (f & 15) * 8;
        bf16x8 v = *(const bf16x8*)(kvb + (rowbase + r) * 4096 + h * 256 + 128 + c8);
#pragma unroll
        for (int e = 0; e < 8; ++e) T[c8 + e][r] = (ushort)v[e];
    }
    __syncthreads();
#pragma unroll
    for (int it = 0; it < 4; ++it) {
        int f = tid + 256 * it;
        int vd = f >> 3, s8 = (f & 7) * 8;
        *(bf16x8*)(vT + ((size_t)bh * 128 + vd) * S_ + sb + s8) =
            *(const bf16x8*)&T[vd][s8];
    }
}

// ============================================================================
// MFMA flash attention v5 (unchanged — passed rounds 3-4)
// ============================================================================
__global__ __launch_bounds__(512, 2) void mla_attn_mfma5(
    const ushort* __restrict__ qb, const ushort* __restrict__ kvb,
    const ushort* __restrict__ krb, const ushort* __restrict__ vT,
    ushort* __restrict__ attn)
{
    __shared__ __align__(16) ushort LDSU[40960];   // 80 KB
    const int KFo[2] = {0, 12288};
    const int VFo[2] = {24576, 32768};

    const int tid = threadIdx.x;
    const int lane = tid & 63;
    const int w = tid >> 6;               // wave 0..7
    const int l31 = lane & 31, hi = lane >> 5;
    const int band = w & 3;               // 32-row q band
    const int koff = (w >> 2) * 32;       // k half of 64-row K tile

    const int lin = (int)blockIdx.y * 8 + (int)blockIdx.x;
    const int swz = (lin & 7) * 32 + (lin >> 3);
    const int bh = swz >> 3;
    const int px = swz & 7;
    const int b = bh >> 4, h = bh & 15;
    const size_t bS = (size_t)b * S_;
    const float scale = 0.07216878364870323f;   // 192^-0.5

    auto stage = [&](int kbase, int bufi) {
#pragma unroll
        for (int r = 0; r < 3; ++r) {
            int c = w + r * 8;                 // 0..23 = d8
            ushort* dst = &LDSU[KFo[bufi] + (c * 64 + lane) * 8];
            const ushort* src = (c < 16)
                ? kvb + (bS + kbase + lane) * 4096 + h * 256 + c * 8
                : krb + (bS + kbase + lane) * 64 + (c - 16) * 8;
            gll16(src, dst);
        }
#pragma unroll
        for (int r = 0; r < 2; ++r) {
            int c = w + r * 8;                 // 0..15: s8 = c&7, vd-half = c>>3
            ushort* dst = &LDSU[VFo[bufi] + (((c & 7) * 128) + (c >> 3) * 64 + lane) * 8];
            const ushort* src =
                vT + ((size_t)bh * 128 + (c >> 3) * 64 + lane) * S_ + kbase + (c & 7) * 8;
            gll16(src, dst);
        }
    };

#pragma unroll 1
    for (int hv = 0; hv < 2; ++hv) {
        const int qt = hv ? 15 - px : px;
        const int qbase = qt * 128;
        const int nkt = 2 * qt + 2;
        const int bmin = qbase + band * 32;   // wave's first q row

        stage(0, 0);

        bf16x8 qf[12];
        {
            const ushort* qrow = qb + (bS + bmin + l31) * (size_t)(H_ * Q_D_) + h * Q_D_;
#pragma unroll
            for (int c = 0; c < 12; ++c)
                qf[c] = *(const bf16x8*)(qrow + c * 16 + hi * 8);
        }

        f32x16 ov[4];
#pragma unroll
        for (int vt = 0; vt < 4; ++vt)
#pragma unroll
            for (int r = 0; r < 16; ++r) ov[vt][r] = 0.f;
        float m_run = -3e38f, lsum = 0.f;

        __syncthreads();                      // tile 0 visible

        for (int kt = 0; kt < nkt; ++kt) {
            const int kb = kt * 64;
            const int cur = kt & 1;
            if (kt + 1 < nkt) stage((kt + 1) * 64, cur ^ 1);

            const int kg = kb + koff;         // wave's 32-k strip start
            if (kg <= bmin + 31) {            // strip not fully masked
                f32x16 sc;
#pragma unroll
                for (int r = 0; r < 16; ++r) sc[r] = 0.f;
                __builtin_amdgcn_s_setprio(1);
#pragma unroll
                for (int c = 0; c < 12; ++c) {
                    bf16x8 kf = *(const bf16x8*)
                        &LDSU[KFo[cur] + ((c * 2 + hi) * 64 + koff + l31) * 8];
                    sc = __builtin_amdgcn_mfma_f32_32x32x16_bf16(kf, qf[c], sc, 0, 0, 0);
                }
                __builtin_amdgcn_s_setprio(0);

                const bool need_mask = (kg == bmin);   // only diagonal strips
                float p[16]; float mx = -3e38f;
#pragma unroll
                for (int r = 0; r < 16; ++r) {
                    float v = sc[r] * scale;
                    if (need_mask) {
                        int kr = (r & 3) + 8 * (r >> 2) + 4 * hi;
                        if (kr > l31) v = -3e38f;
                    }
                    p[r] = v; mx = fmaxf(mx, v);
                }
                mx = fmaxf(mx, __shfl_xor(mx, 32, 64));   // full 64-k row max
                if (!__all(mx - m_run <= 8.0f)) {
                    float mn = fmaxf(mx, m_run);
                    float al = __expf(m_run - mn);
                    m_run = mn; lsum *= al;
#pragma unroll
                    for (int vt = 0; vt < 4; ++vt)
#pragma unroll
                        for (int r = 0; r < 16; ++r) ov[vt][r] *= al;
                }
                float s_loc = 0.f;
#pragma unroll
                for (int r = 0; r < 16; ++r) { p[r] = __expf(p[r] - m_run); s_loc += p[r]; }
                lsum += s_loc + __shfl_xor(s_loc, 32, 64);

                uint32_t w8[8];
#pragma unroll
                for (int m = 0; m < 8; ++m)
                    w8[m] = (uint32_t)f2bf(p[2 * m]) | ((uint32_t)f2bf(p[2 * m + 1]) << 16);
                bf16x8 pb[2];
#pragma unroll
                for (int c = 0; c < 2; ++c) {
                    uint32_t wd[4];
#pragma unroll
                    for (int par = 0; par < 2; ++par) {
                        uint32_t a  = w8[4 * c + par];
                        uint32_t bb = w8[4 * c + 2 + par];
                        uint32_t t  = __shfl_xor(bb, 32, 64);
                        uint32_t t2 = __shfl_xor(a, 32, 64);
                        wd[par]     = hi ? t : a;
                        wd[par + 2] = hi ? bb : t2;
                    }
                    union { uint32_t u[4]; bf16x8 v; } cvt;
                    cvt.u[0] = wd[0]; cvt.u[1] = wd[1]; cvt.u[2] = wd[2]; cvt.u[3] = wd[3];
                    pb[c] = cvt.v;
                }

                __builtin_amdgcn_s_setprio(1);
#pragma unroll
                for (int vt = 0; vt < 4; ++vt)
#pragma unroll
                    for (int c = 0; c < 2; ++c) {
                        bf16x8 vf = *(const bf16x8*)
                            &LDSU[VFo[cur] + (((koff >> 3) + c * 2 + hi) * 128 + vt * 32 + l31) * 8];
                        ov[vt] = __builtin_amdgcn_mfma_f32_32x32x16_bf16(vf, pb[c], ov[vt], 0, 0, 0);
                    }
                __builtin_amdgcn_s_setprio(0);
            }
            __syncthreads();   // publish prefetched tile; WAR-protect buffers
        }

        float* mrg = (float*)LDSU;
        if (w >= 4) {
            float* dst = mrg + (size_t)((w - 4) * 64 + lane) * 68;
#pragma unroll
            for (int vt = 0; vt < 4; ++vt)
#pragma unroll
                for (int g = 0; g < 4; ++g) {
                    f32x4 v4v = { ov[vt][g * 4 + 0], ov[vt][g * 4 + 1],
                                  ov[vt][g * 4 + 2], ov[vt][g * 4 + 3] };
                    *(f32x4*)(dst + vt * 16 + g * 4) = v4v;
                }
            dst[64] = m_run; dst[65] = lsum;
        }
        __syncthreads();
        if (w < 4) {
            const float* srcm = mrg + (size_t)(w * 64 + lane) * 68;
            float mB = srcm[64], lB = srcm[65];
            float M = fmaxf(m_run, mB);
            float eA = __expf(m_run - M), eB = __expf(mB - M);
            float L = lsum * eA + lB * eB;
            float inv = 1.0f / L;
            size_t obase = (bS + bmin + l31) * (size_t)(H_ * V_D_) + h * V_D_;
#pragma unroll
            for (int vt = 0; vt < 4; ++vt)
#pragma unroll
                for (int g = 0; g < 4; ++g) {
                    ushort4 o;
                    o.x = f2bf((ov[vt][g*4+0] * eA + srcm[vt*16+g*4+0] * eB) * inv);
                    o.y = f2bf((ov[vt][g*4+1] * eA + srcm[vt*16+g*4+1] * eB) * inv);
                    o.z = f2bf((ov[vt][g*4+2] * eA + srcm[vt*16+g*4+2] * eB) * inv);
                    o.w = f2bf((ov[vt][g*4+3] * eA + srcm[vt*16+g*4+3] * eB) * inv);
                    *(ushort4*)(attn + obase + vt * 32 + g * 8 + hi * 4) = o;
                }
        }
        __syncthreads();
    }
}

// ============================================================================
// launch
//   Workspace budget (defensive, round-5 container failure):
//     xb 16.8 MB (reused as vT after GEMM 1) | q_bf 25.2 | ckv 12.6 |
//     cnorm 4.2 | kvb 33.6 | attn_bf 16.8 (right-sized: H*V_D=2048 cols) |
//     krb 0.5 | wc_bf 15.7 | wkvb_bf 4.2 | wo_bf 8.4   => ~138 MB total,
//   ~22 MB below the smallest previously-passing layout.
// ============================================================================
extern "C" void kernel_launch(void* const* d_in, const int* in_sizes, int n_in,
                              void* d_out, int out_size, void* d_ws, size_t ws_size,
                              hipStream_t stream)
{
    const float* x          = (const float*)d_in[0];
    const float* rope_cache = (const float*)d_in[1];
    const float* wq         = (const float*)d_in[2];
    const float* wkva       = (const float*)d_in[3];
    const float* norm_w     = (const float*)d_in[4];
    const float* wkvb       = (const float*)d_in[5];
    const float* wo         = (const float*)d_in[6];
    float* out = (float*)d_out;

    char* p = (char*)d_ws;
    ushort* xb       = (ushort*)p; p += (size_t)BS_ * DIM_ * 2;        // 16.8 MB
    ushort* q_bf     = (ushort*)p; p += (size_t)BS_ * H_ * Q_D_ * 2;   // 25.2 MB
    float*  ckv      = (float*) p; p += (size_t)BS_ * CKV_P_ * 4;      // 12.6 MB
    ushort* cnorm_bf = (ushort*)p; p += (size_t)BS_ * KV_LORA_ * 2;    //  4.2 MB
    ushort* kvb      = (ushort*)p; p += (size_t)BS_ * 4096 * 2;        // 33.6 MB
    ushort* attn_bf  = (ushort*)p; p += (size_t)BS_ * 2048 * 2;        // 16.8 MB
    ushort* krb      = (ushort*)p; p += (size_t)BS_ * ROPE_D_ * 2;     //  0.5 MB
    ushort* wc_bf    = (ushort*)p; p += (size_t)3840 * DIM_ * 2;       // 15.7 MB
    ushort* wkvb_bf  = (ushort*)p; p += (size_t)4096 * KV_LORA_ * 2;   //  4.2 MB
    ushort* wo_bf    = (ushort*)p; p += (size_t)DIM_ * 2048 * 2;       //  8.4 MB
    ushort* vT       = xb;   // alias: xb dead after GEMM 1; same size (16.8 MB)

    // 0. all input casts in one dispatch
    cast_all<<<11008, dim3(256), 0, stream>>>(
        x, wq, wkva, wkvb, wo, xb, wc_bf, wkvb_bf, wo_bf);

    // 1. fused: q_bf = x @ wq^T (bf16) and ckv = x @ wkva^T (fp32, pitch 768)
    //    (4096 x 3840 x 2048), 240 blocks
    gemm256_8ph<2><<<dim3(16 * 15), dim3(512), 0, stream>>>(
        xb, wc_bf, q_bf, ckv, 0, DIM_, 15);
    // 2. cnorm + krb fused
    rmsnorm_rope_k<<<BS_ / 4, dim3(256), 0, stream>>>(
        ckv, norm_w, rope_cache, cnorm_bf, krb);
    // 3. RoPE(q) in place
    rope_q_inplace<<<BS_ * H_ / 4, dim3(256), 0, stream>>>(q_bf, rope_cache);
    // 4. kvb = cnorm @ wkvb^T     (4096 x 4096 x 512), bf16 out, 256 blocks
    gemm256_8ph<1><<<dim3(16 * 16), dim3(512), 0, stream>>>(
        cnorm_bf, wkvb_bf, kvb, nullptr, 4096, KV_LORA_, 16);
    // 5. vT = transpose(V part of kvb)   (vT aliases dead xb)
    transpose_v<<<dim3(S_ / 64, B_ * H_), dim3(256), 0, stream>>>(kvb, vT);
    // 6. flash attention v5 -> attn_bf
    mla_attn_mfma5<<<dim3(8, B_ * H_), dim3(512), 0, stream>>>(
        q_bf, kvb, krb, vT, attn_bf);
    // 7. out = attn @ wo^T        (4096 x 2048 x 2048), fp32, 256 blocks
    gemm_bn128<0><<<dim3(16 * 16), dim3(512), 0, stream>>>(
        attn_bf, wo_bf, out, 2048, 2048, 16);
}

// Round 7
// 409.330 us; speedup vs baseline: 1.5830x; 1.0196x over previous
//
#include <hip/hip_runtime.h>
#include <cstdint>
#include <cstddef>

// ---- problem constants ----
#define B_      2
#define S_      2048
#define DIM_    2048
#define H_      16
#define KV_LORA_ 512
#define NOPE_D_ 128
#define ROPE_D_ 64
#define V_D_    128
#define Q_D_    192          // NOPE_D + ROPE_D
#define EPS_    1e-6f
#define BS_     (B_ * S_)    // 4096 rows
#define CKV_P_  768          // ckv row pitch (576 real cols, padded to 768)

typedef __attribute__((ext_vector_type(8))) short bf16x8;
typedef __attribute__((ext_vector_type(4))) float f32x4;
typedef __attribute__((ext_vector_type(16))) float f32x16;

__device__ __forceinline__ ushort f2bf(float f) {
    union { float f; uint32_t u; } v; v.f = f;
    uint32_t u = v.u + 0x7fff + ((v.u >> 16) & 1);  // RNE
    return (ushort)(u >> 16);
}
__device__ __forceinline__ float bf2f(ushort u) {
    union { uint32_t u; float f; } v; v.u = (uint32_t)u << 16; return v.f;
}
__device__ __forceinline__ void gll16(const void* g, void* l) {
    __builtin_amdgcn_global_load_lds(
        (const __attribute__((address_space(1))) unsigned int*)g,
        (__attribute__((address_space(3))) unsigned int*)l, 16, 0, 0);
}

#define GQ_BARRIER()  __builtin_amdgcn_s_barrier()
#define GQ_LGKM0()    do { asm volatile("s_waitcnt lgkmcnt(0)" ::: "memory"); \
                           __builtin_amdgcn_sched_barrier(0); } while (0)

// ============================================================================
// 256x256 8-phase bf16 GEMM (proven rounds 4/6).  MODE:
//   0 = f32 out pitch N
//   1 = bf16 out pitch N
//   2 = split: cols<3072 -> bf16 Cv pitch 3072; else f32 Cv2 pitch 768
//       (fused q-proj + ckv GEMM)
//   3 = kvb + fused V-transpose: waves 0-3 (cols 0..127 of head) -> bf16 Cv
//       (kvb, pitch 4096); waves 4-7 (V cols 128..255) -> LDS-transpose ->
//       Cv2 = vT[bh][vd][s] (pitch 2048).  V never touches kvb.
// ============================================================================
template <int MODE>
__global__ __launch_bounds__(512, 2) void gemm256_8ph(
    const ushort* __restrict__ A, const ushort* __restrict__ Bw,
    void* __restrict__ Cv, void* __restrict__ Cv2, int N, int K, int nbx)
{
    __shared__ __align__(16) ushort L[2][2][2][4][256][8];   // 128 KB

    const int tid = threadIdx.x;
    const int lane = tid & 63;
    const int w = tid >> 6;
    const int l15 = lane & 15, quad = lane >> 4;

    // XCD-bijective swizzle (gridDim.x % 8 == 0 for all our shapes)
    const int nwg = (int)gridDim.x;
    const int cpx = nwg >> 3;
    const int lin = (int)blockIdx.x;
    const int swz = (lin & 7) * cpx + (lin >> 3);
    const int m0 = (swz / nbx) * 256;
    const int n0 = (swz % nbx) * 256;

    const int wm0 = (w & 3) * 64;     // wave M offset (4 M-frags)
    const int wn0 = (w >> 2) * 128;   // wave N offset (8 N-frags)

    const int NT = K >> 6;            // K-tiles (>= 2 for all our shapes)

    f32x4 acc[4][8];
#pragma unroll
    for (int i = 0; i < 4; ++i)
#pragma unroll
        for (int j = 0; j < 8; ++j) acc[i][j] = (f32x4){0.f, 0.f, 0.f, 0.f};

    // stage one 16 KB slot (ab, kh) of K-tile kt into buffer buf
    auto stage = [&](int ab, int kh, int kt, int buf) {
#pragma unroll
        for (int j = 0; j < 2; ++j) {
            int ci = w + j * 8;
            int qd = ci >> 2, rg = ci & 3;
            ushort* dst = &L[buf][ab][kh][qd][rg * 64 + lane][0];
            const ushort* src = (ab ? Bw + (size_t)(n0 + rg * 64 + lane) * K
                                    : A  + (size_t)(m0 + rg * 64 + lane) * K)
                                + kt * 64 + kh * 32 + qd * 8;
            gll16(src, dst);
        }
    };

    // ---- prologue: tile0 (A0,B0,A1,B1) + tile1 (A0,B0,A1) = 14 loads ----
    stage(0, 0, 0, 0); stage(1, 0, 0, 0); stage(0, 1, 0, 0); stage(1, 1, 0, 0);
    if (NT > 1) { stage(0, 0, 1, 1); stage(1, 0, 1, 1); stage(0, 1, 1, 1); }
    else        { stage(0, 0, 0, 1); stage(1, 0, 0, 1); stage(0, 1, 0, 1); }
    asm volatile("s_waitcnt vmcnt(6)" ::: "memory");
    GQ_BARRIER();

    bf16x8 a[4], b[4];

    for (int t = 0; t < NT; ++t) {
        const int c = t & 1, o = c ^ 1;
        const int kt1 = (t + 1 < NT) ? t + 1 : 0;
        const int kt2 = (t + 2 < NT) ? t + 2 : 0;

        // ---------- q0: (kh0, nh0) ----------
#pragma unroll
        for (int fm = 0; fm < 4; ++fm)
            a[fm] = *(const bf16x8*)&L[c][0][0][quad][wm0 + fm * 16 + l15][0];
#pragma unroll
        for (int fn = 0; fn < 4; ++fn)
            b[fn] = *(const bf16x8*)&L[c][1][0][quad][wn0 + fn * 16 + l15][0];
        stage(1, 1, kt1, o);
        GQ_BARRIER();
        GQ_LGKM0();
        __builtin_amdgcn_s_setprio(1);
#pragma unroll
        for (int fm = 0; fm < 4; ++fm)
#pragma unroll
            for (int fn = 0; fn < 4; ++fn)
                acc[fm][fn] = __builtin_amdgcn_mfma_f32_16x16x32_bf16(a[fm], b[fn], acc[fm][fn], 0, 0, 0);
        __builtin_amdgcn_s_setprio(0);
        GQ_BARRIER();

        // ---------- q1: (kh0, nh1) ----------
#pragma unroll
        for (int fn = 0; fn < 4; ++fn)
            b[fn] = *(const bf16x8*)&L[c][1][0][quad][wn0 + 64 + fn * 16 + l15][0];
        stage(0, 0, kt2, c);
        GQ_BARRIER();
        GQ_LGKM0();
        __builtin_amdgcn_s_setprio(1);
#pragma unroll
        for (int fm = 0; fm < 4; ++fm)
#pragma unroll
            for (int fn = 0; fn < 4; ++fn)
                acc[fm][4 + fn] = __builtin_amdgcn_mfma_f32_16x16x32_bf16(a[fm], b[fn], acc[fm][4 + fn], 0, 0, 0);
        __builtin_amdgcn_s_setprio(0);
        GQ_BARRIER();

        // ---------- q2: (kh1, nh0) ----------
#pragma unroll
        for (int fm = 0; fm < 4; ++fm)
            a[fm] = *(const bf16x8*)&L[c][0][1][quad][wm0 + fm * 16 + l15][0];
#pragma unroll
        for (int fn = 0; fn < 4; ++fn)
            b[fn] = *(const bf16x8*)&L[c][1][1][quad][wn0 + fn * 16 + l15][0];
        stage(1, 0, kt2, c);
        GQ_BARRIER();
        GQ_LGKM0();
        __builtin_amdgcn_s_setprio(1);
#pragma unroll
        for (int fm = 0; fm < 4; ++fm)
#pragma unroll
            for (int fn = 0; fn < 4; ++fn)
                acc[fm][fn] = __builtin_amdgcn_mfma_f32_16x16x32_bf16(a[fm], b[fn], acc[fm][fn], 0, 0, 0);
        __builtin_amdgcn_s_setprio(0);
        GQ_BARRIER();

        // ---------- q3: (kh1, nh1) ----------
#pragma unroll
        for (int fn = 0; fn < 4; ++fn)
            b[fn] = *(const bf16x8*)&L[c][1][1][quad][wn0 + 64 + fn * 16 + l15][0];
        stage(0, 1, kt2, c);
        GQ_BARRIER();
        GQ_LGKM0();
        __builtin_amdgcn_s_setprio(1);
#pragma unroll
        for (int fm = 0; fm < 4; ++fm)
#pragma unroll
            for (int fn = 0; fn < 4; ++fn)
                acc[fm][4 + fn] = __builtin_amdgcn_mfma_f32_16x16x32_bf16(a[fm], b[fn], acc[fm][4 + fn], 0, 0, 0);
        __builtin_amdgcn_s_setprio(0);
        asm volatile("s_waitcnt vmcnt(6)" ::: "memory");
        GQ_BARRIER();
    }

    // ---- epilogue ----
    if (MODE == 3) {
        // Drain outstanding dummy-stage DMAs (they land in L, which we are
        // about to reuse as the transpose buffer), then full barrier.
        asm volatile("s_waitcnt vmcnt(0)" ::: "memory");
        GQ_BARRIER();
        const int h = n0 >> 8;
        if (w < 4) {
            // K-nope half -> kvb (pitch 4096), cols n0 + 0..127
#pragma unroll
            for (int fm = 0; fm < 4; ++fm)
#pragma unroll
                for (int r = 0; r < 4; ++r) {
                    size_t base = (size_t)(m0 + wm0 + fm * 16 + quad * 4 + r) * 4096
                                  + n0 + wn0 + l15;
#pragma unroll
                    for (int fn = 0; fn < 8; ++fn)
                        ((ushort*)Cv)[base + fn * 16] = f2bf(acc[fm][fn][r]);
                }
        } else {
            // V half: LDS-transpose own 64x128 tile, write vT[bh][vd][s].
            // Per-wave private region: [vd 0..127][stride 80 ushorts].
            ushort* T = &L[0][0][0][0][0][0] + (size_t)(w - 4) * (128 * 80);
#pragma unroll
            for (int fm = 0; fm < 4; ++fm)
#pragma unroll
                for (int fn = 0; fn < 8; ++fn) {
                    uint32_t lo = (uint32_t)f2bf(acc[fm][fn][0])
                                | ((uint32_t)f2bf(acc[fm][fn][1]) << 16);
                    uint32_t hi2 = (uint32_t)f2bf(acc[fm][fn][2])
                                 | ((uint32_t)f2bf(acc[fm][fn][3]) << 16);
                    uint2 pk; pk.x = lo; pk.y = hi2;
                    *(uint2*)&T[(size_t)(fn * 16 + l15) * 80 + fm * 16 + quad * 4] = pk;
                }
            asm volatile("s_waitcnt lgkmcnt(0)" ::: "memory");
            __builtin_amdgcn_sched_barrier(0);
            const int bh = (m0 >> 11) * 16 + h;
            const int sbase = (m0 & 2047) + (w & 3) * 64;
            ushort* vT = (ushort*)Cv2;
#pragma unroll
            for (int j = 0; j < 16; ++j) {
                int cc = j * 64 + lane;
                int vd = cc >> 3;
                int s8 = (cc & 7) * 8;
                bf16x8 v = *(const bf16x8*)&T[(size_t)vd * 80 + s8];
                *(bf16x8*)(vT + ((size_t)bh * 128 + vd) * 2048 + sbase + s8) = v;
            }
        }
        return;
    }
#pragma unroll
    for (int fm = 0; fm < 4; ++fm)
#pragma unroll
        for (int r = 0; r < 4; ++r) {
            int row = m0 + wm0 + fm * 16 + quad * 4 + r;
            if (MODE == 2) {
                if (n0 < 3072) {
                    size_t base = (size_t)row * 3072 + n0 + wn0 + l15;
#pragma unroll
                    for (int fn = 0; fn < 8; ++fn)
                        ((ushort*)Cv)[base + fn * 16] = f2bf(acc[fm][fn][r]);
                } else {
                    size_t base = (size_t)row * CKV_P_ + (n0 - 3072) + wn0 + l15;
#pragma unroll
                    for (int fn = 0; fn < 8; ++fn)
                        ((float*)Cv2)[base + fn * 16] = acc[fm][fn][r];
                }
            } else {
                size_t base = (size_t)row * N + n0 + wn0 + l15;
#pragma unroll
                for (int fn = 0; fn < 8; ++fn) {
                    float v = acc[fm][fn][r];
                    if (MODE == 1) ((ushort*)Cv)[base + fn * 16] = f2bf(v);
                    else           ((float*)Cv)[base + fn * 16] = v;
                }
            }
        }
}

// ============================================================================
// 256x128-tile GEMM, 2 phases/K-tile, counted-vmcnt pipeline (wo; unchanged)
// ============================================================================
template <int OUT_BF16>
__global__ __launch_bounds__(512, 2) void gemm_bn128(
    const ushort* __restrict__ A, const ushort* __restrict__ Bw,
    void* __restrict__ Cv, int N, int K, int nbx)
{
    __shared__ __align__(16) ushort LA[2][2][4][256][8];   // 64 KB
    __shared__ __align__(16) ushort LB[2][2][4][128][8];   // 32 KB

    const int tid = threadIdx.x;
    const int lane = tid & 63;
    const int w = tid >> 6;
    const int l15 = lane & 15, quad = lane >> 4;

    const int nwg = (int)gridDim.x;
    const int cpx = nwg >> 3;
    const int lin = (int)blockIdx.x;
    const int swz = (lin & 7) * cpx + (lin >> 3);
    const int m0 = (swz / nbx) * 256;
    const int n0 = (swz % nbx) * 128;

    const int wm0 = (w & 3) * 64;
    const int wn0 = (w >> 2) * 64;

    const int NT = K >> 6;

    f32x4 acc[4][4];
#pragma unroll
    for (int i = 0; i < 4; ++i)
#pragma unroll
        for (int j = 0; j < 4; ++j) acc[i][j] = (f32x4){0.f, 0.f, 0.f, 0.f};

    auto stageA = [&](int kh, int kt, int buf) {
#pragma unroll
        for (int j = 0; j < 2; ++j) {
            int ci = w + j * 8;
            int qd = ci >> 2, rg = ci & 3;
            ushort* dst = &LA[buf][kh][qd][rg * 64 + lane][0];
            const ushort* src = A + (size_t)(m0 + rg * 64 + lane) * K
                                + kt * 64 + kh * 32 + qd * 8;
            gll16(src, dst);
        }
    };
    auto stageB = [&](int kt, int buf) {
#pragma unroll
        for (int j = 0; j < 2; ++j) {
            int ci = w + j * 8;
            int kh = ci >> 3, qd = (ci >> 1) & 3, rh = ci & 1;
            ushort* dst = &LB[buf][kh][qd][rh * 64 + lane][0];
            const ushort* src = Bw + (size_t)(n0 + rh * 64 + lane) * K
                                + kt * 64 + kh * 32 + qd * 8;
            gll16(src, dst);
        }
    };

    // ---- prologue: tile0 {A0,A1,B} + A0(tile1) = 8 loads ----
    stageA(0, 0, 0); stageA(1, 0, 0); stageB(0, 0);
    stageA(0, (NT > 1) ? 1 : 0, 1);
    asm volatile("s_waitcnt vmcnt(2)" ::: "memory");
    GQ_BARRIER();

    bf16x8 a[4], b[4];

    for (int t = 0; t < NT; ++t) {
        const int c = t & 1, o = c ^ 1;
        const int kt1 = (t + 1 < NT) ? t + 1 : 0;
        const int kt2 = (t + 2 < NT) ? t + 2 : 0;

        // ---------- ph0 (kh0) ----------
#pragma unroll
        for (int fm = 0; fm < 4; ++fm)
            a[fm] = *(const bf16x8*)&LA[c][0][quad][wm0 + fm * 16 + l15][0];
#pragma unroll
        for (int fn = 0; fn < 4; ++fn)
            b[fn] = *(const bf16x8*)&LB[c][0][quad][wn0 + fn * 16 + l15][0];
        stageA(1, kt1, o); stageB(kt1, o);
        GQ_BARRIER();
        GQ_LGKM0();
        __builtin_amdgcn_s_setprio(1);
#pragma unroll
        for (int fm = 0; fm < 4; ++fm)
#pragma unroll
            for (int fn = 0; fn < 4; ++fn)
                acc[fm][fn] = __builtin_amdgcn_mfma_f32_16x16x32_bf16(a[fm], b[fn], acc[fm][fn], 0, 0, 0);
        __builtin_amdgcn_s_setprio(0);
        GQ_BARRIER();

        // ---------- ph1 (kh1) ----------
#pragma unroll
        for (int fm = 0; fm < 4; ++fm)
            a[fm] = *(const bf16x8*)&LA[c][1][quad][wm0 + fm * 16 + l15][0];
#pragma unroll
        for (int fn = 0; fn < 4; ++fn)
            b[fn] = *(const bf16x8*)&LB[c][1][quad][wn0 + fn * 16 + l15][0];
        stageA(0, kt2, c);
        GQ_BARRIER();
        GQ_LGKM0();
        __builtin_amdgcn_s_setprio(1);
#pragma unroll
        for (int fm = 0; fm < 4; ++fm)
#pragma unroll
            for (int fn = 0; fn < 4; ++fn)
                acc[fm][fn] = __builtin_amdgcn_mfma_f32_16x16x32_bf16(a[fm], b[fn], acc[fm][fn], 0, 0, 0);
        __builtin_amdgcn_s_setprio(0);
        asm volatile("s_waitcnt vmcnt(2)" ::: "memory");   // tile t+1 landed
        GQ_BARRIER();
    }

    // ---- epilogue ----
#pragma unroll
    for (int fm = 0; fm < 4; ++fm)
#pragma unroll
        for (int r = 0; r < 4; ++r) {
            size_t base = (size_t)(m0 + wm0 + fm * 16 + quad * 4 + r) * N + n0 + wn0 + l15;
#pragma unroll
            for (int fn = 0; fn < 4; ++fn) {
                float v = acc[fm][fn][r];
                if (OUT_BF16) ((ushort*)Cv)[base + fn * 16] = f2bf(v);
                else          ((float*)Cv)[base + fn * 16] = v;
            }
        }
}

// ============================================================================
// Fused cast kernel (unchanged from round 6)
// ============================================================================
__global__ __launch_bounds__(256) void cast_all(
    const float* __restrict__ x, const float* __restrict__ wq,
    const float* __restrict__ wkva, const float* __restrict__ wkvb,
    const float* __restrict__ wo,
    ushort* __restrict__ xb, ushort* __restrict__ wc,
    ushort* __restrict__ wkvb_bf, ushort* __restrict__ wo_bf)
{
    size_t i = ((size_t)blockIdx.x * 256 + threadIdx.x) * 8;
    const float* s; ushort* d;
    if (i < 8388608)        { s = x + i;                  d = xb + i; }
    else if (i < 14680064)  { s = wq + (i - 8388608);     d = wc + (i - 8388608); }
    else if (i < 15859712)  { s = wkva + (i - 14680064);  d = wc + (i - 8388608); }
    else if (i < 16252928)  {   // zero pad rows 3648..3839 of wc
        ushort4 z = {0, 0, 0, 0};
        ushort* dz = wc + (i - 8388608);
        *(ushort4*)dz = z; *(ushort4*)(dz + 4) = z;
        return;
    }
    else if (i < 18350080)  { s = wkvb + (i - 16252928);  d = wkvb_bf + (i - 16252928); }
    else                    { s = wo + (i - 18350080);    d = wo_bf + (i - 18350080); }
    float4 a = *(const float4*)s;
    float4 b = *(const float4*)(s + 4);
    ushort4 o0, o1;
    o0.x = f2bf(a.x); o0.y = f2bf(a.y); o0.z = f2bf(a.z); o0.w = f2bf(a.w);
    o1.x = f2bf(b.x); o1.y = f2bf(b.y); o1.z = f2bf(b.z); o1.w = f2bf(b.w);
    *(ushort4*)d = o0;
    *(ushort4*)(d + 4) = o1;
}

// ============================================================================
// Fused RMSNorm + RoPE-k (unchanged, pitch 768)
// ============================================================================
__global__ __launch_bounds__(256) void rmsnorm_rope_k(
    const float* __restrict__ ckv, const float* __restrict__ nw,
    const float* __restrict__ rope_cache,
    ushort* __restrict__ cnorm, ushort* __restrict__ krb)
{
    const int lane = threadIdx.x & 63;
    const int row = blockIdx.x * 4 + (threadIdx.x >> 6);
    const float* src = ckv + (size_t)row * CKV_P_;
    float4 a = *(const float4*)(src + lane * 4);
    float4 b = *(const float4*)(src + 256 + lane * 4);
    float ss = a.x*a.x + a.y*a.y + a.z*a.z + a.w*a.w
             + b.x*b.x + b.y*b.y + b.z*b.z + b.w*b.w;
#pragma unroll
    for (int off = 32; off > 0; off >>= 1) ss += __shfl_xor(ss, off, 64);
    float rs = rsqrtf(ss * (1.0f / 512.0f) + EPS_);
    float4 w0 = *(const float4*)(nw + lane * 4);
    float4 w1 = *(const float4*)(nw + 256 + lane * 4);
    ushort* dst = cnorm + (size_t)row * KV_LORA_;
    ushort4 o0, o1;
    o0.x = f2bf(a.x*rs*w0.x); o0.y = f2bf(a.y*rs*w0.y);
    o0.z = f2bf(a.z*rs*w0.z); o0.w = f2bf(a.w*rs*w0.w);
    o1.x = f2bf(b.x*rs*w1.x); o1.y = f2bf(b.y*rs*w1.y);
    o1.z = f2bf(b.z*rs*w1.z); o1.w = f2bf(b.w*rs*w1.w);
    *(ushort4*)(dst + lane * 4) = o0;
    *(ushort4*)(dst + 256 + lane * 4) = o1;

    float v = src[KV_LORA_ + lane];
    float other = __shfl_xor(v, 32, 64);
    float rot = (lane < 32) ? -other : other;
    int s = row & (S_ - 1);
    float c  = rope_cache[s * (2 * ROPE_D_) + lane];
    float sn = rope_cache[s * (2 * ROPE_D_) + ROPE_D_ + lane];
    krb[(size_t)row * ROPE_D_ + lane] = f2bf(v * c + rot * sn);
}

// ============================================================================
// MFMA flash attention v6 = v5 + fused RoPE-q in the Q-fragment load.
//  Chunks c=8..11 hold q cols 128..191 (d = (c-8)*16 + hi*8 + e).  The
//  rotate-half partner of (c,e) is (c+2,e), same lane; cos/sin from
//  rope_cache row s = bmin+l31 (per-lane).  Everything else unchanged.
// ============================================================================
__global__ __launch_bounds__(512, 2) void mla_attn_mfma6(
    const ushort* __restrict__ qb, const ushort* __restrict__ kvb,
    const ushort* __restrict__ krb, const ushort* __restrict__ vT,
    const float* __restrict__ rope_cache, ushort* __restrict__ attn)
{
    __shared__ __align__(16) ushort LDSU[40960];   // 80 KB
    const int KFo[2] = {0, 12288};
    const int VFo[2] = {24576, 32768};

    const int tid = threadIdx.x;
    const int lane = tid & 63;
    const int w = tid >> 6;               // wave 0..7
    const int l31 = lane & 31, hi = lane >> 5;
    const int band = w & 3;               // 32-row q band
    const int koff = (w >> 2) * 32;       // k half of 64-row K tile

    const int lin = (int)blockIdx.y * 8 + (int)blockIdx.x;
    const int swz = (lin & 7) * 32 + (lin >> 3);
    const int bh = swz >> 3;
    const int px = swz & 7;
    const int b = bh >> 4, h = bh & 15;
    const size_t bS = (size_t)b * S_;
    const float scale = 0.07216878364870323f;   // 192^-0.5

    auto stage = [&](int kbase, int bufi) {
#pragma unroll
        for (int r = 0; r < 3; ++r) {
            int c = w + r * 8;                 // 0..23 = d8
            ushort* dst = &LDSU[KFo[bufi] + (c * 64 + lane) * 8];
            const ushort* src = (c < 16)
                ? kvb + (bS + kbase + lane) * 4096 + h * 256 + c * 8
                : krb + (bS + kbase + lane) * 64 + (c - 16) * 8;
            gll16(src, dst);
        }
#pragma unroll
        for (int r = 0; r < 2; ++r) {
            int c = w + r * 8;                 // 0..15: s8 = c&7, vd-half = c>>3
            ushort* dst = &LDSU[VFo[bufi] + (((c & 7) * 128) + (c >> 3) * 64 + lane) * 8];
            const ushort* src =
                vT + ((size_t)bh * 128 + (c >> 3) * 64 + lane) * S_ + kbase + (c & 7) * 8;
            gll16(src, dst);
        }
    };

#pragma unroll 1
    for (int hv = 0; hv < 2; ++hv) {
        const int qt = hv ? 15 - px : px;
        const int qbase = qt * 128;
        const int nkt = 2 * qt + 2;
        const int bmin = qbase + band * 32;   // wave's first q row

        stage(0, 0);

        // ---- Q fragments with fused RoPE on chunks 8..11 (cols 128..191) ----
        bf16x8 qf[12];
        {
            const ushort* qrow = qb + (bS + bmin + l31) * (size_t)(H_ * Q_D_) + h * Q_D_;
#pragma unroll
            for (int c = 0; c < 8; ++c)
                qf[c] = *(const bf16x8*)(qrow + c * 16 + hi * 8);
            bf16x8 q8  = *(const bf16x8*)(qrow + 128 + hi * 8);
            bf16x8 q9  = *(const bf16x8*)(qrow + 144 + hi * 8);
            bf16x8 q10 = *(const bf16x8*)(qrow + 160 + hi * 8);
            bf16x8 q11 = *(const bf16x8*)(qrow + 176 + hi * 8);
            const float* rc = rope_cache + (size_t)(bmin + l31) * 128 + hi * 8;
            // cos[d]=rc-row[d], sin[d]=rc-row[64+d]
            f32x4 c8a = *(const f32x4*)(rc + 0),  c8b = *(const f32x4*)(rc + 4);
            f32x4 c9a = *(const f32x4*)(rc + 16), c9b = *(const f32x4*)(rc + 20);
            f32x4 cAa = *(const f32x4*)(rc + 32), cAb = *(const f32x4*)(rc + 36);
            f32x4 cBa = *(const f32x4*)(rc + 48), cBb = *(const f32x4*)(rc + 52);
            f32x4 s8a = *(const f32x4*)(rc + 64), s8b = *(const f32x4*)(rc + 68);
            f32x4 s9a = *(const f32x4*)(rc + 80), s9b = *(const f32x4*)(rc + 84);
            f32x4 sAa = *(const f32x4*)(rc + 96), sAb = *(const f32x4*)(rc + 100);
            f32x4 sBa = *(const f32x4*)(rc + 112), sBb = *(const f32x4*)(rc + 116);
            bf16x8 o8, o9, o10, o11;
#pragma unroll
            for (int e = 0; e < 4; ++e) {
                float a8 = bf2f((ushort)q8[e]),  b8 = bf2f((ushort)q8[e + 4]);
                float a9 = bf2f((ushort)q9[e]),  b9 = bf2f((ushort)q9[e + 4]);
                float aA = bf2f((ushort)q10[e]), bA = bf2f((ushort)q10[e + 4]);
                float aB = bf2f((ushort)q11[e]), bB = bf2f((ushort)q11[e + 4]);
                o8[e]      = (short)f2bf(a8 * c8a[e] - aA * s8a[e]);
                o8[e + 4]  = (short)f2bf(b8 * c8b[e] - bA * s8b[e]);
                o9[e]      = (short)f2bf(a9 * c9a[e] - aB * s9a[e]);
                o9[e + 4]  = (short)f2bf(b9 * c9b[e] - bB * s9b[e]);
                o10[e]     = (short)f2bf(aA * cAa[e] + a8 * sAa[e]);
                o10[e + 4] = (short)f2bf(bA * cAb[e] + b8 * sAb[e]);
                o11[e]     = (short)f2bf(aB * cBa[e] + a9 * sBa[e]);
                o11[e + 4] = (short)f2bf(bB * cBb[e] + b9 * sBb[e]);
            }
            qf[8] = o8; qf[9] = o9; qf[10] = o10; qf[11] = o11;
        }

        f32x16 ov[4];
#pragma unroll
        for (int vt = 0; vt < 4; ++vt)
#pragma unroll
            for (int r = 0; r < 16; ++r) ov[vt][r] = 0.f;
        float m_run = -3e38f, lsum = 0.f;

        __syncthreads();                      // tile 0 visible

        for (int kt = 0; kt < nkt; ++kt) {
            const int kb = kt * 64;
            const int cur = kt & 1;
            if (kt + 1 < nkt) stage((kt + 1) * 64, cur ^ 1);

            const int kg = kb + koff;         // wave's 32-k strip start
            if (kg <= bmin + 31) {            // strip not fully masked
                f32x16 sc;
#pragma unroll
                for (int r = 0; r < 16; ++r) sc[r] = 0.f;
                __builtin_amdgcn_s_setprio(1);
#pragma unroll
                for (int c = 0; c < 12; ++c) {
                    bf16x8 kf = *(const bf16x8*)
                        &LDSU[KFo[cur] + ((c * 2 + hi) * 64 + koff + l31) * 8];
                    sc = __builtin_amdgcn_mfma_f32_32x32x16_bf16(kf, qf[c], sc, 0, 0, 0);
                }
                __builtin_amdgcn_s_setprio(0);

                const bool need_mask = (kg == bmin);   // only diagonal strips
                float p[16]; float mx = -3e38f;
#pragma unroll
                for (int r = 0; r < 16; ++r) {
                    float v = sc[r] * scale;
                    if (need_mask) {
                        int kr = (r & 3) + 8 * (r >> 2) + 4 * hi;
                        if (kr > l31) v = -3e38f;
                    }
                    p[r] = v; mx = fmaxf(mx, v);
                }
                mx = fmaxf(mx, __shfl_xor(mx, 32, 64));   // full 64-k row max
                if (!__all(mx - m_run <= 8.0f)) {
                    float mn = fmaxf(mx, m_run);
                    float al = __expf(m_run - mn);
                    m_run = mn; lsum *= al;
#pragma unroll
                    for (int vt = 0; vt < 4; ++vt)
#pragma unroll
                        for (int r = 0; r < 16; ++r) ov[vt][r] *= al;
                }
                float s_loc = 0.f;
#pragma unroll
                for (int r = 0; r < 16; ++r) { p[r] = __expf(p[r] - m_run); s_loc += p[r]; }
                lsum += s_loc + __shfl_xor(s_loc, 32, 64);

                uint32_t w8[8];
#pragma unroll
                for (int m = 0; m < 8; ++m)
                    w8[m] = (uint32_t)f2bf(p[2 * m]) | ((uint32_t)f2bf(p[2 * m + 1]) << 16);
                bf16x8 pb[2];
#pragma unroll
                for (int c = 0; c < 2; ++c) {
                    uint32_t wd[4];
#pragma unroll
                    for (int par = 0; par < 2; ++par) {
                        uint32_t a  = w8[4 * c + par];
                        uint32_t bb = w8[4 * c + 2 + par];
                        uint32_t t  = __shfl_xor(bb, 32, 64);
                        uint32_t t2 = __shfl_xor(a, 32, 64);
                        wd[par]     = hi ? t : a;
                        wd[par + 2] = hi ? bb : t2;
                    }
                    union { uint32_t u[4]; bf16x8 v; } cvt;
                    cvt.u[0] = wd[0]; cvt.u[1] = wd[1]; cvt.u[2] = wd[2]; cvt.u[3] = wd[3];
                    pb[c] = cvt.v;
                }

                __builtin_amdgcn_s_setprio(1);
#pragma unroll
                for (int vt = 0; vt < 4; ++vt)
#pragma unroll
                    for (int c = 0; c < 2; ++c) {
                        bf16x8 vf = *(const bf16x8*)
                            &LDSU[VFo[cur] + (((koff >> 3) + c * 2 + hi) * 128 + vt * 32 + l31) * 8];
                        ov[vt] = __builtin_amdgcn_mfma_f32_32x32x16_bf16(vf, pb[c], ov[vt], 0, 0, 0);
                    }
                __builtin_amdgcn_s_setprio(0);
            }
            __syncthreads();   // publish prefetched tile; WAR-protect buffers
        }

        float* mrg = (float*)LDSU;
        if (w >= 4) {
            float* dst = mrg + (size_t)((w - 4) * 64 + lane) * 68;
#pragma unroll
            for (int vt = 0; vt < 4; ++vt)
#pragma unroll
                for (int g = 0; g < 4; ++g) {
                    f32x4 v4v = { ov[vt][g * 4 + 0], ov[vt][g * 4 + 1],
                                  ov[vt][g * 4 + 2], ov[vt][g * 4 + 3] };
                    *(f32x4*)(dst + vt * 16 + g * 4) = v4v;
                }
            dst[64] = m_run; dst[65] = lsum;
        }
        __syncthreads();
        if (w < 4) {
            const float* srcm = mrg + (size_t)(w * 64 + lane) * 68;
            float mB = srcm[64], lB = srcm[65];
            float M = fmaxf(m_run, mB);
            float eA = __expf(m_run - M), eB = __expf(mB - M);
            float L = lsum * eA + lB * eB;
            float inv = 1.0f / L;
            size_t obase = (bS + bmin + l31) * (size_t)(H_ * V_D_) + h * V_D_;
#pragma unroll
            for (int vt = 0; vt < 4; ++vt)
#pragma unroll
                for (int g = 0; g < 4; ++g) {
                    ushort4 o;
                    o.x = f2bf((ov[vt][g*4+0] * eA + srcm[vt*16+g*4+0] * eB) * inv);
                    o.y = f2bf((ov[vt][g*4+1] * eA + srcm[vt*16+g*4+1] * eB) * inv);
                    o.z = f2bf((ov[vt][g*4+2] * eA + srcm[vt*16+g*4+2] * eB) * inv);
                    o.w = f2bf((ov[vt][g*4+3] * eA + srcm[vt*16+g*4+3] * eB) * inv);
                    *(ushort4*)(attn + obase + vt * 32 + g * 8 + hi * 4) = o;
                }
        }
        __syncthreads();
    }
}

// ============================================================================
// launch — workspace ~138 MB (round-6 layout, unchanged)
// ============================================================================
extern "C" void kernel_launch(void* const* d_in, const int* in_sizes, int n_in,
                              void* d_out, int out_size, void* d_ws, size_t ws_size,
                              hipStream_t stream)
{
    const float* x          = (const float*)d_in[0];
    const float* rope_cache = (const float*)d_in[1];
    const float* wq         = (const float*)d_in[2];
    const float* wkva       = (const float*)d_in[3];
    const float* norm_w     = (const float*)d_in[4];
    const float* wkvb       = (const float*)d_in[5];
    const float* wo         = (const float*)d_in[6];
    float* out = (float*)d_out;

    char* p = (char*)d_ws;
    ushort* xb       = (ushort*)p; p += (size_t)BS_ * DIM_ * 2;        // 16.8 MB
    ushort* q_bf     = (ushort*)p; p += (size_t)BS_ * H_ * Q_D_ * 2;   // 25.2 MB
    float*  ckv      = (float*) p; p += (size_t)BS_ * CKV_P_ * 4;      // 12.6 MB
    ushort* cnorm_bf = (ushort*)p; p += (size_t)BS_ * KV_LORA_ * 2;    //  4.2 MB
    ushort* kvb      = (ushort*)p; p += (size_t)BS_ * 4096 * 2;        // 33.6 MB
    ushort* attn_bf  = (ushort*)p; p += (size_t)BS_ * 2048 * 2;        // 16.8 MB
    ushort* krb      = (ushort*)p; p += (size_t)BS_ * ROPE_D_ * 2;     //  0.5 MB
    ushort* wc_bf    = (ushort*)p; p += (size_t)3840 * DIM_ * 2;       // 15.7 MB
    ushort* wkvb_bf  = (ushort*)p; p += (size_t)4096 * KV_LORA_ * 2;   //  4.2 MB
    ushort* wo_bf    = (ushort*)p; p += (size_t)DIM_ * 2048 * 2;       //  8.4 MB
    ushort* vT       = xb;   // alias: xb dead after GEMM 1; same size (16.8 MB)

    // 0. all input casts in one dispatch
    cast_all<<<11008, dim3(256), 0, stream>>>(
        x, wq, wkva, wkvb, wo, xb, wc_bf, wkvb_bf, wo_bf);

    // 1. fused: q_bf = x @ wq^T (bf16) and ckv = x @ wkva^T (fp32, pitch 768)
    gemm256_8ph<2><<<dim3(16 * 15), dim3(512), 0, stream>>>(
        xb, wc_bf, q_bf, ckv, 0, DIM_, 15);
    // 2. cnorm + krb fused
    rmsnorm_rope_k<<<BS_ / 4, dim3(256), 0, stream>>>(
        ckv, norm_w, rope_cache, cnorm_bf, krb);
    // 3. kvb (K-nope) + vT (V transposed) = cnorm @ wkvb^T, fused epilogue
    gemm256_8ph<3><<<dim3(16 * 16), dim3(512), 0, stream>>>(
        cnorm_bf, wkvb_bf, kvb, vT, 4096, KV_LORA_, 16);
    // 4. flash attention v6 (RoPE-q fused) -> attn_bf
    mla_attn_mfma6<<<dim3(8, B_ * H_), dim3(512), 0, stream>>>(
        q_bf, kvb, krb, vT, rope_cache, attn_bf);
    // 5. out = attn @ wo^T        (4096 x 2048 x 2048), fp32, 256 blocks
    gemm_bn128<0><<<dim3(16 * 16), dim3(512), 0, stream>>>(
        attn_bf, wo_bf, out, 2048, 2048, 16);
}

// Round 8
// 362.275 us; speedup vs baseline: 1.7887x; 1.1299x over previous
//
#include <hip/hip_runtime.h>
#include <cstdint>
#include <cstddef>

// ---- problem constants ----
#define B_      2
#define S_      2048
#define DIM_    2048
#define H_      16
#define KV_LORA_ 512
#define NOPE_D_ 128
#define ROPE_D_ 64
#define V_D_    128
#define Q_D_    192          // NOPE_D + ROPE_D
#define EPS_    1e-6f
#define BS_     (B_ * S_)    // 4096 rows
#define CKV_P_  768          // ckv row pitch (576 real cols, padded to 768)

typedef __attribute__((ext_vector_type(8))) short bf16x8;
typedef __attribute__((ext_vector_type(4))) float f32x4;
typedef __attribute__((ext_vector_type(16))) float f32x16;

__device__ __forceinline__ ushort f2bf(float f) {
    union { float f; uint32_t u; } v; v.f = f;
    uint32_t u = v.u + 0x7fff + ((v.u >> 16) & 1);  // RNE
    return (ushort)(u >> 16);
}
__device__ __forceinline__ float bf2f(ushort u) {
    union { uint32_t u; float f; } v; v.u = (uint32_t)u << 16; return v.f;
}
__device__ __forceinline__ void gll16(const void* g, void* l) {
    __builtin_amdgcn_global_load_lds(
        (const __attribute__((address_space(1))) unsigned int*)g,
        (__attribute__((address_space(3))) unsigned int*)l, 16, 0, 0);
}

#define GQ_BARRIER()  __builtin_amdgcn_s_barrier()
#define GQ_LGKM0()    do { asm volatile("s_waitcnt lgkmcnt(0)" ::: "memory"); \
                           __builtin_amdgcn_sched_barrier(0); } while (0)

// ============================================================================
// 256x256 8-phase bf16 GEMM.  MODE:
//   0 = f32 out pitch N, 1 = bf16 out pitch N,
//   2 = split (q-proj bf16 pitch 3072 | ckv f32 pitch 768),
//   3 = kvb + fused V-transpose (waves 0-3 -> kvb; waves 4-7 -> vT).
//
// ROUND 8: coalesced staging + rule-#21 swizzle.
//   Slot (16 KB) semantic layout: [row 256][cg 4][8 elems], stored at
//   XOR-swizzled offset  off(row,cg) = row*64 + ((cg ^ ((row>>1)&3))*16).
//   - stage: chunk ci covers rows ci*16..+15, 4 lanes/row (one 64B line per
//     4 lanes -> 16 line-requests/instr vs 64 before).  Linear LDS dest
//     (gll16 requirement) + pre-permuted per-lane source col
//     cg = (lane&3) ^ ((lane>>3)&3)  (the same involution).
//   - fragment ds_read: addr = row*32 + (quad*8 ^ ((l15>>1)&3)*8) ushorts;
//     each quarter-wave covers all 8 b128 bank positions exactly 2x (free).
// ============================================================================
template <int MODE>
__global__ __launch_bounds__(512, 2) void gemm256_8ph(
    const ushort* __restrict__ A, const ushort* __restrict__ Bw,
    void* __restrict__ Cv, void* __restrict__ Cv2, int N, int K, int nbx)
{
    __shared__ __align__(16) ushort L[2][2][2][8192];   // 128 KB (slot=16KB)

    const int tid = threadIdx.x;
    const int lane = tid & 63;
    const int w = tid >> 6;
    const int l15 = lane & 15, quad = lane >> 4;
    const int q8 = quad * 8;
    const int rsw8 = ((l15 >> 1) & 3) * 8;    // read-side XOR term (ushorts)

    // XCD-bijective swizzle (gridDim.x % 8 == 0 for all our shapes)
    const int nwg = (int)gridDim.x;
    const int cpx = nwg >> 3;
    const int lin = (int)blockIdx.x;
    const int swz = (lin & 7) * cpx + (lin >> 3);
    const int m0 = (swz / nbx) * 256;
    const int n0 = (swz % nbx) * 256;

    const int wm0 = (w & 3) * 64;     // wave M offset (4 M-frags)
    const int wn0 = (w >> 2) * 128;   // wave N offset (8 N-frags)

    const int NT = K >> 6;            // K-tiles (>= 2 for all our shapes)

    f32x4 acc[4][8];
#pragma unroll
    for (int i = 0; i < 4; ++i)
#pragma unroll
        for (int j = 0; j < 8; ++j) acc[i][j] = (f32x4){0.f, 0.f, 0.f, 0.f};

    // per-lane staging source permutation (write-side involution)
    const int srow = lane >> 2;                        // row within 16-row chunk
    const int scg  = (lane & 3) ^ ((lane >> 3) & 3);   // permuted col-group

    // stage one 16 KB slot (ab, kh) of K-tile kt into buffer buf.
    // chunk ci (0..15) = rows ci*16..+15; wave w takes ci = w, w+8.
    auto stage = [&](int ab, int kh, int kt, int buf) {
#pragma unroll
        for (int j = 0; j < 2; ++j) {
            int ci = w + j * 8;
            ushort* dst = &L[buf][ab][kh][ci * 512 + lane * 8];
            int row = ci * 16 + srow;
            const ushort* src = (ab ? Bw + (size_t)(n0 + row) * K
                                    : A  + (size_t)(m0 + row) * K)
                                + kt * 64 + kh * 32 + scg * 8;
            gll16(src, dst);
        }
    };

    // ---- prologue: tile0 (A0,B0,A1,B1) + tile1 (A0,B0,A1) = 14 loads ----
    stage(0, 0, 0, 0); stage(1, 0, 0, 0); stage(0, 1, 0, 0); stage(1, 1, 0, 0);
    if (NT > 1) { stage(0, 0, 1, 1); stage(1, 0, 1, 1); stage(0, 1, 1, 1); }
    else        { stage(0, 0, 0, 1); stage(1, 0, 0, 1); stage(0, 1, 0, 1); }
    asm volatile("s_waitcnt vmcnt(6)" ::: "memory");
    GQ_BARRIER();

    bf16x8 a[4], b[4];

    for (int t = 0; t < NT; ++t) {
        const int c = t & 1, o = c ^ 1;
        const int kt1 = (t + 1 < NT) ? t + 1 : 0;
        const int kt2 = (t + 2 < NT) ? t + 2 : 0;

        // ---------- q0: (kh0, nh0) ----------
#pragma unroll
        for (int fm = 0; fm < 4; ++fm)
            a[fm] = *(const bf16x8*)&L[c][0][0][(wm0 + fm * 16 + l15) * 32 + (q8 ^ rsw8)];
#pragma unroll
        for (int fn = 0; fn < 4; ++fn)
            b[fn] = *(const bf16x8*)&L[c][1][0][(wn0 + fn * 16 + l15) * 32 + (q8 ^ rsw8)];
        stage(1, 1, kt1, o);
        GQ_BARRIER();
        GQ_LGKM0();
        __builtin_amdgcn_s_setprio(1);
#pragma unroll
        for (int fm = 0; fm < 4; ++fm)
#pragma unroll
            for (int fn = 0; fn < 4; ++fn)
                acc[fm][fn] = __builtin_amdgcn_mfma_f32_16x16x32_bf16(a[fm], b[fn], acc[fm][fn], 0, 0, 0);
        __builtin_amdgcn_s_setprio(0);
        GQ_BARRIER();

        // ---------- q1: (kh0, nh1) ----------
#pragma unroll
        for (int fn = 0; fn < 4; ++fn)
            b[fn] = *(const bf16x8*)&L[c][1][0][(wn0 + 64 + fn * 16 + l15) * 32 + (q8 ^ rsw8)];
        stage(0, 0, kt2, c);
        GQ_BARRIER();
        GQ_LGKM0();
        __builtin_amdgcn_s_setprio(1);
#pragma unroll
        for (int fm = 0; fm < 4; ++fm)
#pragma unroll
            for (int fn = 0; fn < 4; ++fn)
                acc[fm][4 + fn] = __builtin_amdgcn_mfma_f32_16x16x32_bf16(a[fm], b[fn], acc[fm][4 + fn], 0, 0, 0);
        __builtin_amdgcn_s_setprio(0);
        GQ_BARRIER();

        // ---------- q2: (kh1, nh0) ----------
#pragma unroll
        for (int fm = 0; fm < 4; ++fm)
            a[fm] = *(const bf16x8*)&L[c][0][1][(wm0 + fm * 16 + l15) * 32 + (q8 ^ rsw8)];
#pragma unroll
        for (int fn = 0; fn < 4; ++fn)
            b[fn] = *(const bf16x8*)&L[c][1][1][(wn0 + fn * 16 + l15) * 32 + (q8 ^ rsw8)];
        stage(1, 0, kt2, c);
        GQ_BARRIER();
        GQ_LGKM0();
        __builtin_amdgcn_s_setprio(1);
#pragma unroll
        for (int fm = 0; fm < 4; ++fm)
#pragma unroll
            for (int fn = 0; fn < 4; ++fn)
                acc[fm][fn] = __builtin_amdgcn_mfma_f32_16x16x32_bf16(a[fm], b[fn], acc[fm][fn], 0, 0, 0);
        __builtin_amdgcn_s_setprio(0);
        GQ_BARRIER();

        // ---------- q3: (kh1, nh1) ----------
#pragma unroll
        for (int fn = 0; fn < 4; ++fn)
            b[fn] = *(const bf16x8*)&L[c][1][1][(wn0 + 64 + fn * 16 + l15) * 32 + (q8 ^ rsw8)];
        stage(0, 1, kt2, c);
        GQ_BARRIER();
        GQ_LGKM0();
        __builtin_amdgcn_s_setprio(1);
#pragma unroll
        for (int fm = 0; fm < 4; ++fm)
#pragma unroll
            for (int fn = 0; fn < 4; ++fn)
                acc[fm][4 + fn] = __builtin_amdgcn_mfma_f32_16x16x32_bf16(a[fm], b[fn], acc[fm][4 + fn], 0, 0, 0);
        __builtin_amdgcn_s_setprio(0);
        asm volatile("s_waitcnt vmcnt(6)" ::: "memory");
        GQ_BARRIER();
    }

    // ---- epilogue ----
    if (MODE == 3) {
        // Drain outstanding dummy-stage DMAs (they land in L, which we are
        // about to reuse as the transpose buffer), then full barrier.
        asm volatile("s_waitcnt vmcnt(0)" ::: "memory");
        GQ_BARRIER();
        const int h = n0 >> 8;
        if (w < 4) {
            // K-nope half -> kvb (pitch 4096), cols n0 + 0..127
#pragma unroll
            for (int fm = 0; fm < 4; ++fm)
#pragma unroll
                for (int r = 0; r < 4; ++r) {
                    size_t base = (size_t)(m0 + wm0 + fm * 16 + quad * 4 + r) * 4096
                                  + n0 + wn0 + l15;
#pragma unroll
                    for (int fn = 0; fn < 8; ++fn)
                        ((ushort*)Cv)[base + fn * 16] = f2bf(acc[fm][fn][r]);
                }
        } else {
            // V half: LDS-transpose own 64x128 tile, write vT[bh][vd][s].
            // Per-wave private region: [vd 0..127][stride 80 ushorts].
            ushort* T = &L[0][0][0][0] + (size_t)(w - 4) * (128 * 80);
#pragma unroll
            for (int fm = 0; fm < 4; ++fm)
#pragma unroll
                for (int fn = 0; fn < 8; ++fn) {
                    uint32_t lo = (uint32_t)f2bf(acc[fm][fn][0])
                                | ((uint32_t)f2bf(acc[fm][fn][1]) << 16);
                    uint32_t hi2 = (uint32_t)f2bf(acc[fm][fn][2])
                                 | ((uint32_t)f2bf(acc[fm][fn][3]) << 16);
                    uint2 pk; pk.x = lo; pk.y = hi2;
                    *(uint2*)&T[(size_t)(fn * 16 + l15) * 80 + fm * 16 + quad * 4] = pk;
                }
            asm volatile("s_waitcnt lgkmcnt(0)" ::: "memory");
            __builtin_amdgcn_sched_barrier(0);
            const int bh = (m0 >> 11) * 16 + h;
            const int sbase = (m0 & 2047) + (w & 3) * 64;
            ushort* vT = (ushort*)Cv2;
#pragma unroll
            for (int j = 0; j < 16; ++j) {
                int cc = j * 64 + lane;
                int vd = cc >> 3;
                int s8 = (cc & 7) * 8;
                bf16x8 v = *(const bf16x8*)&T[(size_t)vd * 80 + s8];
                *(bf16x8*)(vT + ((size_t)bh * 128 + vd) * 2048 + sbase + s8) = v;
            }
        }
        return;
    }
#pragma unroll
    for (int fm = 0; fm < 4; ++fm)
#pragma unroll
        for (int r = 0; r < 4; ++r) {
            int row = m0 + wm0 + fm * 16 + quad * 4 + r;
            if (MODE == 2) {
                if (n0 < 3072) {
                    size_t base = (size_t)row * 3072 + n0 + wn0 + l15;
#pragma unroll
                    for (int fn = 0; fn < 8; ++fn)
                        ((ushort*)Cv)[base + fn * 16] = f2bf(acc[fm][fn][r]);
                } else {
                    size_t base = (size_t)row * CKV_P_ + (n0 - 3072) + wn0 + l15;
#pragma unroll
                    for (int fn = 0; fn < 8; ++fn)
                        ((float*)Cv2)[base + fn * 16] = acc[fm][fn][r];
                }
            } else {
                size_t base = (size_t)row * N + n0 + wn0 + l15;
#pragma unroll
                for (int fn = 0; fn < 8; ++fn) {
                    float v = acc[fm][fn][r];
                    if (MODE == 1) ((ushort*)Cv)[base + fn * 16] = f2bf(v);
                    else           ((float*)Cv)[base + fn * 16] = v;
                }
            }
        }
}

// ============================================================================
// 256x128-tile GEMM, 2 phases/K-tile, counted-vmcnt pipeline (wo; unchanged)
// ============================================================================
template <int OUT_BF16>
__global__ __launch_bounds__(512, 2) void gemm_bn128(
    const ushort* __restrict__ A, const ushort* __restrict__ Bw,
    void* __restrict__ Cv, int N, int K, int nbx)
{
    __shared__ __align__(16) ushort LA[2][2][4][256][8];   // 64 KB
    __shared__ __align__(16) ushort LB[2][2][4][128][8];   // 32 KB

    const int tid = threadIdx.x;
    const int lane = tid & 63;
    const int w = tid >> 6;
    const int l15 = lane & 15, quad = lane >> 4;

    const int nwg = (int)gridDim.x;
    const int cpx = nwg >> 3;
    const int lin = (int)blockIdx.x;
    const int swz = (lin & 7) * cpx + (lin >> 3);
    const int m0 = (swz / nbx) * 256;
    const int n0 = (swz % nbx) * 128;

    const int wm0 = (w & 3) * 64;
    const int wn0 = (w >> 2) * 64;

    const int NT = K >> 6;

    f32x4 acc[4][4];
#pragma unroll
    for (int i = 0; i < 4; ++i)
#pragma unroll
        for (int j = 0; j < 4; ++j) acc[i][j] = (f32x4){0.f, 0.f, 0.f, 0.f};

    auto stageA = [&](int kh, int kt, int buf) {
#pragma unroll
        for (int j = 0; j < 2; ++j) {
            int ci = w + j * 8;
            int qd = ci >> 2, rg = ci & 3;
            ushort* dst = &LA[buf][kh][qd][rg * 64 + lane][0];
            const ushort* src = A + (size_t)(m0 + rg * 64 + lane) * K
                                + kt * 64 + kh * 32 + qd * 8;
            gll16(src, dst);
        }
    };
    auto stageB = [&](int kt, int buf) {
#pragma unroll
        for (int j = 0; j < 2; ++j) {
            int ci = w + j * 8;
            int kh = ci >> 3, qd = (ci >> 1) & 3, rh = ci & 1;
            ushort* dst = &LB[buf][kh][qd][rh * 64 + lane][0];
            const ushort* src = Bw + (size_t)(n0 + rh * 64 + lane) * K
                                + kt * 64 + kh * 32 + qd * 8;
            gll16(src, dst);
        }
    };

    // ---- prologue: tile0 {A0,A1,B} + A0(tile1) = 8 loads ----
    stageA(0, 0, 0); stageA(1, 0, 0); stageB(0, 0);
    stageA(0, (NT > 1) ? 1 : 0, 1);
    asm volatile("s_waitcnt vmcnt(2)" ::: "memory");
    GQ_BARRIER();

    bf16x8 a[4], b[4];

    for (int t = 0; t < NT; ++t) {
        const int c = t & 1, o = c ^ 1;
        const int kt1 = (t + 1 < NT) ? t + 1 : 0;
        const int kt2 = (t + 2 < NT) ? t + 2 : 0;

        // ---------- ph0 (kh0) ----------
#pragma unroll
        for (int fm = 0; fm < 4; ++fm)
            a[fm] = *(const bf16x8*)&LA[c][0][quad][wm0 + fm * 16 + l15][0];
#pragma unroll
        for (int fn = 0; fn < 4; ++fn)
            b[fn] = *(const bf16x8*)&LB[c][0][quad][wn0 + fn * 16 + l15][0];
        stageA(1, kt1, o); stageB(kt1, o);
        GQ_BARRIER();
        GQ_LGKM0();
        __builtin_amdgcn_s_setprio(1);
#pragma unroll
        for (int fm = 0; fm < 4; ++fm)
#pragma unroll
            for (int fn = 0; fn < 4; ++fn)
                acc[fm][fn] = __builtin_amdgcn_mfma_f32_16x16x32_bf16(a[fm], b[fn], acc[fm][fn], 0, 0, 0);
        __builtin_amdgcn_s_setprio(0);
        GQ_BARRIER();

        // ---------- ph1 (kh1) ----------
#pragma unroll
        for (int fm = 0; fm < 4; ++fm)
            a[fm] = *(const bf16x8*)&LA[c][1][quad][wm0 + fm * 16 + l15][0];
#pragma unroll
        for (int fn = 0; fn < 4; ++fn)
            b[fn] = *(const bf16x8*)&LB[c][1][quad][wn0 + fn * 16 + l15][0];
        stageA(0, kt2, c);
        GQ_BARRIER();
        GQ_LGKM0();
        __builtin_amdgcn_s_setprio(1);
#pragma unroll
        for (int fm = 0; fm < 4; ++fm)
#pragma unroll
            for (int fn = 0; fn < 4; ++fn)
                acc[fm][fn] = __builtin_amdgcn_mfma_f32_16x16x32_bf16(a[fm], b[fn], acc[fm][fn], 0, 0, 0);
        __builtin_amdgcn_s_setprio(0);
        asm volatile("s_waitcnt vmcnt(2)" ::: "memory");   // tile t+1 landed
        GQ_BARRIER();
    }

    // ---- epilogue ----
#pragma unroll
    for (int fm = 0; fm < 4; ++fm)
#pragma unroll
        for (int r = 0; r < 4; ++r) {
            size_t base = (size_t)(m0 + wm0 + fm * 16 + quad * 4 + r) * N + n0 + wn0 + l15;
#pragma unroll
            for (int fn = 0; fn < 4; ++fn) {
                float v = acc[fm][fn][r];
                if (OUT_BF16) ((ushort*)Cv)[base + fn * 16] = f2bf(v);
                else          ((float*)Cv)[base + fn * 16] = v;
            }
        }
}

// ============================================================================
// Fused cast kernel (unchanged)
// ============================================================================
__global__ __launch_bounds__(256) void cast_all(
    const float* __restrict__ x, const float* __restrict__ wq,
    const float* __restrict__ wkva, const float* __restrict__ wkvb,
    const float* __restrict__ wo,
    ushort* __restrict__ xb, ushort* __restrict__ wc,
    ushort* __restrict__ wkvb_bf, ushort* __restrict__ wo_bf)
{
    size_t i = ((size_t)blockIdx.x * 256 + threadIdx.x) * 8;
    const float* s; ushort* d;
    if (i < 8388608)        { s = x + i;                  d = xb + i; }
    else if (i < 14680064)  { s = wq + (i - 8388608);     d = wc + (i - 8388608); }
    else if (i < 15859712)  { s = wkva + (i - 14680064);  d = wc + (i - 8388608); }
    else if (i < 16252928)  {   // zero pad rows 3648..3839 of wc
        ushort4 z = {0, 0, 0, 0};
        ushort* dz = wc + (i - 8388608);
        *(ushort4*)dz = z; *(ushort4*)(dz + 4) = z;
        return;
    }
    else if (i < 18350080)  { s = wkvb + (i - 16252928);  d = wkvb_bf + (i - 16252928); }
    else                    { s = wo + (i - 18350080);    d = wo_bf + (i - 18350080); }
    float4 a = *(const float4*)s;
    float4 b = *(const float4*)(s + 4);
    ushort4 o0, o1;
    o0.x = f2bf(a.x); o0.y = f2bf(a.y); o0.z = f2bf(a.z); o0.w = f2bf(a.w);
    o1.x = f2bf(b.x); o1.y = f2bf(b.y); o1.z = f2bf(b.z); o1.w = f2bf(b.w);
    *(ushort4*)d = o0;
    *(ushort4*)(d + 4) = o1;
}

// ============================================================================
// Fused RMSNorm + RoPE-k (unchanged, pitch 768)
// ============================================================================
__global__ __launch_bounds__(256) void rmsnorm_rope_k(
    const float* __restrict__ ckv, const float* __restrict__ nw,
    const float* __restrict__ rope_cache,
    ushort* __restrict__ cnorm, ushort* __restrict__ krb)
{
    const int lane = threadIdx.x & 63;
    const int row = blockIdx.x * 4 + (threadIdx.x >> 6);
    const float* src = ckv + (size_t)row * CKV_P_;
    float4 a = *(const float4*)(src + lane * 4);
    float4 b = *(const float4*)(src + 256 + lane * 4);
    float ss = a.x*a.x + a.y*a.y + a.z*a.z + a.w*a.w
             + b.x*b.x + b.y*b.y + b.z*b.z + b.w*b.w;
#pragma unroll
    for (int off = 32; off > 0; off >>= 1) ss += __shfl_xor(ss, off, 64);
    float rs = rsqrtf(ss * (1.0f / 512.0f) + EPS_);
    float4 w0 = *(const float4*)(nw + lane * 4);
    float4 w1 = *(const float4*)(nw + 256 + lane * 4);
    ushort* dst = cnorm + (size_t)row * KV_LORA_;
    ushort4 o0, o1;
    o0.x = f2bf(a.x*rs*w0.x); o0.y = f2bf(a.y*rs*w0.y);
    o0.z = f2bf(a.z*rs*w0.z); o0.w = f2bf(a.w*rs*w0.w);
    o1.x = f2bf(b.x*rs*w1.x); o1.y = f2bf(b.y*rs*w1.y);
    o1.z = f2bf(b.z*rs*w1.z); o1.w = f2bf(b.w*rs*w1.w);
    *(ushort4*)(dst + lane * 4) = o0;
    *(ushort4*)(dst + 256 + lane * 4) = o1;

    float v = src[KV_LORA_ + lane];
    float other = __shfl_xor(v, 32, 64);
    float rot = (lane < 32) ? -other : other;
    int s = row & (S_ - 1);
    float c  = rope_cache[s * (2 * ROPE_D_) + lane];
    float sn = rope_cache[s * (2 * ROPE_D_) + ROPE_D_ + lane];
    krb[(size_t)row * ROPE_D_ + lane] = f2bf(v * c + rot * sn);
}

// ============================================================================
// MFMA flash attention v6 (unchanged — passed round 7)
// ============================================================================
__global__ __launch_bounds__(512, 2) void mla_attn_mfma6(
    const ushort* __restrict__ qb, const ushort* __restrict__ kvb,
    const ushort* __restrict__ krb, const ushort* __restrict__ vT,
    const float* __restrict__ rope_cache, ushort* __restrict__ attn)
{
    __shared__ __align__(16) ushort LDSU[40960];   // 80 KB
    const int KFo[2] = {0, 12288};
    const int VFo[2] = {24576, 32768};

    const int tid = threadIdx.x;
    const int lane = tid & 63;
    const int w = tid >> 6;               // wave 0..7
    const int l31 = lane & 31, hi = lane >> 5;
    const int band = w & 3;               // 32-row q band
    const int koff = (w >> 2) * 32;       // k half of 64-row K tile

    const int lin = (int)blockIdx.y * 8 + (int)blockIdx.x;
    const int swz = (lin & 7) * 32 + (lin >> 3);
    const int bh = swz >> 3;
    const int px = swz & 7;
    const int b = bh >> 4, h = bh & 15;
    const size_t bS = (size_t)b * S_;
    const float scale = 0.07216878364870323f;   // 192^-0.5

    auto stage = [&](int kbase, int bufi) {
#pragma unroll
        for (int r = 0; r < 3; ++r) {
            int c = w + r * 8;                 // 0..23 = d8
            ushort* dst = &LDSU[KFo[bufi] + (c * 64 + lane) * 8];
            const ushort* src = (c < 16)
                ? kvb + (bS + kbase + lane) * 4096 + h * 256 + c * 8
                : krb + (bS + kbase + lane) * 64 + (c - 16) * 8;
            gll16(src, dst);
        }
#pragma unroll
        for (int r = 0; r < 2; ++r) {
            int c = w + r * 8;                 // 0..15: s8 = c&7, vd-half = c>>3
            ushort* dst = &LDSU[VFo[bufi] + (((c & 7) * 128) + (c >> 3) * 64 + lane) * 8];
            const ushort* src =
                vT + ((size_t)bh * 128 + (c >> 3) * 64 + lane) * S_ + kbase + (c & 7) * 8;
            gll16(src, dst);
        }
    };

#pragma unroll 1
    for (int hv = 0; hv < 2; ++hv) {
        const int qt = hv ? 15 - px : px;
        const int qbase = qt * 128;
        const int nkt = 2 * qt + 2;
        const int bmin = qbase + band * 32;   // wave's first q row

        stage(0, 0);

        // ---- Q fragments with fused RoPE on chunks 8..11 (cols 128..191) ----
        bf16x8 qf[12];
        {
            const ushort* qrow = qb + (bS + bmin + l31) * (size_t)(H_ * Q_D_) + h * Q_D_;
#pragma unroll
            for (int c = 0; c < 8; ++c)
                qf[c] = *(const bf16x8*)(qrow + c * 16 + hi * 8);
            bf16x8 q8  = *(const bf16x8*)(qrow + 128 + hi * 8);
            bf16x8 q9  = *(const bf16x8*)(qrow + 144 + hi * 8);
            bf16x8 q10 = *(const bf16x8*)(qrow + 160 + hi * 8);
            bf16x8 q11 = *(const bf16x8*)(qrow + 176 + hi * 8);
            const float* rc = rope_cache + (size_t)(bmin + l31) * 128 + hi * 8;
            f32x4 c8a = *(const f32x4*)(rc + 0),  c8b = *(const f32x4*)(rc + 4);
            f32x4 c9a = *(const f32x4*)(rc + 16), c9b = *(const f32x4*)(rc + 20);
            f32x4 cAa = *(const f32x4*)(rc + 32), cAb = *(const f32x4*)(rc + 36);
            f32x4 cBa = *(const f32x4*)(rc + 48), cBb = *(const f32x4*)(rc + 52);
            f32x4 s8a = *(const f32x4*)(rc + 64), s8b = *(const f32x4*)(rc + 68);
            f32x4 s9a = *(const f32x4*)(rc + 80), s9b = *(const f32x4*)(rc + 84);
            f32x4 sAa = *(const f32x4*)(rc + 96), sAb = *(const f32x4*)(rc + 100);
            f32x4 sBa = *(const f32x4*)(rc + 112), sBb = *(const f32x4*)(rc + 116);
            bf16x8 o8, o9, o10, o11;
#pragma unroll
            for (int e = 0; e < 4; ++e) {
                float a8 = bf2f((ushort)q8[e]),  b8 = bf2f((ushort)q8[e + 4]);
                float a9 = bf2f((ushort)q9[e]),  b9 = bf2f((ushort)q9[e + 4]);
                float aA = bf2f((ushort)q10[e]), bA = bf2f((ushort)q10[e + 4]);
                float aB = bf2f((ushort)q11[e]), bB = bf2f((ushort)q11[e + 4]);
                o8[e]      = (short)f2bf(a8 * c8a[e] - aA * s8a[e]);
                o8[e + 4]  = (short)f2bf(b8 * c8b[e] - bA * s8b[e]);
                o9[e]      = (short)f2bf(a9 * c9a[e] - aB * s9a[e]);
                o9[e + 4]  = (short)f2bf(b9 * c9b[e] - bB * s9b[e]);
                o10[e]     = (short)f2bf(aA * cAa[e] + a8 * sAa[e]);
                o10[e + 4] = (short)f2bf(bA * cAb[e] + b8 * sAb[e]);
                o11[e]     = (short)f2bf(aB * cBa[e] + a9 * sBa[e]);
                o11[e + 4] = (short)f2bf(bB * cBb[e] + b9 * sBb[e]);
            }
            qf[8] = o8; qf[9] = o9; qf[10] = o10; qf[11] = o11;
        }

        f32x16 ov[4];
#pragma unroll
        for (int vt = 0; vt < 4; ++vt)
#pragma unroll
            for (int r = 0; r < 16; ++r) ov[vt][r] = 0.f;
        float m_run = -3e38f, lsum = 0.f;

        __syncthreads();                      // tile 0 visible

        for (int kt = 0; kt < nkt; ++kt) {
            const int kb = kt * 64;
            const int cur = kt & 1;
            if (kt + 1 < nkt) stage((kt + 1) * 64, cur ^ 1);

            const int kg = kb + koff;         // wave's 32-k strip start
            if (kg <= bmin + 31) {            // strip not fully masked
                f32x16 sc;
#pragma unroll
                for (int r = 0; r < 16; ++r) sc[r] = 0.f;
                __builtin_amdgcn_s_setprio(1);
#pragma unroll
                for (int c = 0; c < 12; ++c) {
                    bf16x8 kf = *(const bf16x8*)
                        &LDSU[KFo[cur] + ((c * 2 + hi) * 64 + koff + l31) * 8];
                    sc = __builtin_amdgcn_mfma_f32_32x32x16_bf16(kf, qf[c], sc, 0, 0, 0);
                }
                __builtin_amdgcn_s_setprio(0);

                const bool need_mask = (kg == bmin);   // only diagonal strips
                float p[16]; float mx = -3e38f;
#pragma unroll
                for (int r = 0; r < 16; ++r) {
                    float v = sc[r] * scale;
                    if (need_mask) {
                        int kr = (r & 3) + 8 * (r >> 2) + 4 * hi;
                        if (kr > l31) v = -3e38f;
                    }
                    p[r] = v; mx = fmaxf(mx, v);
                }
                mx = fmaxf(mx, __shfl_xor(mx, 32, 64));   // full 64-k row max
                if (!__all(mx - m_run <= 8.0f)) {
                    float mn = fmaxf(mx, m_run);
                    float al = __expf(m_run - mn);
                    m_run = mn; lsum *= al;
#pragma unroll
                    for (int vt = 0; vt < 4; ++vt)
#pragma unroll
                        for (int r = 0; r < 16; ++r) ov[vt][r] *= al;
                }
                float s_loc = 0.f;
#pragma unroll
                for (int r = 0; r < 16; ++r) { p[r] = __expf(p[r] - m_run); s_loc += p[r]; }
                lsum += s_loc + __shfl_xor(s_loc, 32, 64);

                uint32_t w8[8];
#pragma unroll
                for (int m = 0; m < 8; ++m)
                    w8[m] = (uint32_t)f2bf(p[2 * m]) | ((uint32_t)f2bf(p[2 * m + 1]) << 16);
                bf16x8 pb[2];
#pragma unroll
                for (int c = 0; c < 2; ++c) {
                    uint32_t wd[4];
#pragma unroll
                    for (int par = 0; par < 2; ++par) {
                        uint32_t a  = w8[4 * c + par];
                        uint32_t bb = w8[4 * c + 2 + par];
                        uint32_t t  = __shfl_xor(bb, 32, 64);
                        uint32_t t2 = __shfl_xor(a, 32, 64);
                        wd[par]     = hi ? t : a;
                        wd[par + 2] = hi ? bb : t2;
                    }
                    union { uint32_t u[4]; bf16x8 v; } cvt;
                    cvt.u[0] = wd[0]; cvt.u[1] = wd[1]; cvt.u[2] = wd[2]; cvt.u[3] = wd[3];
                    pb[c] = cvt.v;
                }

                __builtin_amdgcn_s_setprio(1);
#pragma unroll
                for (int vt = 0; vt < 4; ++vt)
#pragma unroll
                    for (int c = 0; c < 2; ++c) {
                        bf16x8 vf = *(const bf16x8*)
                            &LDSU[VFo[cur] + (((koff >> 3) + c * 2 + hi) * 128 + vt * 32 + l31) * 8];
                        ov[vt] = __builtin_amdgcn_mfma_f32_32x32x16_bf16(vf, pb[c], ov[vt], 0, 0, 0);
                    }
                __builtin_amdgcn_s_setprio(0);
            }
            __syncthreads();   // publish prefetched tile; WAR-protect buffers
        }

        float* mrg = (float*)LDSU;
        if (w >= 4) {
            float* dst = mrg + (size_t)((w - 4) * 64 + lane) * 68;
#pragma unroll
            for (int vt = 0; vt < 4; ++vt)
#pragma unroll
                for (int g = 0; g < 4; ++g) {
                    f32x4 v4v = { ov[vt][g * 4 + 0], ov[vt][g * 4 + 1],
                                  ov[vt][g * 4 + 2], ov[vt][g * 4 + 3] };
                    *(f32x4*)(dst + vt * 16 + g * 4) = v4v;
                }
            dst[64] = m_run; dst[65] = lsum;
        }
        __syncthreads();
        if (w < 4) {
            const float* srcm = mrg + (size_t)(w * 64 + lane) * 68;
            float mB = srcm[64], lB = srcm[65];
            float M = fmaxf(m_run, mB);
            float eA = __expf(m_run - M), eB = __expf(mB - M);
            float L = lsum * eA + lB * eB;
            float inv = 1.0f / L;
            size_t obase = (bS + bmin + l31) * (size_t)(H_ * V_D_) + h * V_D_;
#pragma unroll
            for (int vt = 0; vt < 4; ++vt)
#pragma unroll
                for (int g = 0; g < 4; ++g) {
                    ushort4 o;
                    o.x = f2bf((ov[vt][g*4+0] * eA + srcm[vt*16+g*4+0] * eB) * inv);
                    o.y = f2bf((ov[vt][g*4+1] * eA + srcm[vt*16+g*4+1] * eB) * inv);
                    o.z = f2bf((ov[vt][g*4+2] * eA + srcm[vt*16+g*4+2] * eB) * inv);
                    o.w = f2bf((ov[vt][g*4+3] * eA + srcm[vt*16+g*4+3] * eB) * inv);
                    *(ushort4*)(attn + obase + vt * 32 + g * 8 + hi * 4) = o;
                }
        }
        __syncthreads();
    }
}

// ============================================================================
// launch — workspace ~138 MB (round-6/7 layout, unchanged)
// ============================================================================
extern "C" void kernel_launch(void* const* d_in, const int* in_sizes, int n_in,
                              void* d_out, int out_size, void* d_ws, size_t ws_size,
                              hipStream_t stream)
{
    const float* x          = (const float*)d_in[0];
    const float* rope_cache = (const float*)d_in[1];
    const float* wq         = (const float*)d_in[2];
    const float* wkva       = (const float*)d_in[3];
    const float* norm_w     = (const float*)d_in[4];
    const float* wkvb       = (const float*)d_in[5];
    const float* wo         = (const float*)d_in[6];
    float* out = (float*)d_out;

    char* p = (char*)d_ws;
    ushort* xb       = (ushort*)p; p += (size_t)BS_ * DIM_ * 2;        // 16.8 MB
    ushort* q_bf     = (ushort*)p; p += (size_t)BS_ * H_ * Q_D_ * 2;   // 25.2 MB
    float*  ckv      = (float*) p; p += (size_t)BS_ * CKV_P_ * 4;      // 12.6 MB
    ushort* cnorm_bf = (ushort*)p; p += (size_t)BS_ * KV_LORA_ * 2;    //  4.2 MB
    ushort* kvb      = (ushort*)p; p += (size_t)BS_ * 4096 * 2;        // 33.6 MB
    ushort* attn_bf  = (ushort*)p; p += (size_t)BS_ * 2048 * 2;        // 16.8 MB
    ushort* krb      = (ushort*)p; p += (size_t)BS_ * ROPE_D_ * 2;     //  0.5 MB
    ushort* wc_bf    = (ushort*)p; p += (size_t)3840 * DIM_ * 2;       // 15.7 MB
    ushort* wkvb_bf  = (ushort*)p; p += (size_t)4096 * KV_LORA_ * 2;   //  4.2 MB
    ushort* wo_bf    = (ushort*)p; p += (size_t)DIM_ * 2048 * 2;       //  8.4 MB
    ushort* vT       = xb;   // alias: xb dead after GEMM 1; same size (16.8 MB)

    // 0. all input casts in one dispatch
    cast_all<<<11008, dim3(256), 0, stream>>>(
        x, wq, wkva, wkvb, wo, xb, wc_bf, wkvb_bf, wo_bf);

    // 1. fused: q_bf = x @ wq^T (bf16) and ckv = x @ wkva^T (fp32, pitch 768)
    gemm256_8ph<2><<<dim3(16 * 15), dim3(512), 0, stream>>>(
        xb, wc_bf, q_bf, ckv, 0, DIM_, 15);
    // 2. cnorm + krb fused
    rmsnorm_rope_k<<<BS_ / 4, dim3(256), 0, stream>>>(
        ckv, norm_w, rope_cache, cnorm_bf, krb);
    // 3. kvb (K-nope) + vT (V transposed) = cnorm @ wkvb^T, fused epilogue
    gemm256_8ph<3><<<dim3(16 * 16), dim3(512), 0, stream>>>(
        cnorm_bf, wkvb_bf, kvb, vT, 4096, KV_LORA_, 16);
    // 4. flash attention v6 (RoPE-q fused) -> attn_bf
    mla_attn_mfma6<<<dim3(8, B_ * H_), dim3(512), 0, stream>>>(
        q_bf, kvb, krb, vT, rope_cache, attn_bf);
    // 5. out = attn @ wo^T        (4096 x 2048 x 2048), fp32, 256 blocks
    gemm_bn128<0><<<dim3(16 * 16), dim3(512), 0, stream>>>(
        attn_bf, wo_bf, out, 2048, 2048, 16);
}

// Round 9
// 340.659 us; speedup vs baseline: 1.9021x; 1.0635x over previous
//
#include <hip/hip_runtime.h>
#include <cstdint>
#include <cstddef>

// ---- problem constants ----
#define B_      2
#define S_      2048
#define DIM_    2048
#define H_      16
#define KV_LORA_ 512
#define NOPE_D_ 128
#define ROPE_D_ 64
#define V_D_    128
#define Q_D_    192          // NOPE_D + ROPE_D
#define EPS_    1e-6f
#define BS_     (B_ * S_)    // 4096 rows
#define CKV_P_  768          // ckv row pitch (576 real cols, padded to 768)

typedef __attribute__((ext_vector_type(8))) short bf16x8;
typedef __attribute__((ext_vector_type(4))) float f32x4;
typedef __attribute__((ext_vector_type(16))) float f32x16;

__device__ __forceinline__ ushort f2bf(float f) {
    union { float f; uint32_t u; } v; v.f = f;
    uint32_t u = v.u + 0x7fff + ((v.u >> 16) & 1);  // RNE
    return (ushort)(u >> 16);
}
__device__ __forceinline__ float bf2f(ushort u) {
    union { uint32_t u; float f; } v; v.u = (uint32_t)u << 16; return v.f;
}
__device__ __forceinline__ void gll16(const void* g, void* l) {
    __builtin_amdgcn_global_load_lds(
        (const __attribute__((address_space(1))) unsigned int*)g,
        (__attribute__((address_space(3))) unsigned int*)l, 16, 0, 0);
}

#define GQ_BARRIER()  __builtin_amdgcn_s_barrier()
#define GQ_LGKM0()    do { asm volatile("s_waitcnt lgkmcnt(0)" ::: "memory"); \
                           __builtin_amdgcn_sched_barrier(0); } while (0)

// ============================================================================
// 256x256 8-phase bf16 GEMM (round-8 coalesced+swizzled staging, proven).
// MODE: 0 = f32 pitch N, 1 = bf16 pitch N,
//       2 = split (q-proj bf16 pitch 3072 | ckv f32 pitch 768),
//       3 = kvb + fused V-transpose.
// ============================================================================
template <int MODE>
__global__ __launch_bounds__(512, 2) void gemm256_8ph(
    const ushort* __restrict__ A, const ushort* __restrict__ Bw,
    void* __restrict__ Cv, void* __restrict__ Cv2, int N, int K, int nbx)
{
    __shared__ __align__(16) ushort L[2][2][2][8192];   // 128 KB (slot=16KB)

    const int tid = threadIdx.x;
    const int lane = tid & 63;
    const int w = tid >> 6;
    const int l15 = lane & 15, quad = lane >> 4;
    const int q8 = quad * 8;
    const int rsw8 = ((l15 >> 1) & 3) * 8;    // read-side XOR term (ushorts)

    const int nwg = (int)gridDim.x;
    const int cpx = nwg >> 3;
    const int lin = (int)blockIdx.x;
    const int swz = (lin & 7) * cpx + (lin >> 3);
    const int m0 = (swz / nbx) * 256;
    const int n0 = (swz % nbx) * 256;

    const int wm0 = (w & 3) * 64;
    const int wn0 = (w >> 2) * 128;

    const int NT = K >> 6;

    f32x4 acc[4][8];
#pragma unroll
    for (int i = 0; i < 4; ++i)
#pragma unroll
        for (int j = 0; j < 8; ++j) acc[i][j] = (f32x4){0.f, 0.f, 0.f, 0.f};

    const int srow = lane >> 2;                        // row within 16-row chunk
    const int scg  = (lane & 3) ^ ((lane >> 3) & 3);   // permuted col-group

    auto stage = [&](int ab, int kh, int kt, int buf) {
#pragma unroll
        for (int j = 0; j < 2; ++j) {
            int ci = w + j * 8;
            ushort* dst = &L[buf][ab][kh][ci * 512 + lane * 8];
            int row = ci * 16 + srow;
            const ushort* src = (ab ? Bw + (size_t)(n0 + row) * K
                                    : A  + (size_t)(m0 + row) * K)
                                + kt * 64 + kh * 32 + scg * 8;
            gll16(src, dst);
        }
    };

    // ---- prologue ----
    stage(0, 0, 0, 0); stage(1, 0, 0, 0); stage(0, 1, 0, 0); stage(1, 1, 0, 0);
    if (NT > 1) { stage(0, 0, 1, 1); stage(1, 0, 1, 1); stage(0, 1, 1, 1); }
    else        { stage(0, 0, 0, 1); stage(1, 0, 0, 1); stage(0, 1, 0, 1); }
    asm volatile("s_waitcnt vmcnt(6)" ::: "memory");
    GQ_BARRIER();

    bf16x8 a[4], b[4];

    for (int t = 0; t < NT; ++t) {
        const int c = t & 1, o = c ^ 1;
        const int kt1 = (t + 1 < NT) ? t + 1 : 0;
        const int kt2 = (t + 2 < NT) ? t + 2 : 0;

        // ---------- q0 ----------
#pragma unroll
        for (int fm = 0; fm < 4; ++fm)
            a[fm] = *(const bf16x8*)&L[c][0][0][(wm0 + fm * 16 + l15) * 32 + (q8 ^ rsw8)];
#pragma unroll
        for (int fn = 0; fn < 4; ++fn)
            b[fn] = *(const bf16x8*)&L[c][1][0][(wn0 + fn * 16 + l15) * 32 + (q8 ^ rsw8)];
        stage(1, 1, kt1, o);
        GQ_BARRIER();
        GQ_LGKM0();
        __builtin_amdgcn_s_setprio(1);
#pragma unroll
        for (int fm = 0; fm < 4; ++fm)
#pragma unroll
            for (int fn = 0; fn < 4; ++fn)
                acc[fm][fn] = __builtin_amdgcn_mfma_f32_16x16x32_bf16(a[fm], b[fn], acc[fm][fn], 0, 0, 0);
        __builtin_amdgcn_s_setprio(0);
        GQ_BARRIER();

        // ---------- q1 ----------
#pragma unroll
        for (int fn = 0; fn < 4; ++fn)
            b[fn] = *(const bf16x8*)&L[c][1][0][(wn0 + 64 + fn * 16 + l15) * 32 + (q8 ^ rsw8)];
        stage(0, 0, kt2, c);
        GQ_BARRIER();
        GQ_LGKM0();
        __builtin_amdgcn_s_setprio(1);
#pragma unroll
        for (int fm = 0; fm < 4; ++fm)
#pragma unroll
            for (int fn = 0; fn < 4; ++fn)
                acc[fm][4 + fn] = __builtin_amdgcn_mfma_f32_16x16x32_bf16(a[fm], b[fn], acc[fm][4 + fn], 0, 0, 0);
        __builtin_amdgcn_s_setprio(0);
        GQ_BARRIER();

        // ---------- q2 ----------
#pragma unroll
        for (int fm = 0; fm < 4; ++fm)
            a[fm] = *(const bf16x8*)&L[c][0][1][(wm0 + fm * 16 + l15) * 32 + (q8 ^ rsw8)];
#pragma unroll
        for (int fn = 0; fn < 4; ++fn)
            b[fn] = *(const bf16x8*)&L[c][1][1][(wn0 + fn * 16 + l15) * 32 + (q8 ^ rsw8)];
        stage(1, 0, kt2, c);
        GQ_BARRIER();
        GQ_LGKM0();
        __builtin_amdgcn_s_setprio(1);
#pragma unroll
        for (int fm = 0; fm < 4; ++fm)
#pragma unroll
            for (int fn = 0; fn < 4; ++fn)
                acc[fm][fn] = __builtin_amdgcn_mfma_f32_16x16x32_bf16(a[fm], b[fn], acc[fm][fn], 0, 0, 0);
        __builtin_amdgcn_s_setprio(0);
        GQ_BARRIER();

        // ---------- q3 ----------
#pragma unroll
        for (int fn = 0; fn < 4; ++fn)
            b[fn] = *(const bf16x8*)&L[c][1][1][(wn0 + 64 + fn * 16 + l15) * 32 + (q8 ^ rsw8)];
        stage(0, 1, kt2, c);
        GQ_BARRIER();
        GQ_LGKM0();
        __builtin_amdgcn_s_setprio(1);
#pragma unroll
        for (int fm = 0; fm < 4; ++fm)
#pragma unroll
            for (int fn = 0; fn < 4; ++fn)
                acc[fm][4 + fn] = __builtin_amdgcn_mfma_f32_16x16x32_bf16(a[fm], b[fn], acc[fm][4 + fn], 0, 0, 0);
        __builtin_amdgcn_s_setprio(0);
        asm volatile("s_waitcnt vmcnt(6)" ::: "memory");
        GQ_BARRIER();
    }

    // ---- epilogue ----
    if (MODE == 3) {
        asm volatile("s_waitcnt vmcnt(0)" ::: "memory");
        GQ_BARRIER();
        const int h = n0 >> 8;
        if (w < 4) {
#pragma unroll
            for (int fm = 0; fm < 4; ++fm)
#pragma unroll
                for (int r = 0; r < 4; ++r) {
                    size_t base = (size_t)(m0 + wm0 + fm * 16 + quad * 4 + r) * 4096
                                  + n0 + wn0 + l15;
#pragma unroll
                    for (int fn = 0; fn < 8; ++fn)
                        ((ushort*)Cv)[base + fn * 16] = f2bf(acc[fm][fn][r]);
                }
        } else {
            ushort* T = &L[0][0][0][0] + (size_t)(w - 4) * (128 * 80);
#pragma unroll
            for (int fm = 0; fm < 4; ++fm)
#pragma unroll
                for (int fn = 0; fn < 8; ++fn) {
                    uint32_t lo = (uint32_t)f2bf(acc[fm][fn][0])
                                | ((uint32_t)f2bf(acc[fm][fn][1]) << 16);
                    uint32_t hi2 = (uint32_t)f2bf(acc[fm][fn][2])
                                 | ((uint32_t)f2bf(acc[fm][fn][3]) << 16);
                    uint2 pk; pk.x = lo; pk.y = hi2;
                    *(uint2*)&T[(size_t)(fn * 16 + l15) * 80 + fm * 16 + quad * 4] = pk;
                }
            asm volatile("s_waitcnt lgkmcnt(0)" ::: "memory");
            __builtin_amdgcn_sched_barrier(0);
            const int bh = (m0 >> 11) * 16 + h;
            const int sbase = (m0 & 2047) + (w & 3) * 64;
            ushort* vT = (ushort*)Cv2;
#pragma unroll
            for (int j = 0; j < 16; ++j) {
                int cc = j * 64 + lane;
                int vd = cc >> 3;
                int s8 = (cc & 7) * 8;
                bf16x8 v = *(const bf16x8*)&T[(size_t)vd * 80 + s8];
                *(bf16x8*)(vT + ((size_t)bh * 128 + vd) * 2048 + sbase + s8) = v;
            }
        }
        return;
    }
#pragma unroll
    for (int fm = 0; fm < 4; ++fm)
#pragma unroll
        for (int r = 0; r < 4; ++r) {
            int row = m0 + wm0 + fm * 16 + quad * 4 + r;
            if (MODE == 2) {
                if (n0 < 3072) {
                    size_t base = (size_t)row * 3072 + n0 + wn0 + l15;
#pragma unroll
                    for (int fn = 0; fn < 8; ++fn)
                        ((ushort*)Cv)[base + fn * 16] = f2bf(acc[fm][fn][r]);
                } else {
                    size_t base = (size_t)row * CKV_P_ + (n0 - 3072) + wn0 + l15;
#pragma unroll
                    for (int fn = 0; fn < 8; ++fn)
                        ((float*)Cv2)[base + fn * 16] = acc[fm][fn][r];
                }
            } else {
                size_t base = (size_t)row * N + n0 + wn0 + l15;
#pragma unroll
                for (int fn = 0; fn < 8; ++fn) {
                    float v = acc[fm][fn][r];
                    if (MODE == 1) ((ushort*)Cv)[base + fn * 16] = f2bf(v);
                    else           ((float*)Cv)[base + fn * 16] = v;
                }
            }
        }
}

// ============================================================================
// 256x128-tile GEMM, 2 phases/K-tile (wo).  ROUND 9: same coalesced+swizzled
// staging as gemm256 (round-8-proven math).  LA slot [256 rows][4cg][8];
// LB per-kh slot [128 rows][4cg][8].  Load counts unchanged -> vmcnt(2) intact.
// ============================================================================
template <int OUT_BF16>
__global__ __launch_bounds__(512, 2) void gemm_bn128(
    const ushort* __restrict__ A, const ushort* __restrict__ Bw,
    void* __restrict__ Cv, int N, int K, int nbx)
{
    __shared__ __align__(16) ushort LA[2][2][8192];   // 64 KB
    __shared__ __align__(16) ushort LB[2][2][4096];   // 32 KB

    const int tid = threadIdx.x;
    const int lane = tid & 63;
    const int w = tid >> 6;
    const int l15 = lane & 15, quad = lane >> 4;
    const int q8 = quad * 8;
    const int rsw8 = ((l15 >> 1) & 3) * 8;

    const int nwg = (int)gridDim.x;
    const int cpx = nwg >> 3;
    const int lin = (int)blockIdx.x;
    const int swz = (lin & 7) * cpx + (lin >> 3);
    const int m0 = (swz / nbx) * 256;
    const int n0 = (swz % nbx) * 128;

    const int wm0 = (w & 3) * 64;
    const int wn0 = (w >> 2) * 64;

    const int NT = K >> 6;

    f32x4 acc[4][4];
#pragma unroll
    for (int i = 0; i < 4; ++i)
#pragma unroll
        for (int j = 0; j < 4; ++j) acc[i][j] = (f32x4){0.f, 0.f, 0.f, 0.f};

    const int srow = lane >> 2;
    const int scg  = (lane & 3) ^ ((lane >> 3) & 3);

    auto stageA = [&](int kh, int kt, int buf) {
#pragma unroll
        for (int j = 0; j < 2; ++j) {
            int ci = w + j * 8;
            ushort* dst = &LA[buf][kh][ci * 512 + lane * 8];
            int row = ci * 16 + srow;
            const ushort* src = A + (size_t)(m0 + row) * K
                                + kt * 64 + kh * 32 + scg * 8;
            gll16(src, dst);
        }
    };
    auto stageB = [&](int kt, int buf) {
#pragma unroll
        for (int j = 0; j < 2; ++j) {         // j = kh
            ushort* dst = &LB[buf][j][(w * 64 + lane) * 8];
            int row = w * 16 + srow;
            const ushort* src = Bw + (size_t)(n0 + row) * K
                                + kt * 64 + j * 32 + scg * 8;
            gll16(src, dst);
        }
    };

    // ---- prologue: tile0 {A0,A1,B} + A0(tile1) = 8 loads ----
    stageA(0, 0, 0); stageA(1, 0, 0); stageB(0, 0);
    stageA(0, (NT > 1) ? 1 : 0, 1);
    asm volatile("s_waitcnt vmcnt(2)" ::: "memory");
    GQ_BARRIER();

    bf16x8 a[4], b[4];

    for (int t = 0; t < NT; ++t) {
        const int c = t & 1, o = c ^ 1;
        const int kt1 = (t + 1 < NT) ? t + 1 : 0;
        const int kt2 = (t + 2 < NT) ? t + 2 : 0;

        // ---------- ph0 (kh0) ----------
#pragma unroll
        for (int fm = 0; fm < 4; ++fm)
            a[fm] = *(const bf16x8*)&LA[c][0][(wm0 + fm * 16 + l15) * 32 + (q8 ^ rsw8)];
#pragma unroll
        for (int fn = 0; fn < 4; ++fn)
            b[fn] = *(const bf16x8*)&LB[c][0][(wn0 + fn * 16 + l15) * 32 + (q8 ^ rsw8)];
        stageA(1, kt1, o); stageB(kt1, o);
        GQ_BARRIER();
        GQ_LGKM0();
        __builtin_amdgcn_s_setprio(1);
#pragma unroll
        for (int fm = 0; fm < 4; ++fm)
#pragma unroll
            for (int fn = 0; fn < 4; ++fn)
                acc[fm][fn] = __builtin_amdgcn_mfma_f32_16x16x32_bf16(a[fm], b[fn], acc[fm][fn], 0, 0, 0);
        __builtin_amdgcn_s_setprio(0);
        GQ_BARRIER();

        // ---------- ph1 (kh1) ----------
#pragma unroll
        for (int fm = 0; fm < 4; ++fm)
            a[fm] = *(const bf16x8*)&LA[c][1][(wm0 + fm * 16 + l15) * 32 + (q8 ^ rsw8)];
#pragma unroll
        for (int fn = 0; fn < 4; ++fn)
            b[fn] = *(const bf16x8*)&LB[c][1][(wn0 + fn * 16 + l15) * 32 + (q8 ^ rsw8)];
        stageA(0, kt2, c);
        GQ_BARRIER();
        GQ_LGKM0();
        __builtin_amdgcn_s_setprio(1);
#pragma unroll
        for (int fm = 0; fm < 4; ++fm)
#pragma unroll
            for (int fn = 0; fn < 4; ++fn)
                acc[fm][fn] = __builtin_amdgcn_mfma_f32_16x16x32_bf16(a[fm], b[fn], acc[fm][fn], 0, 0, 0);
        __builtin_amdgcn_s_setprio(0);
        asm volatile("s_waitcnt vmcnt(2)" ::: "memory");
        GQ_BARRIER();
    }

    // ---- epilogue ----
#pragma unroll
    for (int fm = 0; fm < 4; ++fm)
#pragma unroll
        for (int r = 0; r < 4; ++r) {
            size_t base = (size_t)(m0 + wm0 + fm * 16 + quad * 4 + r) * N + n0 + wn0 + l15;
#pragma unroll
            for (int fn = 0; fn < 4; ++fn) {
                float v = acc[fm][fn][r];
                if (OUT_BF16) ((ushort*)Cv)[base + fn * 16] = f2bf(v);
                else          ((float*)Cv)[base + fn * 16] = v;
            }
        }
}

// ============================================================================
// Fused cast kernel (unchanged)
// ============================================================================
__global__ __launch_bounds__(256) void cast_all(
    const float* __restrict__ x, const float* __restrict__ wq,
    const float* __restrict__ wkva, const float* __restrict__ wkvb,
    const float* __restrict__ wo,
    ushort* __restrict__ xb, ushort* __restrict__ wc,
    ushort* __restrict__ wkvb_bf, ushort* __restrict__ wo_bf)
{
    size_t i = ((size_t)blockIdx.x * 256 + threadIdx.x) * 8;
    const float* s; ushort* d;
    if (i < 8388608)        { s = x + i;                  d = xb + i; }
    else if (i < 14680064)  { s = wq + (i - 8388608);     d = wc + (i - 8388608); }
    else if (i < 15859712)  { s = wkva + (i - 14680064);  d = wc + (i - 8388608); }
    else if (i < 16252928)  {
        ushort4 z = {0, 0, 0, 0};
        ushort* dz = wc + (i - 8388608);
        *(ushort4*)dz = z; *(ushort4*)(dz + 4) = z;
        return;
    }
    else if (i < 18350080)  { s = wkvb + (i - 16252928);  d = wkvb_bf + (i - 16252928); }
    else                    { s = wo + (i - 18350080);    d = wo_bf + (i - 18350080); }
    float4 a = *(const float4*)s;
    float4 b = *(const float4*)(s + 4);
    ushort4 o0, o1;
    o0.x = f2bf(a.x); o0.y = f2bf(a.y); o0.z = f2bf(a.z); o0.w = f2bf(a.w);
    o1.x = f2bf(b.x); o1.y = f2bf(b.y); o1.z = f2bf(b.z); o1.w = f2bf(b.w);
    *(ushort4*)d = o0;
    *(ushort4*)(d + 4) = o1;
}

// ============================================================================
// Fused RMSNorm + RoPE-k (unchanged, pitch 768)
// ============================================================================
__global__ __launch_bounds__(256) void rmsnorm_rope_k(
    const float* __restrict__ ckv, const float* __restrict__ nw,
    const float* __restrict__ rope_cache,
    ushort* __restrict__ cnorm, ushort* __restrict__ krb)
{
    const int lane = threadIdx.x & 63;
    const int row = blockIdx.x * 4 + (threadIdx.x >> 6);
    const float* src = ckv + (size_t)row * CKV_P_;
    float4 a = *(const float4*)(src + lane * 4);
    float4 b = *(const float4*)(src + 256 + lane * 4);
    float ss = a.x*a.x + a.y*a.y + a.z*a.z + a.w*a.w
             + b.x*b.x + b.y*b.y + b.z*b.z + b.w*b.w;
#pragma unroll
    for (int off = 32; off > 0; off >>= 1) ss += __shfl_xor(ss, off, 64);
    float rs = rsqrtf(ss * (1.0f / 512.0f) + EPS_);
    float4 w0 = *(const float4*)(nw + lane * 4);
    float4 w1 = *(const float4*)(nw + 256 + lane * 4);
    ushort* dst = cnorm + (size_t)row * KV_LORA_;
    ushort4 o0, o1;
    o0.x = f2bf(a.x*rs*w0.x); o0.y = f2bf(a.y*rs*w0.y);
    o0.z = f2bf(a.z*rs*w0.z); o0.w = f2bf(a.w*rs*w0.w);
    o1.x = f2bf(b.x*rs*w1.x); o1.y = f2bf(b.y*rs*w1.y);
    o1.z = f2bf(b.z*rs*w1.z); o1.w = f2bf(b.w*rs*w1.w);
    *(ushort4*)(dst + lane * 4) = o0;
    *(ushort4*)(dst + 256 + lane * 4) = o1;

    float v = src[KV_LORA_ + lane];
    float other = __shfl_xor(v, 32, 64);
    float rot = (lane < 32) ? -other : other;
    int s = row & (S_ - 1);
    float c  = rope_cache[s * (2 * ROPE_D_) + lane];
    float sn = rope_cache[s * (2 * ROPE_D_) + ROPE_D_ + lane];
    krb[(size_t)row * ROPE_D_ + lane] = f2bf(v * c + rot * sn);
}

// ============================================================================
// MFMA flash attention v7 = v6 + coalesced, XOR-swizzled K/V staging.
//  LDS (ushorts): Kn[2][64 rows][16 ch] @ {0,8192}   (chunk ^= row&7)
//                 Kr[2][64 rows][8 ch]  @ {16384,20480}
//                 Vv[2][128 rows][8 ch] @ {24576,32768}
//  Staging: 16/8/8 lanes-per-row => 16 line-requests/instr (was 64).
//  Source pre-permuted with the same involution (rule #21).
//  Reads: Kn 2-way (free); Kr/Vv residual 4-way (m214 pattern, measured ok).
// ============================================================================
__global__ __launch_bounds__(512, 2) void mla_attn_mfma7(
    const ushort* __restrict__ qb, const ushort* __restrict__ kvb,
    const ushort* __restrict__ krb, const ushort* __restrict__ vT,
    const float* __restrict__ rope_cache, ushort* __restrict__ attn)
{
    __shared__ __align__(16) ushort LDSU[40960];   // 80 KB
    const int KNo[2] = {0, 8192};
    const int KRo[2] = {16384, 20480};
    const int VVo[2] = {24576, 32768};

    const int tid = threadIdx.x;
    const int lane = tid & 63;
    const int w = tid >> 6;               // wave 0..7
    const int l31 = lane & 31, hi = lane >> 5;
    const int band = w & 3;               // 32-row q band
    const int koff = (w >> 2) * 32;       // k half of 64-row K tile

    const int lin = (int)blockIdx.y * 8 + (int)blockIdx.x;
    const int swz = (lin & 7) * 32 + (lin >> 3);
    const int bh = swz >> 3;
    const int px = swz & 7;
    const int b = bh >> 4, h = bh & 15;
    const size_t bS = (size_t)b * S_;
    const float scale = 0.07216878364870323f;   // 192^-0.5

    auto stage = [&](int kbase, int bufi) {
        // K-nope: 64 rows x 16 chunks, 16 lanes/row
#pragma unroll
        for (int j = 0; j < 2; ++j) {
            int g = (j * 8 + w) * 64 + lane;
            int row = g >> 4;
            int d8 = (g & 15) ^ (row & 7);
            ushort* dst = &LDSU[KNo[bufi] + g * 8];
            const ushort* src = kvb + (bS + kbase + row) * 4096 + h * 256 + d8 * 8;
            gll16(src, dst);
        }
        // K-rope: 64 rows x 8 chunks, 8 lanes/row
        {
            int g = w * 64 + lane;
            int row = g >> 3;
            int r8 = (g & 7) ^ (row & 7);
            ushort* dst = &LDSU[KRo[bufi] + g * 8];
            const ushort* src = krb + (bS + kbase + row) * 64 + r8 * 8;
            gll16(src, dst);
        }
        // V: 128 vd-rows x 8 chunks, 8 lanes/row
#pragma unroll
        for (int j = 0; j < 2; ++j) {
            int g = (j * 8 + w) * 64 + lane;
            int vd = g >> 3;
            int kc = (g & 7) ^ (vd & 7);
            ushort* dst = &LDSU[VVo[bufi] + g * 8];
            const ushort* src = vT + ((size_t)bh * 128 + vd) * 2048 + kbase + kc * 8;
            gll16(src, dst);
        }
    };

#pragma unroll 1
    for (int hv = 0; hv < 2; ++hv) {
        const int qt = hv ? 15 - px : px;
        const int qbase = qt * 128;
        const int nkt = 2 * qt + 2;
        const int bmin = qbase + band * 32;   // wave's first q row

        stage(0, 0);

        // ---- Q fragments with fused RoPE on chunks 8..11 (cols 128..191) ----
        bf16x8 qf[12];
        {
            const ushort* qrow = qb + (bS + bmin + l31) * (size_t)(H_ * Q_D_) + h * Q_D_;
#pragma unroll
            for (int c = 0; c < 8; ++c)
                qf[c] = *(const bf16x8*)(qrow + c * 16 + hi * 8);
            bf16x8 q8  = *(const bf16x8*)(qrow + 128 + hi * 8);
            bf16x8 q9  = *(const bf16x8*)(qrow + 144 + hi * 8);
            bf16x8 q10 = *(const bf16x8*)(qrow + 160 + hi * 8);
            bf16x8 q11 = *(const bf16x8*)(qrow + 176 + hi * 8);
            const float* rc = rope_cache + (size_t)(bmin + l31) * 128 + hi * 8;
            f32x4 c8a = *(const f32x4*)(rc + 0),  c8b = *(const f32x4*)(rc + 4);
            f32x4 c9a = *(const f32x4*)(rc + 16), c9b = *(const f32x4*)(rc + 20);
            f32x4 cAa = *(const f32x4*)(rc + 32), cAb = *(const f32x4*)(rc + 36);
            f32x4 cBa = *(const f32x4*)(rc + 48), cBb = *(const f32x4*)(rc + 52);
            f32x4 s8a = *(const f32x4*)(rc + 64), s8b = *(const f32x4*)(rc + 68);
            f32x4 s9a = *(const f32x4*)(rc + 80), s9b = *(const f32x4*)(rc + 84);
            f32x4 sAa = *(const f32x4*)(rc + 96), sAb = *(const f32x4*)(rc + 100);
            f32x4 sBa = *(const f32x4*)(rc + 112), sBb = *(const f32x4*)(rc + 116);
            bf16x8 o8, o9, o10, o11;
#pragma unroll
            for (int e = 0; e < 4; ++e) {
                float a8 = bf2f((ushort)q8[e]),  b8 = bf2f((ushort)q8[e + 4]);
                float a9 = bf2f((ushort)q9[e]),  b9 = bf2f((ushort)q9[e + 4]);
                float aA = bf2f((ushort)q10[e]), bA = bf2f((ushort)q10[e + 4]);
                float aB = bf2f((ushort)q11[e]), bB = bf2f((ushort)q11[e + 4]);
                o8[e]      = (short)f2bf(a8 * c8a[e] - aA * s8a[e]);
                o8[e + 4]  = (short)f2bf(b8 * c8b[e] - bA * s8b[e]);
                o9[e]      = (short)f2bf(a9 * c9a[e] - aB * s9a[e]);
                o9[e + 4]  = (short)f2bf(b9 * c9b[e] - bB * s9b[e]);
                o10[e]     = (short)f2bf(aA * cAa[e] + a8 * sAa[e]);
                o10[e + 4] = (short)f2bf(bA * cAb[e] + b8 * sAb[e]);
                o11[e]     = (short)f2bf(aB * cBa[e] + a9 * sBa[e]);
                o11[e + 4] = (short)f2bf(bB * cBb[e] + b9 * sBb[e]);
            }
            qf[8] = o8; qf[9] = o9; qf[10] = o10; qf[11] = o11;
        }

        f32x16 ov[4];
#pragma unroll
        for (int vt = 0; vt < 4; ++vt)
#pragma unroll
            for (int r = 0; r < 16; ++r) ov[vt][r] = 0.f;
        float m_run = -3e38f, lsum = 0.f;

        __syncthreads();                      // tile 0 visible

        const int krow = koff + l31;
        const int kx7 = krow & 7;
        const int vx7 = l31 & 7;

        for (int kt = 0; kt < nkt; ++kt) {
            const int kb = kt * 64;
            const int cur = kt & 1;
            if (kt + 1 < nkt) stage((kt + 1) * 64, cur ^ 1);

            const int kg = kb + koff;         // wave's 32-k strip start
            if (kg <= bmin + 31) {            // strip not fully masked
                f32x16 sc;
#pragma unroll
                for (int r = 0; r < 16; ++r) sc[r] = 0.f;
                __builtin_amdgcn_s_setprio(1);
#pragma unroll
                for (int c = 0; c < 12; ++c) {
                    const bf16x8* kp;
                    if (c < 8)
                        kp = (const bf16x8*)&LDSU[KNo[cur] + (krow * 16 + ((c * 2 + hi) ^ kx7)) * 8];
                    else
                        kp = (const bf16x8*)&LDSU[KRo[cur] + (krow * 8 + (((c - 8) * 2 + hi) ^ kx7)) * 8];
                    sc = __builtin_amdgcn_mfma_f32_32x32x16_bf16(*kp, qf[c], sc, 0, 0, 0);
                }
                __builtin_amdgcn_s_setprio(0);

                const bool need_mask = (kg == bmin);   // only diagonal strips
                float p[16]; float mx = -3e38f;
#pragma unroll
                for (int r = 0; r < 16; ++r) {
                    float v = sc[r] * scale;
                    if (need_mask) {
                        int kr = (r & 3) + 8 * (r >> 2) + 4 * hi;
                        if (kr > l31) v = -3e38f;
                    }
                    p[r] = v; mx = fmaxf(mx, v);
                }
                mx = fmaxf(mx, __shfl_xor(mx, 32, 64));   // full 64-k row max
                if (!__all(mx - m_run <= 8.0f)) {
                    float mn = fmaxf(mx, m_run);
                    float al = __expf(m_run - mn);
                    m_run = mn; lsum *= al;
#pragma unroll
                    for (int vt = 0; vt < 4; ++vt)
#pragma unroll
                        for (int r = 0; r < 16; ++r) ov[vt][r] *= al;
                }
                float s_loc = 0.f;
#pragma unroll
                for (int r = 0; r < 16; ++r) { p[r] = __expf(p[r] - m_run); s_loc += p[r]; }
                lsum += s_loc + __shfl_xor(s_loc, 32, 64);

                uint32_t w8[8];
#pragma unroll
                for (int m = 0; m < 8; ++m)
                    w8[m] = (uint32_t)f2bf(p[2 * m]) | ((uint32_t)f2bf(p[2 * m + 1]) << 16);
                bf16x8 pb[2];
#pragma unroll
                for (int c = 0; c < 2; ++c) {
                    uint32_t wd[4];
#pragma unroll
                    for (int par = 0; par < 2; ++par) {
                        uint32_t a  = w8[4 * c + par];
                        uint32_t bb = w8[4 * c + 2 + par];
                        uint32_t t  = __shfl_xor(bb, 32, 64);
                        uint32_t t2 = __shfl_xor(a, 32, 64);
                        wd[par]     = hi ? t : a;
                        wd[par + 2] = hi ? bb : t2;
                    }
                    union { uint32_t u[4]; bf16x8 v; } cvt;
                    cvt.u[0] = wd[0]; cvt.u[1] = wd[1]; cvt.u[2] = wd[2]; cvt.u[3] = wd[3];
                    pb[c] = cvt.v;
                }

                __builtin_amdgcn_s_setprio(1);
#pragma unroll
                for (int vt = 0; vt < 4; ++vt)
#pragma unroll
                    for (int cc = 0; cc < 2; ++cc) {
                        int vd = vt * 32 + l31;
                        int k8 = (koff >> 3) + cc * 2 + hi;
                        bf16x8 vf = *(const bf16x8*)
                            &LDSU[VVo[cur] + (vd * 8 + (k8 ^ vx7)) * 8];
                        ov[vt] = __builtin_amdgcn_mfma_f32_32x32x16_bf16(vf, pb[cc], ov[vt], 0, 0, 0);
                    }
                __builtin_amdgcn_s_setprio(0);
            }
            __syncthreads();   // publish prefetched tile; WAR-protect buffers
        }

        float* mrg = (float*)LDSU;
        if (w >= 4) {
            float* dst = mrg + (size_t)((w - 4) * 64 + lane) * 68;
#pragma unroll
            for (int vt = 0; vt < 4; ++vt)
#pragma unroll
                for (int g = 0; g < 4; ++g) {
                    f32x4 v4v = { ov[vt][g * 4 + 0], ov[vt][g * 4 + 1],
                                  ov[vt][g * 4 + 2], ov[vt][g * 4 + 3] };
                    *(f32x4*)(dst + vt * 16 + g * 4) = v4v;
                }
            dst[64] = m_run; dst[65] = lsum;
        }
        __syncthreads();
        if (w < 4) {
            const float* srcm = mrg + (size_t)(w * 64 + lane) * 68;
            float mB = srcm[64], lB = srcm[65];
            float M = fmaxf(m_run, mB);
            float eA = __expf(m_run - M), eB = __expf(mB - M);
            float L = lsum * eA + lB * eB;
            float inv = 1.0f / L;
            size_t obase = (bS + bmin + l31) * (size_t)(H_ * V_D_) + h * V_D_;
#pragma unroll
            for (int vt = 0; vt < 4; ++vt)
#pragma unroll
                for (int g = 0; g < 4; ++g) {
                    ushort4 o;
                    o.x = f2bf((ov[vt][g*4+0] * eA + srcm[vt*16+g*4+0] * eB) * inv);
                    o.y = f2bf((ov[vt][g*4+1] * eA + srcm[vt*16+g*4+1] * eB) * inv);
                    o.z = f2bf((ov[vt][g*4+2] * eA + srcm[vt*16+g*4+2] * eB) * inv);
                    o.w = f2bf((ov[vt][g*4+3] * eA + srcm[vt*16+g*4+3] * eB) * inv);
                    *(ushort4*)(attn + obase + vt * 32 + g * 8 + hi * 4) = o;
                }
        }
        __syncthreads();
    }
}

// ============================================================================
// launch — workspace ~138 MB (round-6/7/8 layout, unchanged)
// ============================================================================
extern "C" void kernel_launch(void* const* d_in, const int* in_sizes, int n_in,
                              void* d_out, int out_size, void* d_ws, size_t ws_size,
                              hipStream_t stream)
{
    const float* x          = (const float*)d_in[0];
    const float* rope_cache = (const float*)d_in[1];
    const float* wq         = (const float*)d_in[2];
    const float* wkva       = (const float*)d_in[3];
    const float* norm_w     = (const float*)d_in[4];
    const float* wkvb       = (const float*)d_in[5];
    const float* wo         = (const float*)d_in[6];
    float* out = (float*)d_out;

    char* p = (char*)d_ws;
    ushort* xb       = (ushort*)p; p += (size_t)BS_ * DIM_ * 2;        // 16.8 MB
    ushort* q_bf     = (ushort*)p; p += (size_t)BS_ * H_ * Q_D_ * 2;   // 25.2 MB
    float*  ckv      = (float*) p; p += (size_t)BS_ * CKV_P_ * 4;      // 12.6 MB
    ushort* cnorm_bf = (ushort*)p; p += (size_t)BS_ * KV_LORA_ * 2;    //  4.2 MB
    ushort* kvb      = (ushort*)p; p += (size_t)BS_ * 4096 * 2;        // 33.6 MB
    ushort* attn_bf  = (ushort*)p; p += (size_t)BS_ * 2048 * 2;        // 16.8 MB
    ushort* krb      = (ushort*)p; p += (size_t)BS_ * ROPE_D_ * 2;     //  0.5 MB
    ushort* wc_bf    = (ushort*)p; p += (size_t)3840 * DIM_ * 2;       // 15.7 MB
    ushort* wkvb_bf  = (ushort*)p; p += (size_t)4096 * KV_LORA_ * 2;   //  4.2 MB
    ushort* wo_bf    = (ushort*)p; p += (size_t)DIM_ * 2048 * 2;       //  8.4 MB
    ushort* vT       = xb;   // alias: xb dead after GEMM 1; same size (16.8 MB)

    // 0. all input casts in one dispatch
    cast_all<<<11008, dim3(256), 0, stream>>>(
        x, wq, wkva, wkvb, wo, xb, wc_bf, wkvb_bf, wo_bf);

    // 1. fused: q_bf = x @ wq^T (bf16) and ckv = x @ wkva^T (fp32, pitch 768)
    gemm256_8ph<2><<<dim3(16 * 15), dim3(512), 0, stream>>>(
        xb, wc_bf, q_bf, ckv, 0, DIM_, 15);
    // 2. cnorm + krb fused
    rmsnorm_rope_k<<<BS_ / 4, dim3(256), 0, stream>>>(
        ckv, norm_w, rope_cache, cnorm_bf, krb);
    // 3. kvb (K-nope) + vT (V transposed) = cnorm @ wkvb^T, fused epilogue
    gemm256_8ph<3><<<dim3(16 * 16), dim3(512), 0, stream>>>(
        cnorm_bf, wkvb_bf, kvb, vT, 4096, KV_LORA_, 16);
    // 4. flash attention v7 (RoPE-q fused, coalesced staging) -> attn_bf
    mla_attn_mfma7<<<dim3(8, B_ * H_), dim3(512), 0, stream>>>(
        q_bf, kvb, krb, vT, rope_cache, attn_bf);
    // 5. out = attn @ wo^T        (4096 x 2048 x 2048), fp32, 256 blocks
    gemm_bn128<0><<<dim3(16 * 16), dim3(512), 0, stream>>>(
        attn_bf, wo_bf, out, 2048, 2048, 16);
}